// Round 1
// baseline (2680.240 us; speedup 1.0000x reference)
//
#include <hip/hip_runtime.h>
#include <math.h>

// ---------------------------------------------------------------------------
// Model dims (fixed): B=8 L=400 F=128 D=256 T=256 H=512 NH=8 HD=64 P=1200
// ---------------------------------------------------------------------------

__device__ __forceinline__ float mishf(float x) {
    float sp = fmaxf(x, 0.f) + log1pf(expf(-fabsf(x)));   // stable softplus
    return x * tanhf(sp);
}

// ---------------------------------------------------------------------------
// Generic fp32 GEMM: C[M,N] = A[M,K] @ B[K,N] + bias[N]  (EPI=1: mish)
// 64x64 tile, BK=16, 256 threads, 4x4 microtile, float4 LDS reads.
// ---------------------------------------------------------------------------
template<int EPI>
__global__ __launch_bounds__(256) void gemm_bias(
    const float* __restrict__ A, const float* __restrict__ Bm,
    const float* __restrict__ bias, float* __restrict__ C,
    int M, int N, int K, int ldc)
{
    __shared__ float As[16][68];   // [k][m]
    __shared__ float Bs[16][68];   // [k][n]
    int bm = blockIdx.y << 6, bn = blockIdx.x << 6;
    int tid = threadIdx.x;
    int tm = (tid >> 4) << 2, tn = (tid & 15) << 2;
    int ar = tid >> 2, ac4 = (tid & 3) << 2;   // A tile: row, col4
    int br = tid >> 4, bc4 = (tid & 15) << 2;  // B tile: row, col4
    float acc[4][4] = {};
    for (int k0 = 0; k0 < K; k0 += 16) {
        float4 av = make_float4(0.f, 0.f, 0.f, 0.f);
        if (bm + ar < M)
            av = *(const float4*)&A[(long long)(bm + ar) * K + k0 + ac4];
        As[ac4][ar] = av.x; As[ac4 + 1][ar] = av.y;
        As[ac4 + 2][ar] = av.z; As[ac4 + 3][ar] = av.w;
        *(float4*)&Bs[br][bc4] =
            *(const float4*)&Bm[(long long)(k0 + br) * N + bn + bc4];
        __syncthreads();
        #pragma unroll
        for (int kk = 0; kk < 16; ++kk) {
            float4 a4 = *(const float4*)&As[kk][tm];
            float4 b4 = *(const float4*)&Bs[kk][tn];
            acc[0][0] += a4.x * b4.x; acc[0][1] += a4.x * b4.y;
            acc[0][2] += a4.x * b4.z; acc[0][3] += a4.x * b4.w;
            acc[1][0] += a4.y * b4.x; acc[1][1] += a4.y * b4.y;
            acc[1][2] += a4.y * b4.z; acc[1][3] += a4.y * b4.w;
            acc[2][0] += a4.z * b4.x; acc[2][1] += a4.z * b4.y;
            acc[2][2] += a4.z * b4.z; acc[2][3] += a4.z * b4.w;
            acc[3][0] += a4.w * b4.x; acc[3][1] += a4.w * b4.y;
            acc[3][2] += a4.w * b4.z; acc[3][3] += a4.w * b4.w;
        }
        __syncthreads();
    }
    #pragma unroll
    for (int i = 0; i < 4; ++i) {
        int r = bm + tm + i;
        if (r < M) {
            float4 o;
            float v0 = acc[i][0] + bias[bn + tn + 0];
            float v1 = acc[i][1] + bias[bn + tn + 1];
            float v2 = acc[i][2] + bias[bn + tn + 2];
            float v3 = acc[i][3] + bias[bn + tn + 3];
            if (EPI == 1) { v0 = mishf(v0); v1 = mishf(v1); v2 = mishf(v2); v3 = mishf(v3); }
            o.x = v0; o.y = v1; o.z = v2; o.w = v3;
            *(float4*)&C[(long long)r * ldc + bn + tn] = o;
        }
    }
}

// ---------------------------------------------------------------------------
// Conv1d k=3 SAME over L, in=f1 (feats cols 0..255), out=relu -> feats cols 256..511
// ---------------------------------------------------------------------------
__global__ __launch_bounds__(256) void conv_kernel(
    const float* __restrict__ feats, const float* __restrict__ w,
    const float* __restrict__ bias, float* __restrict__ fo)
{
    int bl = blockIdx.x; int b = bl / 400, l = bl % 400;
    int t = threadIdx.x;
    __shared__ float xr[768];
    #pragma unroll
    for (int dl = 0; dl < 3; ++dl) {
        int ls = l + dl - 1;
        float vv = 0.f;
        if (ls >= 0 && ls < 400) vv = feats[((long long)(b * 400 + ls)) * 512 + t];
        xr[dl * 256 + t] = vv;
    }
    __syncthreads();
    float acc = bias[t];
    #pragma unroll 4
    for (int j = 0; j < 768; ++j) acc += xr[j] * w[j * 256 + t];
    fo[((long long)bl) * 512 + 256 + t] = fmaxf(acc, 0.f);
}

// ---------------------------------------------------------------------------
// masks[4][B][L] from x channels
// ---------------------------------------------------------------------------
__global__ void masks_kernel(const float* __restrict__ x, float* __restrict__ mk)
{
    int i = blockIdx.x * 256 + threadIdx.x;
    if (i >= 3200) return;
    const float* xr = x + (long long)i * 128;
    mk[0 * 3200 + i] = xr[4];
    mk[1 * 3200 + i] = fmaxf(xr[2], xr[3]);
    mk[2 * 3200 + i] = xr[0];
    mk[3 * 3200 + i] = xr[1];
}

// ---------------------------------------------------------------------------
// DeBERTa-v2 log-bucket rel index table T[dd], dd = (l-m)+399 in [0,799)
// (c2p index == swapped p2c index by odd symmetry of bpos)
// ---------------------------------------------------------------------------
__global__ void relidx_kernel(int* __restrict__ T)
{
    int i = blockIdx.x * blockDim.x + threadIdx.x;
    if (i >= 799) return;
    int rel = i - 399;
    int sgn = (rel > 0) - (rel < 0);
    int ab = (rel < 300 && rel > -300) ? 299 : (rel < 0 ? -rel : rel);
    long long bpos;
    if (ab <= 300) bpos = rel;
    else {
        double lp = ceil(log((double)ab / 300.0) / log(599.0 / 300.0) * 299.0) + 300.0;
        bpos = (long long)lp * sgn;
    }
    long long c2p = bpos + 600;
    c2p = c2p < 0 ? 0 : (c2p > 1199 ? 1199 : c2p);
    T[i] = (int)c2p;
}

// ---------------------------------------------------------------------------
// Gather rel rows: pkg[dd][512] = pk[T[dd]][:], same for pq
// ---------------------------------------------------------------------------
__global__ void gather_rel(const float* __restrict__ pk, const float* __restrict__ pq,
                           const int* __restrict__ T,
                           float* __restrict__ pkg, float* __restrict__ pqg)
{
    int idx = blockIdx.x * 256 + threadIdx.x;
    if (idx >= 799 * 512) return;
    int dd = idx >> 9, c = idx & 511;
    int r = T[dd];
    pkg[idx] = pk[(long long)r * 512 + c];
    pqg[idx] = pq[(long long)r * 512 + c];
}

// ---------------------------------------------------------------------------
// LayerNorm (eps 1e-7). RES: adds residual R. Hd = 256 or 512. One row/block.
// ---------------------------------------------------------------------------
template<bool RES>
__global__ __launch_bounds__(256) void ln_kernel(
    const float* __restrict__ X, const float* __restrict__ R,
    const float* __restrict__ g, const float* __restrict__ be,
    float* __restrict__ Y, int Hd)
{
    long long row = blockIdx.x;
    int t = threadIdx.x;
    __shared__ float buf[512];
    __shared__ float red[256];
    const float* x = X + row * Hd;
    float s = 0.f;
    for (int j = t; j < Hd; j += 256) {
        float vv = x[j];
        if (RES) vv += R[row * Hd + j];
        buf[j] = vv; s += vv;
    }
    red[t] = s; __syncthreads();
    for (int k = 128; k; k >>= 1) { if (t < k) red[t] += red[t + k]; __syncthreads(); }
    float mean = red[0] / (float)Hd;
    __syncthreads();
    float s2 = 0.f;
    for (int j = t; j < Hd; j += 256) { float d = buf[j] - mean; s2 += d * d; }
    red[t] = s2; __syncthreads();
    for (int k = 128; k; k >>= 1) { if (t < k) red[t] += red[t + k]; __syncthreads(); }
    float inv = 1.f / sqrtf(red[0] / (float)Hd + 1e-7f);
    for (int j = t; j < Hd; j += 256)
        Y[row * Hd + j] = (buf[j] - mean) * inv * g[j] + be[j];
}

// ---------------------------------------------------------------------------
// Fused disentangled attention (flash-style).
// Block = (l-tile of 32, head, batch). score(l,m) =
//   scale*( q.k + q.pkg[l-m+399] + k.pqg[l-m+399] ), masked, softmax, @V.
// ---------------------------------------------------------------------------
__global__ __launch_bounds__(256) void attn_kernel(
    const float* __restrict__ q, const float* __restrict__ k, const float* __restrict__ v,
    const float* __restrict__ pkg, const float* __restrict__ pqg,
    const float* __restrict__ mask, float* __restrict__ ctx)
{
    const float scale = 0.07216878364870322f;       // 1/sqrt(64*3)
    const float NEGMIN = -3.402823466e38f;          // finfo(f32).min
    int lt = blockIdx.x, h = blockIdx.y, b = blockIdx.z;
    int l0 = lt * 32;
    int tid = threadIdx.x;
    int ty = tid >> 4, tx = tid & 15;
    int i0 = ty * 2;          // local l rows i0, i0+1
    int j0 = tx * 2;          // local m cols j0, j0+1

    __shared__ float Qs[32][68];
    __shared__ float Ks[32][68];
    __shared__ float Vs[32][68];
    __shared__ float PKs[63][68];
    __shared__ float PQs[63][68];
    __shared__ float St[32][34];                    // [m][l] = scores then P
    __shared__ float mstate[32], lstate[32], corrs[32], wlv[32], wmv[32];

    // stage Q tile once
    for (int u = tid; u < 512; u += 256) {
        int r = u >> 4, c4 = (u & 15) << 2;
        float4 val = make_float4(0.f, 0.f, 0.f, 0.f);
        int lg = l0 + r;
        if (lg < 400) val = *(const float4*)&q[((long long)(b * 400 + lg)) * 512 + h * 64 + c4];
        *(float4*)&Qs[r][c4] = val;
    }
    if (tid < 32) {
        int lg = l0 + tid;
        wlv[tid] = (lg < 400) ? mask[b * 400 + lg] : 0.f;
        mstate[tid] = -INFINITY;
        lstate[tid] = 0.f;
    }
    float O[2][4] = {};

    for (int mt = 0; mt < 13; ++mt) {
        int m0 = mt * 32;
        __syncthreads();   // prev iter's PV done before restaging
        // stage K, V
        for (int u = tid; u < 512; u += 256) {
            int r = u >> 4, c4 = (u & 15) << 2;
            int mg = m0 + r;
            float4 kv4 = make_float4(0.f, 0.f, 0.f, 0.f);
            float4 vv4 = make_float4(0.f, 0.f, 0.f, 0.f);
            if (mg < 400) {
                long long base = ((long long)(b * 400 + mg)) * 512 + h * 64 + c4;
                kv4 = *(const float4*)&k[base];
                vv4 = *(const float4*)&v[base];
            }
            *(float4*)&Ks[r][c4] = kv4;
            *(float4*)&Vs[r][c4] = vv4;
        }
        if (tid < 32) {
            int mg = m0 + tid;
            wmv[tid] = (mg < 400) ? mask[b * 400 + mg] : 0.f;
        }
        // stage rel band: rows dd = D0..D0+62
        int D0 = l0 - m0 + 368;
        for (int u = tid; u < 63 * 16; u += 256) {
            int rr = u >> 4, c4 = (u & 15) << 2;
            int dd = D0 + rr;
            float4 a = make_float4(0.f, 0.f, 0.f, 0.f);
            float4 bb = make_float4(0.f, 0.f, 0.f, 0.f);
            if (dd >= 0 && dd < 799) {
                a = *(const float4*)&pkg[(long long)dd * 512 + h * 64 + c4];
                bb = *(const float4*)&pqg[(long long)dd * 512 + h * 64 + c4];
            }
            *(float4*)&PKs[rr][c4] = a;
            *(float4*)&PQs[rr][c4] = bb;
        }
        __syncthreads();

        // compute 2x2 scores; band row for (i,j) = (i-j)+31
        float acc00 = 0.f, acc01 = 0.f, acc10 = 0.f, acc11 = 0.f;
        int rb = (i0 - j0) + 31;   // in [1,61]
        #pragma unroll 4
        for (int d4 = 0; d4 < 16; ++d4) {
            int dc = d4 << 2;
            float4 qa0 = *(const float4*)&Qs[i0][dc];
            float4 qa1 = *(const float4*)&Qs[i0 + 1][dc];
            float4 kb0 = *(const float4*)&Ks[j0][dc];
            float4 kb1 = *(const float4*)&Ks[j0 + 1][dc];
            float4 pk0 = *(const float4*)&PKs[rb][dc];
            float4 pkm = *(const float4*)&PKs[rb - 1][dc];
            float4 pkp = *(const float4*)&PKs[rb + 1][dc];
            float4 pq0 = *(const float4*)&PQs[rb][dc];
            float4 pqm = *(const float4*)&PQs[rb - 1][dc];
            float4 pqp = *(const float4*)&PQs[rb + 1][dc];
            acc00 += qa0.x*(kb0.x + pk0.x) + kb0.x*pq0.x
                   + qa0.y*(kb0.y + pk0.y) + kb0.y*pq0.y
                   + qa0.z*(kb0.z + pk0.z) + kb0.z*pq0.z
                   + qa0.w*(kb0.w + pk0.w) + kb0.w*pq0.w;
            acc01 += qa0.x*(kb1.x + pkm.x) + kb1.x*pqm.x
                   + qa0.y*(kb1.y + pkm.y) + kb1.y*pqm.y
                   + qa0.z*(kb1.z + pkm.z) + kb1.z*pqm.z
                   + qa0.w*(kb1.w + pkm.w) + kb1.w*pqm.w;
            acc10 += qa1.x*(kb0.x + pkp.x) + kb0.x*pqp.x
                   + qa1.y*(kb0.y + pkp.y) + kb0.y*pqp.y
                   + qa1.z*(kb0.z + pkp.z) + kb0.z*pqp.z
                   + qa1.w*(kb0.w + pkp.w) + kb0.w*pqp.w;
            acc11 += qa1.x*(kb1.x + pk0.x) + kb1.x*pq0.x
                   + qa1.y*(kb1.y + pk0.y) + kb1.y*pq0.y
                   + qa1.z*(kb1.z + pk0.z) + kb1.z*pq0.z
                   + qa1.w*(kb1.w + pk0.w) + kb1.w*pq0.w;
        }
        float wl0 = wlv[i0], wl1 = wlv[i0 + 1];
        float wm0 = wmv[j0], wm1 = wmv[j0 + 1];
        bool jv0 = (m0 + j0) < 400, jv1 = (m0 + j0 + 1) < 400;
        float s00 = jv0 ? ((wl0 != 0.f && wm0 != 0.f) ? acc00 * scale : NEGMIN) : -INFINITY;
        float s01 = jv1 ? ((wl0 != 0.f && wm1 != 0.f) ? acc01 * scale : NEGMIN) : -INFINITY;
        float s10 = jv0 ? ((wl1 != 0.f && wm0 != 0.f) ? acc10 * scale : NEGMIN) : -INFINITY;
        float s11 = jv1 ? ((wl1 != 0.f && wm1 != 0.f) ? acc11 * scale : NEGMIN) : -INFINITY;
        St[j0][i0] = s00; St[j0][i0 + 1] = s10;
        St[j0 + 1][i0] = s01; St[j0 + 1][i0 + 1] = s11;
        __syncthreads();

        // flash state update (threads 0..31, one per l row)
        if (tid < 32) {
            int i = tid;
            float mtile = -INFINITY;
            for (int j = 0; j < 32; ++j) mtile = fmaxf(mtile, St[j][i]);
            float mo = mstate[i];
            float mn = fmaxf(mo, mtile);
            float corr = expf(mo - mn);   // first tile: exp(-inf - finite) = 0
            float rs = 0.f;
            for (int j = 0; j < 32; ++j) {
                float p = expf(St[j][i] - mn);
                St[j][i] = p;
                rs += p;
            }
            lstate[i] = lstate[i] * corr + rs;
            mstate[i] = mn;
            corrs[i] = corr;
        }
        __syncthreads();

        // PV accumulate (with rescale)
        float c0 = corrs[i0], c1 = corrs[i0 + 1];
        #pragma unroll
        for (int u = 0; u < 4; ++u) { O[0][u] *= c0; O[1][u] *= c1; }
        int dcol = tx << 2;
        #pragma unroll 8
        for (int kk = 0; kk < 32; ++kk) {
            float a0 = St[kk][i0], a1 = St[kk][i0 + 1];
            float4 bv = *(const float4*)&Vs[kk][dcol];
            O[0][0] += a0 * bv.x; O[0][1] += a0 * bv.y;
            O[0][2] += a0 * bv.z; O[0][3] += a0 * bv.w;
            O[1][0] += a1 * bv.x; O[1][1] += a1 * bv.y;
            O[1][2] += a1 * bv.z; O[1][3] += a1 * bv.w;
        }
    }
    // write ctx
    int lg0 = l0 + i0;
    if (lg0 < 400) {
        float inv = 1.f / lstate[i0];
        float4 r = make_float4(O[0][0] * inv, O[0][1] * inv, O[0][2] * inv, O[0][3] * inv);
        *(float4*)&ctx[((long long)(b * 400 + lg0)) * 512 + h * 64 + (tx << 2)] = r;
    }
    if (lg0 + 1 < 400) {
        float inv = 1.f / lstate[i0 + 1];
        float4 r = make_float4(O[1][0] * inv, O[1][1] * inv, O[1][2] * inv, O[1][3] * inv);
        *(float4*)&ctx[((long long)(b * 400 + lg0 + 1)) * 512 + h * 64 + (tx << 2)] = r;
    }
}

// ---------------------------------------------------------------------------
// Masked attention pooling over L: att = sum(x*w)/ (sum w + 1e-6), mx = max(x*w)
// ---------------------------------------------------------------------------
__global__ __launch_bounds__(256) void pool_kernel(
    const float* __restrict__ oenc, const float* __restrict__ mk,
    float* __restrict__ pooled)
{
    int b = blockIdx.x; int t = threadIdx.x;
    float acc = 0.f, mxv = -INFINITY, sw = 0.f;
    for (int l = 0; l < 400; ++l) {
        float w = mk[b * 400 + l];
        float vv = oenc[((long long)(b * 400 + l)) * 256 + t] * w;
        acc += vv; mxv = fmaxf(mxv, vv); sw += w;
    }
    pooled[b * 512 + t] = acc / (sw + 1e-6f);
    pooled[b * 512 + 256 + t] = mxv;
}

// ---------------------------------------------------------------------------
// feats mean/max over L -> mm[b][0..511]=mean, [512..1023]=max
// ---------------------------------------------------------------------------
__global__ __launch_bounds__(512) void meanmax_kernel(
    const float* __restrict__ feats, float* __restrict__ mm)
{
    int b = blockIdx.x; int t = threadIdx.x;
    float s = 0.f, mx = -INFINITY;
    for (int l = 0; l < 400; ++l) {
        float vv = feats[((long long)(b * 400 + l)) * 512 + t];
        s += vv; mx = fmaxf(mx, vv);
    }
    mm[b * 1024 + t] = s / 400.f;
    mm[b * 1024 + 512 + t] = mx;
}

// ---------------------------------------------------------------------------
// Heads: grid (B, 5): role 0=bowel, 1=extravasation(+zeros), 2..4=organ i
// ---------------------------------------------------------------------------
__global__ __launch_bounds__(256) void heads_kernel(
    const float* __restrict__ pooled, const float* __restrict__ mm,
    const float* __restrict__ w_bow1, const float* __restrict__ b_bow1,
    const float* __restrict__ w_bow2, const float* __restrict__ b_bow2,
    const float* __restrict__ w_ext1, const float* __restrict__ b_ext1,
    const float* __restrict__ w_ext2, const float* __restrict__ b_ext2,
    const float* __restrict__ w_org1, const float* __restrict__ b_org1,
    const float* __restrict__ w_org2, const float* __restrict__ b_org2,
    float* __restrict__ out)
{
    int b = blockIdx.x, role = blockIdx.y;
    int t = threadIdx.x;
    __shared__ float inb[1024];
    __shared__ float red[256];
    __shared__ float hid[256];
    if (role == 0) {
        inb[t] = pooled[b * 512 + t];
        inb[256 + t] = pooled[b * 512 + 256 + t];
        __syncthreads();
        float acc = b_bow1[t];
        for (int j = 0; j < 512; ++j) acc += inb[j] * w_bow1[j * 256 + t];
        red[t] = mishf(acc) * w_bow2[t];
        __syncthreads();
        for (int s = 128; s; s >>= 1) { if (t < s) red[t] += red[t + s]; __syncthreads(); }
        if (t == 0) out[b * 11 + 0] = red[0] + b_bow2[0];
    } else if (role == 1) {
        inb[t] = mm[b * 1024 + t];
        inb[256 + t] = mm[b * 1024 + 256 + t];
        inb[512 + t] = mm[b * 1024 + 512 + t];
        inb[768 + t] = mm[b * 1024 + 768 + t];
        __syncthreads();
        float acc = b_ext1[t];
        for (int j = 0; j < 1024; ++j) acc += inb[j] * w_ext1[j * 256 + t];
        red[t] = mishf(acc) * w_ext2[t];
        __syncthreads();
        for (int s = 128; s; s >>= 1) { if (t < s) red[t] += red[t + s]; __syncthreads(); }
        if (t == 0) { out[b * 11 + 1] = red[0] + b_ext2[0]; out[88 + b] = 0.f; }
    } else {
        int i = role - 2;
        inb[t] = pooled[((1 + i) * 8 + b) * 512 + t];
        inb[256 + t] = pooled[((1 + i) * 8 + b) * 512 + 256 + t];
        __syncthreads();
        float acc = b_org1[i * 256 + t];
        for (int j = 0; j < 512; ++j)
            acc += inb[j] * w_org1[((long long)i * 512 + j) * 256 + t];
        hid[t] = mishf(acc);
        __syncthreads();
        for (int c = 0; c < 3; ++c) {
            red[t] = hid[t] * w_org2[(i * 256 + t) * 3 + c];
            __syncthreads();
            for (int s = 128; s; s >>= 1) { if (t < s) red[t] += red[t + s]; __syncthreads(); }
            if (t == 0) out[b * 11 + 2 + i * 3 + c] = red[0] + b_org2[i * 3 + c];
            __syncthreads();
        }
    }
}

// ---------------------------------------------------------------------------
// Launch
// ---------------------------------------------------------------------------
extern "C" void kernel_launch(void* const* d_in, const int* in_sizes, int n_in,
                              void* d_out, int out_size, void* d_ws, size_t ws_size,
                              hipStream_t stream)
{
    const float* x      = (const float*)d_in[0];
    const float* w_mlp  = (const float*)d_in[1];
    const float* b_mlp  = (const float*)d_in[2];
    const float* w_cnn  = (const float*)d_in[3];
    const float* b_cnn  = (const float*)d_in[4];
    const float* rel_emb= (const float*)d_in[5];
    const float* rel_g  = (const float*)d_in[6];
    const float* rel_b  = (const float*)d_in[7];
    const float* wq     = (const float*)d_in[8];
    const float* wk     = (const float*)d_in[9];
    const float* wv     = (const float*)d_in[10];
    const float* wo     = (const float*)d_in[11];
    const float* wi     = (const float*)d_in[12];
    const float* bq     = (const float*)d_in[13];
    const float* bk     = (const float*)d_in[14];
    const float* bv     = (const float*)d_in[15];
    const float* bo     = (const float*)d_in[16];
    const float* bi     = (const float*)d_in[17];
    const float* wout   = (const float*)d_in[18];
    const float* bout   = (const float*)d_in[19];
    const float* ln1g   = (const float*)d_in[20];
    const float* ln1b   = (const float*)d_in[21];
    const float* ln2g   = (const float*)d_in[22];
    const float* ln2b   = (const float*)d_in[23];
    const float* w_bow1 = (const float*)d_in[24];
    const float* b_bow1 = (const float*)d_in[25];
    const float* w_bow2 = (const float*)d_in[26];
    const float* b_bow2 = (const float*)d_in[27];
    const float* w_ext1 = (const float*)d_in[28];
    const float* b_ext1 = (const float*)d_in[29];
    const float* w_ext2 = (const float*)d_in[30];
    const float* b_ext2 = (const float*)d_in[31];
    const float* w_org1 = (const float*)d_in[32];
    const float* b_org1 = (const float*)d_in[33];
    const float* w_org2 = (const float*)d_in[34];
    const float* b_org2 = (const float*)d_in[35];

    float* ws = (float*)d_ws;
    // workspace layout (floats)
    float* featsb = ws + 0;                 // 1,638,400
    float* qb     = ws + 1638400;           // 1,638,400 (later: tmp_wo)
    float* kb     = ws + 3276800;           // 1,638,400 (later: h1)
    float* vb     = ws + 4915200;           // 1,638,400 (later: tmp2 + out_enc)
    float* ctxb   = ws + 6553600;           // 1,638,400 (later: inter)
    float* rellnb = ws + 8192000;           // 614,400
    float* pqb    = ws + 8806400;           // 614,400
    float* pkb    = ws + 9420800;           // 614,400
    float* pkgb   = ws + 10035200;          // 409,600 (799*512 used)
    float* pqgb   = ws + 10444800;          // 409,600
    float* masksb = ws + 10854400;          // 12,800
    float* pooledb= ws + 10867200;          // 16,384
    float* mmb    = ws + 10883584;          // 8,192
    int*   relidx = (int*)(ws + 10891776);  // 800 ints
    float* outf   = (float*)d_out;

    // front: f1 = mish(x@w_mlp+b_mlp) into feats cols 0..255 (ldc=512)
    gemm_bias<1><<<dim3(4, 50), 256, 0, stream>>>(x, w_mlp, b_mlp, featsb,
                                                  3200, 256, 128, 512);
    conv_kernel<<<3200, 256, 0, stream>>>(featsb, w_cnn, b_cnn, featsb);
    masks_kernel<<<13, 256, 0, stream>>>(x, masksb);
    relidx_kernel<<<4, 256, 0, stream>>>(relidx);

    for (int o = 0; o < 4; ++o) {
        const long long oW = (long long)o * 512 * 512;
        // rel layernorm
        ln_kernel<false><<<1200, 256, 0, stream>>>(rel_emb + (long long)o * 614400,
            nullptr, rel_g + o * 512, rel_b + o * 512, rellnb, 512);
        // projections
        gemm_bias<0><<<dim3(8, 50), 256, 0, stream>>>(featsb, wq + oW, bq + o * 512, qb, 3200, 512, 512, 512);
        gemm_bias<0><<<dim3(8, 50), 256, 0, stream>>>(featsb, wk + oW, bk + o * 512, kb, 3200, 512, 512, 512);
        gemm_bias<0><<<dim3(8, 50), 256, 0, stream>>>(featsb, wv + oW, bv + o * 512, vb, 3200, 512, 512, 512);
        gemm_bias<0><<<dim3(8, 19), 256, 0, stream>>>(rellnb, wq + oW, bq + o * 512, pqb, 1200, 512, 512, 512);
        gemm_bias<0><<<dim3(8, 19), 256, 0, stream>>>(rellnb, wk + oW, bk + o * 512, pkb, 1200, 512, 512, 512);
        // rel gathers
        gather_rel<<<1598, 256, 0, stream>>>(pkb, pqb, relidx, pkgb, pqgb);
        // fused attention
        attn_kernel<<<dim3(13, 8, 8), 256, 0, stream>>>(qb, kb, vb, pkgb, pqgb,
                                                        masksb + o * 3200, ctxb);
        // output proj + LN(residual)
        gemm_bias<0><<<dim3(8, 50), 256, 0, stream>>>(ctxb, wo + oW, bo + o * 512, qb, 3200, 512, 512, 512);
        ln_kernel<true><<<3200, 256, 0, stream>>>(qb, featsb, ln1g + o * 512, ln1b + o * 512, kb, 512);
        // intermediate mish
        gemm_bias<1><<<dim3(8, 50), 256, 0, stream>>>(kb, wi + oW, bi + o * 512, ctxb, 3200, 512, 512, 512);
        // out proj + LN (no residual), dim 256
        gemm_bias<0><<<dim3(4, 50), 256, 0, stream>>>(ctxb, wout + (long long)o * 131072,
            bout + o * 256, vb, 3200, 256, 512, 256);
        ln_kernel<false><<<3200, 256, 0, stream>>>(vb, nullptr, ln2g + o * 256, ln2b + o * 256,
            vb + 819200, 256);
        // pooling
        pool_kernel<<<8, 256, 0, stream>>>(vb + 819200, masksb + o * 3200, pooledb + o * 4096);
    }

    meanmax_kernel<<<8, 512, 0, stream>>>(featsb, mmb);
    heads_kernel<<<dim3(8, 5), 256, 0, stream>>>(pooledb, mmb,
        w_bow1, b_bow1, w_bow2, b_bow2, w_ext1, b_ext1, w_ext2, b_ext2,
        w_org1, b_org1, w_org2, b_org2, outf);
}

// Round 2
// 1936.448 us; speedup vs baseline: 1.3841x; 1.3841x over previous
//
#include <hip/hip_runtime.h>
#include <math.h>

// ---------------------------------------------------------------------------
// Model dims (fixed): B=8 L=400 F=128 D=256 T=256 H=512 NH=8 HD=64 P=1200
// ---------------------------------------------------------------------------

typedef __attribute__((ext_vector_type(8))) short bf16x8;
typedef __attribute__((ext_vector_type(4))) float f32x4;
typedef __attribute__((ext_vector_type(4))) unsigned int u32x4;

__device__ __forceinline__ float mishf(float x) {
    float sp = fmaxf(x, 0.f) + log1pf(expf(-fabsf(x)));   // stable softplus
    return x * tanhf(sp);
}

__device__ __forceinline__ unsigned short f2bf(float f) {
    unsigned int u = __float_as_uint(f);
    u = (u + 0x7fffu + ((u >> 16) & 1u)) >> 16;           // RNE
    return (unsigned short)u;
}
__device__ __forceinline__ float bf2f(unsigned short h) {
    return __uint_as_float(((unsigned int)h) << 16);
}

// ---------------------------------------------------------------------------
// fp32 GEMM (kept for the small MLP front GEMM K=128)
// ---------------------------------------------------------------------------
template<int EPI>
__global__ __launch_bounds__(256) void gemm_bias(
    const float* __restrict__ A, const float* __restrict__ Bm,
    const float* __restrict__ bias, float* __restrict__ C,
    int M, int N, int K, int ldc)
{
    __shared__ float As[16][68];
    __shared__ float Bs[16][68];
    int bm = blockIdx.y << 6, bn = blockIdx.x << 6;
    int tid = threadIdx.x;
    int tm = (tid >> 4) << 2, tn = (tid & 15) << 2;
    int ar = tid >> 2, ac4 = (tid & 3) << 2;
    int br = tid >> 4, bc4 = (tid & 15) << 2;
    float acc[4][4] = {};
    for (int k0 = 0; k0 < K; k0 += 16) {
        float4 av = make_float4(0.f, 0.f, 0.f, 0.f);
        if (bm + ar < M)
            av = *(const float4*)&A[(long long)(bm + ar) * K + k0 + ac4];
        As[ac4][ar] = av.x; As[ac4 + 1][ar] = av.y;
        As[ac4 + 2][ar] = av.z; As[ac4 + 3][ar] = av.w;
        *(float4*)&Bs[br][bc4] =
            *(const float4*)&Bm[(long long)(k0 + br) * N + bn + bc4];
        __syncthreads();
        #pragma unroll
        for (int kk = 0; kk < 16; ++kk) {
            float4 a4 = *(const float4*)&As[kk][tm];
            float4 b4 = *(const float4*)&Bs[kk][tn];
            acc[0][0] += a4.x * b4.x; acc[0][1] += a4.x * b4.y;
            acc[0][2] += a4.x * b4.z; acc[0][3] += a4.x * b4.w;
            acc[1][0] += a4.y * b4.x; acc[1][1] += a4.y * b4.y;
            acc[1][2] += a4.y * b4.z; acc[1][3] += a4.y * b4.w;
            acc[2][0] += a4.z * b4.x; acc[2][1] += a4.z * b4.y;
            acc[2][2] += a4.z * b4.z; acc[2][3] += a4.z * b4.w;
            acc[3][0] += a4.w * b4.x; acc[3][1] += a4.w * b4.y;
            acc[3][2] += a4.w * b4.z; acc[3][3] += a4.w * b4.w;
        }
        __syncthreads();
    }
    #pragma unroll
    for (int i = 0; i < 4; ++i) {
        int r = bm + tm + i;
        if (r < M) {
            float v0 = acc[i][0] + bias[bn + tn + 0];
            float v1 = acc[i][1] + bias[bn + tn + 1];
            float v2 = acc[i][2] + bias[bn + tn + 2];
            float v3 = acc[i][3] + bias[bn + tn + 3];
            if (EPI == 1) { v0 = mishf(v0); v1 = mishf(v1); v2 = mishf(v2); v3 = mishf(v3); }
            float4 o; o.x = v0; o.y = v1; o.z = v2; o.w = v3;
            *(float4*)&C[(long long)r * ldc + bn + tn] = o;
        }
    }
}

// ---------------------------------------------------------------------------
// MFMA bf16x3-split GEMM: C[M,N] = A[M,K](fp32) @ B + bias
// B pre-transposed+split: Bth/Btl are [N][K] bf16 (hi/lo).
// Tile 64(M) x 128(N), BK=32, 256 thr = 4 waves (2x2), wave tile 32x64,
// 2x4 frags of 16x16x32 MFMA, 3 MFMAs per frag pair (hihi, hilo, lohi).
// GATHER: A row remap via gidx (rows >= M -> zero). EPI=1: mish.
// ---------------------------------------------------------------------------
template<int EPI, bool GATHER>
__global__ __launch_bounds__(256) void gemm_mfma(
    const float* __restrict__ A,
    const unsigned short* __restrict__ Bth, const unsigned short* __restrict__ Btl,
    const float* __restrict__ bias, float* __restrict__ C,
    int M, int K, int ldc, const int* __restrict__ gidx)
{
    __shared__ unsigned short Ah[64 * 40];
    __shared__ unsigned short Al[64 * 40];
    __shared__ unsigned short Bh[128 * 40];
    __shared__ unsigned short Bl[128 * 40];

    int bm = blockIdx.y << 6, bn = blockIdx.x << 7;
    int tid = threadIdx.x;
    int lane = tid & 63, wid = tid >> 6;
    int wm = wid >> 1, wn = wid & 1;
    int fr = lane & 15, kg = (lane >> 4) << 3;

    // staging coords
    int ar = tid >> 2, akc = (tid & 3) << 3;     // A: row, 8 k
    int bnr = tid >> 1, bkc = (tid & 1) << 4;    // B: row, 16 k

    long long arow; bool avalid;
    {
        int gr = bm + ar;
        avalid = gr < M;
        if (GATHER) arow = avalid ? (long long)gidx[gr] : 0;
        else        arow = avalid ? (long long)gr : 0;
    }

    f32x4 acc[2][4] = {};

    for (int k0 = 0; k0 < K; k0 += 32) {
        // ---- stage A (fp32 -> hi/lo bf16) ----
        float vv[8];
        if (avalid) {
            float4 v0 = *(const float4*)&A[arow * K + k0 + akc];
            float4 v1 = *(const float4*)&A[arow * K + k0 + akc + 4];
            vv[0] = v0.x; vv[1] = v0.y; vv[2] = v0.z; vv[3] = v0.w;
            vv[4] = v1.x; vv[5] = v1.y; vv[6] = v1.z; vv[7] = v1.w;
        } else {
            #pragma unroll
            for (int e = 0; e < 8; ++e) vv[e] = 0.f;
        }
        union { unsigned short u[8]; u32x4 v; } ph, pl;
        #pragma unroll
        for (int e = 0; e < 8; ++e) {
            unsigned short h = f2bf(vv[e]);
            ph.u[e] = h;
            pl.u[e] = f2bf(vv[e] - bf2f(h));
        }
        *(u32x4*)&Ah[ar * 40 + akc] = ph.v;
        *(u32x4*)&Al[ar * 40 + akc] = pl.v;

        // ---- stage B (pre-split bf16, straight copy) ----
        {
            long long boff = (long long)(bn + bnr) * K + k0 + bkc;
            *(u32x4*)&Bh[bnr * 40 + bkc]     = *(const u32x4*)&Bth[boff];
            *(u32x4*)&Bh[bnr * 40 + bkc + 8] = *(const u32x4*)&Bth[boff + 8];
            *(u32x4*)&Bl[bnr * 40 + bkc]     = *(const u32x4*)&Btl[boff];
            *(u32x4*)&Bl[bnr * 40 + bkc + 8] = *(const u32x4*)&Btl[boff + 8];
        }
        __syncthreads();

        bf16x8 af[2], alf[2], bf[4], blf[4];
        #pragma unroll
        for (int i = 0; i < 2; ++i) {
            int row = wm * 32 + i * 16 + fr;
            af[i]  = *(const bf16x8*)&Ah[row * 40 + kg];
            alf[i] = *(const bf16x8*)&Al[row * 40 + kg];
        }
        #pragma unroll
        for (int j = 0; j < 4; ++j) {
            int row = wn * 64 + j * 16 + fr;
            bf[j]  = *(const bf16x8*)&Bh[row * 40 + kg];
            blf[j] = *(const bf16x8*)&Bl[row * 40 + kg];
        }
        #pragma unroll
        for (int i = 0; i < 2; ++i)
        #pragma unroll
        for (int j = 0; j < 4; ++j) {
            acc[i][j] = __builtin_amdgcn_mfma_f32_16x16x32_bf16(af[i],  bf[j],  acc[i][j], 0, 0, 0);
            acc[i][j] = __builtin_amdgcn_mfma_f32_16x16x32_bf16(af[i],  blf[j], acc[i][j], 0, 0, 0);
            acc[i][j] = __builtin_amdgcn_mfma_f32_16x16x32_bf16(alf[i], bf[j],  acc[i][j], 0, 0, 0);
        }
        __syncthreads();
    }

    // ---- epilogue: C/D layout col=lane&15, row=(lane>>4)*4+r ----
    #pragma unroll
    for (int i = 0; i < 2; ++i) {
        int rbase = bm + wm * 32 + i * 16 + ((lane >> 4) << 2);
        #pragma unroll
        for (int j = 0; j < 4; ++j) {
            int ccol = bn + wn * 64 + j * 16 + fr;
            float bv = bias[ccol];
            #pragma unroll
            for (int r = 0; r < 4; ++r) {
                int row = rbase + r;
                if (row < M) {
                    float val = acc[i][j][r] + bv;
                    if (EPI == 1) val = mishf(val);
                    C[(long long)row * ldc + ccol] = val;
                }
            }
        }
    }
}

// ---------------------------------------------------------------------------
// Weight prep: transpose + split to bf16 hi/lo, [N][K] layout.
// prep_wqkv: [1536][512] from wq|wk|wv of organ o.
// ---------------------------------------------------------------------------
__global__ __launch_bounds__(256) void prep_wqkv(
    const float* __restrict__ wq, const float* __restrict__ wk,
    const float* __restrict__ wv,
    unsigned short* __restrict__ whi, unsigned short* __restrict__ wlo, int o)
{
    int idx = blockIdx.x * 256 + threadIdx.x;
    if (idx >= 1536 * 512) return;
    int k = idx / 1536, n = idx % 1536;
    int sel = n >> 9, col = n & 511;
    const float* W = sel == 0 ? wq : (sel == 1 ? wk : wv);
    float v = W[(long long)o * 262144 + k * 512 + col];
    unsigned short h = f2bf(v);
    whi[n * 512 + k] = h;
    wlo[n * 512 + k] = f2bf(v - bf2f(h));
}

// prep_woiw: packs Wo^T (off 0), Wi^T (off 262144), Wout^T (off 524288)
__global__ __launch_bounds__(256) void prep_woiw(
    const float* __restrict__ wo, const float* __restrict__ wi,
    const float* __restrict__ wout,
    unsigned short* __restrict__ whi, unsigned short* __restrict__ wlo, int o)
{
    int idx = blockIdx.x * 256 + threadIdx.x;
    if (idx >= 655360) return;
    const float* W; int N, nk, base;
    if (idx < 262144)      { W = wo + (long long)o * 262144; N = 512; nk = idx; base = 0; }
    else if (idx < 524288) { W = wi + (long long)o * 262144; N = 512; nk = idx - 262144; base = 262144; }
    else                   { W = wout + (long long)o * 131072; N = 256; nk = idx - 524288; base = 524288; }
    int k = nk / N, n = nk % N;
    float v = W[k * N + n];
    unsigned short h = f2bf(v);
    whi[base + n * 512 + k] = h;
    wlo[base + n * 512 + k] = f2bf(v - bf2f(h));
}

// pack bqkv[4][1536]
__global__ void pack_bqkv(const float* __restrict__ bq, const float* __restrict__ bk,
                          const float* __restrict__ bv, float* __restrict__ bqkv)
{
    int idx = blockIdx.x * 256 + threadIdx.x;
    if (idx >= 6144) return;
    int o = idx / 1536, n = idx % 1536;
    float v;
    if (n < 512) v = bq[o * 512 + n];
    else if (n < 1024) v = bk[o * 512 + n - 512];
    else v = bv[o * 512 + n - 1024];
    bqkv[idx] = v;
}

// ---------------------------------------------------------------------------
// Conv1d k=3 SAME over L (reads feats cols 0..255, writes cols 256..511)
// ---------------------------------------------------------------------------
__global__ __launch_bounds__(256) void conv_kernel(
    const float* __restrict__ feats, const float* __restrict__ w,
    const float* __restrict__ bias, float* __restrict__ fo)
{
    int bl = blockIdx.x; int b = bl / 400, l = bl % 400;
    int t = threadIdx.x;
    __shared__ float xr[768];
    #pragma unroll
    for (int dl = 0; dl < 3; ++dl) {
        int ls = l + dl - 1;
        float vv = 0.f;
        if (ls >= 0 && ls < 400) vv = feats[((long long)(b * 400 + ls)) * 512 + t];
        xr[dl * 256 + t] = vv;
    }
    __syncthreads();
    float acc = bias[t];
    #pragma unroll 4
    for (int j = 0; j < 768; ++j) acc += xr[j] * w[j * 256 + t];
    fo[((long long)bl) * 512 + 256 + t] = fmaxf(acc, 0.f);
}

__global__ void masks_kernel(const float* __restrict__ x, float* __restrict__ mk)
{
    int i = blockIdx.x * 256 + threadIdx.x;
    if (i >= 3200) return;
    const float* xr = x + (long long)i * 128;
    mk[0 * 3200 + i] = xr[4];
    mk[1 * 3200 + i] = fmaxf(xr[2], xr[3]);
    mk[2 * 3200 + i] = xr[0];
    mk[3 * 3200 + i] = xr[1];
}

// DeBERTa-v2 log-bucket rel index T[dd], dd=(l-m)+399 in [0,799)
__global__ void relidx_kernel(int* __restrict__ T)
{
    int i = blockIdx.x * blockDim.x + threadIdx.x;
    if (i >= 799) return;
    int rel = i - 399;
    int sgn = (rel > 0) - (rel < 0);
    int ab = (rel < 300 && rel > -300) ? 299 : (rel < 0 ? -rel : rel);
    long long bpos;
    if (ab <= 300) bpos = rel;
    else {
        double lp = ceil(log((double)ab / 300.0) / log(599.0 / 300.0) * 299.0) + 300.0;
        bpos = (long long)lp * sgn;
    }
    long long c2p = bpos + 600;
    c2p = c2p < 0 ? 0 : (c2p > 1199 ? 1199 : c2p);
    T[i] = (int)c2p;
}

// ---------------------------------------------------------------------------
// LayerNorm (eps 1e-7). RES: adds residual R.
// ---------------------------------------------------------------------------
template<bool RES>
__global__ __launch_bounds__(256) void ln_kernel(
    const float* __restrict__ X, const float* __restrict__ R,
    const float* __restrict__ g, const float* __restrict__ be,
    float* __restrict__ Y, int Hd)
{
    long long row = blockIdx.x;
    int t = threadIdx.x;
    __shared__ float buf[512];
    __shared__ float red[256];
    const float* x = X + row * Hd;
    float s = 0.f;
    for (int j = t; j < Hd; j += 256) {
        float vv = x[j];
        if (RES) vv += R[row * Hd + j];
        buf[j] = vv; s += vv;
    }
    red[t] = s; __syncthreads();
    for (int k = 128; k; k >>= 1) { if (t < k) red[t] += red[t + k]; __syncthreads(); }
    float mean = red[0] / (float)Hd;
    __syncthreads();
    float s2 = 0.f;
    for (int j = t; j < Hd; j += 256) { float d = buf[j] - mean; s2 += d * d; }
    red[t] = s2; __syncthreads();
    for (int k = 128; k; k >>= 1) { if (t < k) red[t] += red[t + k]; __syncthreads(); }
    float inv = 1.f / sqrtf(red[0] / (float)Hd + 1e-7f);
    for (int j = t; j < Hd; j += 256)
        Y[row * Hd + j] = (buf[j] - mean) * inv * g[j] + be[j];
}

// ---------------------------------------------------------------------------
// Fused disentangled attention (flash-style), fp32 SIMT.
// q/k/v packed in qkv with ld 1536 (q@0, k@512, v@1024).
// pq_g|pk_g packed in pkgpqg with ld 1024 (pq@0, pk@512).
// ---------------------------------------------------------------------------
__global__ __launch_bounds__(256) void attn_kernel(
    const float* __restrict__ qkv,
    const float* __restrict__ pkgpqg,
    const float* __restrict__ mask, float* __restrict__ ctx)
{
    const float scale = 0.07216878364870322f;       // 1/sqrt(64*3)
    const float NEGMIN = -3.402823466e38f;
    int lt = blockIdx.x, h = blockIdx.y, b = blockIdx.z;
    int l0 = lt * 32;
    int tid = threadIdx.x;
    int ty = tid >> 4, tx = tid & 15;
    int i0 = ty * 2;
    int j0 = tx * 2;

    __shared__ float Qs[32][68];
    __shared__ float Ks[32][68];
    __shared__ float Vs[32][68];
    __shared__ float PKs[63][68];
    __shared__ float PQs[63][68];
    __shared__ float St[32][34];
    __shared__ float mstate[32], lstate[32], corrs[32], wlv[32], wmv[32];

    for (int u = tid; u < 512; u += 256) {
        int r = u >> 4, c4 = (u & 15) << 2;
        float4 val = make_float4(0.f, 0.f, 0.f, 0.f);
        int lg = l0 + r;
        if (lg < 400) val = *(const float4*)&qkv[((long long)(b * 400 + lg)) * 1536 + h * 64 + c4];
        *(float4*)&Qs[r][c4] = val;
    }
    if (tid < 32) {
        int lg = l0 + tid;
        wlv[tid] = (lg < 400) ? mask[b * 400 + lg] : 0.f;
        mstate[tid] = -INFINITY;
        lstate[tid] = 0.f;
    }
    float O[2][4] = {};

    for (int mt = 0; mt < 13; ++mt) {
        int m0 = mt * 32;
        __syncthreads();
        for (int u = tid; u < 512; u += 256) {
            int r = u >> 4, c4 = (u & 15) << 2;
            int mg = m0 + r;
            float4 kv4 = make_float4(0.f, 0.f, 0.f, 0.f);
            float4 vv4 = make_float4(0.f, 0.f, 0.f, 0.f);
            if (mg < 400) {
                long long base = ((long long)(b * 400 + mg)) * 1536 + h * 64 + c4;
                kv4 = *(const float4*)&qkv[base + 512];
                vv4 = *(const float4*)&qkv[base + 1024];
            }
            *(float4*)&Ks[r][c4] = kv4;
            *(float4*)&Vs[r][c4] = vv4;
        }
        if (tid < 32) {
            int mg = m0 + tid;
            wmv[tid] = (mg < 400) ? mask[b * 400 + mg] : 0.f;
        }
        int D0 = l0 - m0 + 368;
        for (int u = tid; u < 63 * 16; u += 256) {
            int rr = u >> 4, c4 = (u & 15) << 2;
            int dd = D0 + rr;
            float4 a = make_float4(0.f, 0.f, 0.f, 0.f);
            float4 bb = make_float4(0.f, 0.f, 0.f, 0.f);
            if (dd >= 0 && dd < 799) {
                a  = *(const float4*)&pkgpqg[(long long)dd * 1024 + 512 + h * 64 + c4];
                bb = *(const float4*)&pkgpqg[(long long)dd * 1024 + h * 64 + c4];
            }
            *(float4*)&PKs[rr][c4] = a;
            *(float4*)&PQs[rr][c4] = bb;
        }
        __syncthreads();

        float acc00 = 0.f, acc01 = 0.f, acc10 = 0.f, acc11 = 0.f;
        int rb = (i0 - j0) + 31;
        #pragma unroll 4
        for (int d4 = 0; d4 < 16; ++d4) {
            int dc = d4 << 2;
            float4 qa0 = *(const float4*)&Qs[i0][dc];
            float4 qa1 = *(const float4*)&Qs[i0 + 1][dc];
            float4 kb0 = *(const float4*)&Ks[j0][dc];
            float4 kb1 = *(const float4*)&Ks[j0 + 1][dc];
            float4 pk0 = *(const float4*)&PKs[rb][dc];
            float4 pkm = *(const float4*)&PKs[rb - 1][dc];
            float4 pkp = *(const float4*)&PKs[rb + 1][dc];
            float4 pq0 = *(const float4*)&PQs[rb][dc];
            float4 pqm = *(const float4*)&PQs[rb - 1][dc];
            float4 pqp = *(const float4*)&PQs[rb + 1][dc];
            acc00 += qa0.x*(kb0.x + pk0.x) + kb0.x*pq0.x
                   + qa0.y*(kb0.y + pk0.y) + kb0.y*pq0.y
                   + qa0.z*(kb0.z + pk0.z) + kb0.z*pq0.z
                   + qa0.w*(kb0.w + pk0.w) + kb0.w*pq0.w;
            acc01 += qa0.x*(kb1.x + pkm.x) + kb1.x*pqm.x
                   + qa0.y*(kb1.y + pkm.y) + kb1.y*pqm.y
                   + qa0.z*(kb1.z + pkm.z) + kb1.z*pqm.z
                   + qa0.w*(kb1.w + pkm.w) + kb1.w*pqm.w;
            acc10 += qa1.x*(kb0.x + pkp.x) + kb0.x*pqp.x
                   + qa1.y*(kb0.y + pkp.y) + kb0.y*pqp.y
                   + qa1.z*(kb0.z + pkp.z) + kb0.z*pqp.z
                   + qa1.w*(kb0.w + pkp.w) + kb0.w*pqp.w;
            acc11 += qa1.x*(kb1.x + pk0.x) + kb1.x*pq0.x
                   + qa1.y*(kb1.y + pk0.y) + kb1.y*pq0.y
                   + qa1.z*(kb1.z + pk0.z) + kb1.z*pq0.z
                   + qa1.w*(kb1.w + pk0.w) + kb1.w*pq0.w;
        }
        float wl0 = wlv[i0], wl1 = wlv[i0 + 1];
        float wm0 = wmv[j0], wm1 = wmv[j0 + 1];
        bool jv0 = (m0 + j0) < 400, jv1 = (m0 + j0 + 1) < 400;
        float s00 = jv0 ? ((wl0 != 0.f && wm0 != 0.f) ? acc00 * scale : NEGMIN) : -INFINITY;
        float s01 = jv1 ? ((wl0 != 0.f && wm1 != 0.f) ? acc01 * scale : NEGMIN) : -INFINITY;
        float s10 = jv0 ? ((wl1 != 0.f && wm0 != 0.f) ? acc10 * scale : NEGMIN) : -INFINITY;
        float s11 = jv1 ? ((wl1 != 0.f && wm1 != 0.f) ? acc11 * scale : NEGMIN) : -INFINITY;
        St[j0][i0] = s00; St[j0][i0 + 1] = s10;
        St[j0 + 1][i0] = s01; St[j0 + 1][i0 + 1] = s11;
        __syncthreads();

        if (tid < 32) {
            int i = tid;
            float mtile = -INFINITY;
            for (int j = 0; j < 32; ++j) mtile = fmaxf(mtile, St[j][i]);
            float mo = mstate[i];
            float mn = fmaxf(mo, mtile);
            float corr = expf(mo - mn);
            float rs = 0.f;
            for (int j = 0; j < 32; ++j) {
                float p = expf(St[j][i] - mn);
                St[j][i] = p;
                rs += p;
            }
            lstate[i] = lstate[i] * corr + rs;
            mstate[i] = mn;
            corrs[i] = corr;
        }
        __syncthreads();

        float c0 = corrs[i0], c1 = corrs[i0 + 1];
        #pragma unroll
        for (int u = 0; u < 4; ++u) { O[0][u] *= c0; O[1][u] *= c1; }
        int dcol = tx << 2;
        #pragma unroll 8
        for (int kk = 0; kk < 32; ++kk) {
            float a0 = St[kk][i0], a1 = St[kk][i0 + 1];
            float4 bv = *(const float4*)&Vs[kk][dcol];
            O[0][0] += a0 * bv.x; O[0][1] += a0 * bv.y;
            O[0][2] += a0 * bv.z; O[0][3] += a0 * bv.w;
            O[1][0] += a1 * bv.x; O[1][1] += a1 * bv.y;
            O[1][2] += a1 * bv.z; O[1][3] += a1 * bv.w;
        }
    }
    int lg0 = l0 + i0;
    if (lg0 < 400) {
        float inv = 1.f / lstate[i0];
        float4 r = make_float4(O[0][0] * inv, O[0][1] * inv, O[0][2] * inv, O[0][3] * inv);
        *(float4*)&ctx[((long long)(b * 400 + lg0)) * 512 + h * 64 + (tx << 2)] = r;
    }
    if (lg0 + 1 < 400) {
        float inv = 1.f / lstate[i0 + 1];
        float4 r = make_float4(O[1][0] * inv, O[1][1] * inv, O[1][2] * inv, O[1][3] * inv);
        *(float4*)&ctx[((long long)(b * 400 + lg0 + 1)) * 512 + h * 64 + (tx << 2)] = r;
    }
}

// ---------------------------------------------------------------------------
// Pool / meanmax / heads
// ---------------------------------------------------------------------------
__global__ __launch_bounds__(256) void pool_kernel(
    const float* __restrict__ oenc, const float* __restrict__ mk,
    float* __restrict__ pooled)
{
    int b = blockIdx.x; int t = threadIdx.x;
    float acc = 0.f, mxv = -INFINITY, sw = 0.f;
    for (int l = 0; l < 400; ++l) {
        float w = mk[b * 400 + l];
        float vv = oenc[((long long)(b * 400 + l)) * 256 + t] * w;
        acc += vv; mxv = fmaxf(mxv, vv); sw += w;
    }
    pooled[b * 512 + t] = acc / (sw + 1e-6f);
    pooled[b * 512 + 256 + t] = mxv;
}

__global__ __launch_bounds__(512) void meanmax_kernel(
    const float* __restrict__ feats, float* __restrict__ mm)
{
    int b = blockIdx.x; int t = threadIdx.x;
    float s = 0.f, mx = -INFINITY;
    for (int l = 0; l < 400; ++l) {
        float vv = feats[((long long)(b * 400 + l)) * 512 + t];
        s += vv; mx = fmaxf(mx, vv);
    }
    mm[b * 1024 + t] = s / 400.f;
    mm[b * 1024 + 512 + t] = mx;
}

__global__ __launch_bounds__(256) void heads_kernel(
    const float* __restrict__ pooled, const float* __restrict__ mm,
    const float* __restrict__ w_bow1, const float* __restrict__ b_bow1,
    const float* __restrict__ w_bow2, const float* __restrict__ b_bow2,
    const float* __restrict__ w_ext1, const float* __restrict__ b_ext1,
    const float* __restrict__ w_ext2, const float* __restrict__ b_ext2,
    const float* __restrict__ w_org1, const float* __restrict__ b_org1,
    const float* __restrict__ w_org2, const float* __restrict__ b_org2,
    float* __restrict__ out)
{
    int b = blockIdx.x, role = blockIdx.y;
    int t = threadIdx.x;
    __shared__ float inb[1024];
    __shared__ float red[256];
    __shared__ float hid[256];
    if (role == 0) {
        inb[t] = pooled[b * 512 + t];
        inb[256 + t] = pooled[b * 512 + 256 + t];
        __syncthreads();
        float acc = b_bow1[t];
        for (int j = 0; j < 512; ++j) acc += inb[j] * w_bow1[j * 256 + t];
        red[t] = mishf(acc) * w_bow2[t];
        __syncthreads();
        for (int s = 128; s; s >>= 1) { if (t < s) red[t] += red[t + s]; __syncthreads(); }
        if (t == 0) out[b * 11 + 0] = red[0] + b_bow2[0];
    } else if (role == 1) {
        inb[t] = mm[b * 1024 + t];
        inb[256 + t] = mm[b * 1024 + 256 + t];
        inb[512 + t] = mm[b * 1024 + 512 + t];
        inb[768 + t] = mm[b * 1024 + 768 + t];
        __syncthreads();
        float acc = b_ext1[t];
        for (int j = 0; j < 1024; ++j) acc += inb[j] * w_ext1[j * 256 + t];
        red[t] = mishf(acc) * w_ext2[t];
        __syncthreads();
        for (int s = 128; s; s >>= 1) { if (t < s) red[t] += red[t + s]; __syncthreads(); }
        if (t == 0) { out[b * 11 + 1] = red[0] + b_ext2[0]; out[88 + b] = 0.f; }
    } else {
        int i = role - 2;
        inb[t] = pooled[((1 + i) * 8 + b) * 512 + t];
        inb[256 + t] = pooled[((1 + i) * 8 + b) * 512 + 256 + t];
        __syncthreads();
        float acc = b_org1[i * 256 + t];
        for (int j = 0; j < 512; ++j)
            acc += inb[j] * w_org1[((long long)i * 512 + j) * 256 + t];
        hid[t] = mishf(acc);
        __syncthreads();
        for (int c = 0; c < 3; ++c) {
            red[t] = hid[t] * w_org2[(i * 256 + t) * 3 + c];
            __syncthreads();
            for (int s = 128; s; s >>= 1) { if (t < s) red[t] += red[t + s]; __syncthreads(); }
            if (t == 0) out[b * 11 + 2 + i * 3 + c] = red[0] + b_org2[i * 3 + c];
            __syncthreads();
        }
    }
}

// ---------------------------------------------------------------------------
// Launch
// ---------------------------------------------------------------------------
extern "C" void kernel_launch(void* const* d_in, const int* in_sizes, int n_in,
                              void* d_out, int out_size, void* d_ws, size_t ws_size,
                              hipStream_t stream)
{
    const float* x      = (const float*)d_in[0];
    const float* w_mlp  = (const float*)d_in[1];
    const float* b_mlp  = (const float*)d_in[2];
    const float* w_cnn  = (const float*)d_in[3];
    const float* b_cnn  = (const float*)d_in[4];
    const float* rel_emb= (const float*)d_in[5];
    const float* rel_g  = (const float*)d_in[6];
    const float* rel_b  = (const float*)d_in[7];
    const float* wq     = (const float*)d_in[8];
    const float* wk     = (const float*)d_in[9];
    const float* wv     = (const float*)d_in[10];
    const float* wo     = (const float*)d_in[11];
    const float* wi     = (const float*)d_in[12];
    const float* bq     = (const float*)d_in[13];
    const float* bk     = (const float*)d_in[14];
    const float* bv     = (const float*)d_in[15];
    const float* bo     = (const float*)d_in[16];
    const float* bi     = (const float*)d_in[17];
    const float* wout   = (const float*)d_in[18];
    const float* bout   = (const float*)d_in[19];
    const float* ln1g   = (const float*)d_in[20];
    const float* ln1b   = (const float*)d_in[21];
    const float* ln2g   = (const float*)d_in[22];
    const float* ln2b   = (const float*)d_in[23];
    const float* w_bow1 = (const float*)d_in[24];
    const float* b_bow1 = (const float*)d_in[25];
    const float* w_bow2 = (const float*)d_in[26];
    const float* b_bow2 = (const float*)d_in[27];
    const float* w_ext1 = (const float*)d_in[28];
    const float* b_ext1 = (const float*)d_in[29];
    const float* w_ext2 = (const float*)d_in[30];
    const float* b_ext2 = (const float*)d_in[31];
    const float* w_org1 = (const float*)d_in[32];
    const float* b_org1 = (const float*)d_in[33];
    const float* w_org2 = (const float*)d_in[34];
    const float* b_org2 = (const float*)d_in[35];

    float* ws = (float*)d_ws;
    // workspace layout (float offsets), total ~10.46M floats = 41.8 MB
    float* featsb  = ws + 0;          // 1,638,400
    float* qkvT    = ws + 1638400;    // 4,915,200 (qkv / tmp_wo / inter)
    float* ctxB    = ws + 6553600;    // 1,638,400 (ctx / h1 / outenc@0 / outln@819200)
    float* rellnb  = ws + 8192000;    //   614,400
    float* pkgpqg  = ws + 8806400;    //   818,176 (799 x 1024: pq@0, pk@512)
    unsigned short* whi = (unsigned short*)(ws + 9624800);  // 786,432 ushort
    unsigned short* wlo = whi + 786432;                     // 786,432 ushort
    float* bqkvb   = ws + 10411232;   //     6,144
    float* masksb  = ws + 10417376;   //    12,800
    float* pooledb = ws + 10430176;   //    16,384
    float* mmb     = ws + 10446560;   //     8,192
    int*   relidx  = (int*)(ws + 10454752); // 800 ints
    float* outf    = (float*)d_out;

    // front
    gemm_bias<1><<<dim3(4, 50), 256, 0, stream>>>(x, w_mlp, b_mlp, featsb,
                                                  3200, 256, 128, 512);
    conv_kernel<<<3200, 256, 0, stream>>>(featsb, w_cnn, b_cnn, featsb);
    masks_kernel<<<13, 256, 0, stream>>>(x, masksb);
    relidx_kernel<<<4, 256, 0, stream>>>(relidx);
    pack_bqkv<<<24, 256, 0, stream>>>(bq, bk, bv, bqkvb);

    for (int o = 0; o < 4; ++o) {
        // rel layernorm
        ln_kernel<false><<<1200, 256, 0, stream>>>(rel_emb + (long long)o * 614400,
            nullptr, rel_g + o * 512, rel_b + o * 512, rellnb, 512);
        // weight prep (qkv pack, [1536][512] hi/lo)
        prep_wqkv<<<3072, 256, 0, stream>>>(wq, wk, wv, whi, wlo, o);
        // PQK: gathered rel projections -> pkgpqg[799][1024] (pq|pk)
        gemm_mfma<0, true><<<dim3(8, 13), 256, 0, stream>>>(
            rellnb, whi, wlo, bqkvb + o * 1536, pkgpqg, 799, 512, 1024, relidx);
        // QKV: feats -> qkv [3200][1536]
        gemm_mfma<0, false><<<dim3(12, 50), 256, 0, stream>>>(
            featsb, whi, wlo, bqkvb + o * 1536, qkvT, 3200, 512, 1536, nullptr);
        // weight prep for wo/wi/wout (overwrites whi/wlo)
        prep_woiw<<<2560, 256, 0, stream>>>(wo, wi, wout, whi, wlo, o);
        // fused attention
        attn_kernel<<<dim3(13, 8, 8), 256, 0, stream>>>(qkvT, pkgpqg,
                                                        masksb + o * 3200, ctxB);
        // WO: ctx @ wo -> qkvT (tmp)
        gemm_mfma<0, false><<<dim3(4, 50), 256, 0, stream>>>(
            ctxB, whi, wlo, bo + o * 512, qkvT, 3200, 512, 512, nullptr);
        // LN1(tmp + feats) -> ctxB (h1)
        ln_kernel<true><<<3200, 256, 0, stream>>>(qkvT, featsb, ln1g + o * 512,
                                                  ln1b + o * 512, ctxB, 512);
        // WI (mish): h1 @ wi -> qkvT (inter)
        gemm_mfma<1, false><<<dim3(4, 50), 256, 0, stream>>>(
            ctxB, whi + 262144, wlo + 262144, bi + o * 512, qkvT, 3200, 512, 512, nullptr);
        // WOUT: inter @ wout -> ctxB (outenc, [3200][256])
        gemm_mfma<0, false><<<dim3(2, 50), 256, 0, stream>>>(
            qkvT, whi + 524288, wlo + 524288, bout + o * 256, ctxB, 3200, 512, 256, nullptr);
        // LN2 -> ctxB+819200
        ln_kernel<false><<<3200, 256, 0, stream>>>(ctxB, nullptr, ln2g + o * 256,
                                                   ln2b + o * 256, ctxB + 819200, 256);
        // pooling
        pool_kernel<<<8, 256, 0, stream>>>(ctxB + 819200, masksb + o * 3200,
                                           pooledb + o * 4096);
    }

    meanmax_kernel<<<8, 512, 0, stream>>>(featsb, mmb);
    heads_kernel<<<dim3(8, 5), 256, 0, stream>>>(pooledb, mmb,
        w_bow1, b_bow1, w_bow2, b_bow2, w_ext1, b_ext1, w_ext2, b_ext2,
        w_org1, b_org1, w_org2, b_org2, outf);
}

// Round 3
// 1682.287 us; speedup vs baseline: 1.5932x; 1.1511x over previous
//
#include <hip/hip_runtime.h>
#include <math.h>

// ---------------------------------------------------------------------------
// Model dims (fixed): B=8 L=400 F=128 D=256 T=256 H=512 NH=8 HD=64 P=1200
// ---------------------------------------------------------------------------

typedef __attribute__((ext_vector_type(8))) short bf16x8;
typedef __attribute__((ext_vector_type(4))) float f32x4;
typedef __attribute__((ext_vector_type(4))) unsigned int u32x4;

__device__ __forceinline__ float mishf(float x) {
    float sp = fmaxf(x, 0.f) + log1pf(expf(-fabsf(x)));   // stable softplus
    return x * tanhf(sp);
}

__device__ __forceinline__ unsigned short f2bf(float f) {
    unsigned int u = __float_as_uint(f);
    u = (u + 0x7fffu + ((u >> 16) & 1u)) >> 16;           // RNE
    return (unsigned short)u;
}
__device__ __forceinline__ float bf2f(unsigned short h) {
    return __uint_as_float(((unsigned int)h) << 16);
}

__device__ __forceinline__ bf16x8 load_bf8(const unsigned short* p, bool valid) {
    bf16x8 z = {0, 0, 0, 0, 0, 0, 0, 0};
    if (valid) z = *(const bf16x8*)p;
    return z;
}

// ---------------------------------------------------------------------------
// fp32 GEMM (front MLP, K=128)
// ---------------------------------------------------------------------------
template<int EPI>
__global__ __launch_bounds__(256) void gemm_bias(
    const float* __restrict__ A, const float* __restrict__ Bm,
    const float* __restrict__ bias, float* __restrict__ C,
    int M, int N, int K, int ldc)
{
    __shared__ float As[16][68];
    __shared__ float Bs[16][68];
    int bm = blockIdx.y << 6, bn = blockIdx.x << 6;
    int tid = threadIdx.x;
    int tm = (tid >> 4) << 2, tn = (tid & 15) << 2;
    int ar = tid >> 2, ac4 = (tid & 3) << 2;
    int br = tid >> 4, bc4 = (tid & 15) << 2;
    float acc[4][4] = {};
    for (int k0 = 0; k0 < K; k0 += 16) {
        float4 av = make_float4(0.f, 0.f, 0.f, 0.f);
        if (bm + ar < M)
            av = *(const float4*)&A[(long long)(bm + ar) * K + k0 + ac4];
        As[ac4][ar] = av.x; As[ac4 + 1][ar] = av.y;
        As[ac4 + 2][ar] = av.z; As[ac4 + 3][ar] = av.w;
        *(float4*)&Bs[br][bc4] =
            *(const float4*)&Bm[(long long)(k0 + br) * N + bn + bc4];
        __syncthreads();
        #pragma unroll
        for (int kk = 0; kk < 16; ++kk) {
            float4 a4 = *(const float4*)&As[kk][tm];
            float4 b4 = *(const float4*)&Bs[kk][tn];
            acc[0][0] += a4.x * b4.x; acc[0][1] += a4.x * b4.y;
            acc[0][2] += a4.x * b4.z; acc[0][3] += a4.x * b4.w;
            acc[1][0] += a4.y * b4.x; acc[1][1] += a4.y * b4.y;
            acc[1][2] += a4.y * b4.z; acc[1][3] += a4.y * b4.w;
            acc[2][0] += a4.z * b4.x; acc[2][1] += a4.z * b4.y;
            acc[2][2] += a4.z * b4.z; acc[2][3] += a4.z * b4.w;
            acc[3][0] += a4.w * b4.x; acc[3][1] += a4.w * b4.y;
            acc[3][2] += a4.w * b4.z; acc[3][3] += a4.w * b4.w;
        }
        __syncthreads();
    }
    #pragma unroll
    for (int i = 0; i < 4; ++i) {
        int r = bm + tm + i;
        if (r < M) {
            float v0 = acc[i][0] + bias[bn + tn + 0];
            float v1 = acc[i][1] + bias[bn + tn + 1];
            float v2 = acc[i][2] + bias[bn + tn + 2];
            float v3 = acc[i][3] + bias[bn + tn + 3];
            if (EPI == 1) { v0 = mishf(v0); v1 = mishf(v1); v2 = mishf(v2); v3 = mishf(v3); }
            float4 o; o.x = v0; o.y = v1; o.z = v2; o.w = v3;
            *(float4*)&C[(long long)r * ldc + bn + tn] = o;
        }
    }
}

// ---------------------------------------------------------------------------
// MFMA bf16x3-split GEMM. B pre-transposed+split [N][K] bf16 hi/lo.
// Tile 64(M) x 128(N), BK=32, 4 waves (2x2), 2x4 frags 16x16x32, x3 split.
// GATHER: A-row remap. SPLIT: write hi/lo bf16 for cols<nhl (ld ldhl),
//   fp32 to C[(col-voff)] (ld ldc) for cols>=voff. Else: fp32 C (+EPI mish).
// ---------------------------------------------------------------------------
template<int EPI, bool GATHER, bool SPLIT>
__global__ __launch_bounds__(256) void gemm_mfma(
    const float* __restrict__ A,
    const unsigned short* __restrict__ Bth, const unsigned short* __restrict__ Btl,
    const float* __restrict__ bias, float* __restrict__ C,
    int M, int K, int ldc, const int* __restrict__ gidx,
    unsigned short* __restrict__ Chi, unsigned short* __restrict__ Clo,
    int ldhl, int nhl, int voff)
{
    __shared__ unsigned short Ah[64 * 40];
    __shared__ unsigned short Al[64 * 40];
    __shared__ unsigned short Bh[128 * 40];
    __shared__ unsigned short Bl[128 * 40];

    int bm = blockIdx.y << 6, bn = blockIdx.x << 7;
    int tid = threadIdx.x;
    int lane = tid & 63, wid = tid >> 6;
    int wm = wid >> 1, wn = wid & 1;
    int fr = lane & 15, kg = (lane >> 4) << 3;

    int ar = tid >> 2, akc = (tid & 3) << 3;
    int bnr = tid >> 1, bkc = (tid & 1) << 4;

    long long arow; bool avalid;
    {
        int gr = bm + ar;
        avalid = gr < M;
        if (GATHER) arow = avalid ? (long long)gidx[gr] : 0;
        else        arow = avalid ? (long long)gr : 0;
    }

    f32x4 acc[2][4] = {};

    for (int k0 = 0; k0 < K; k0 += 32) {
        float vv[8];
        if (avalid) {
            float4 v0 = *(const float4*)&A[arow * K + k0 + akc];
            float4 v1 = *(const float4*)&A[arow * K + k0 + akc + 4];
            vv[0] = v0.x; vv[1] = v0.y; vv[2] = v0.z; vv[3] = v0.w;
            vv[4] = v1.x; vv[5] = v1.y; vv[6] = v1.z; vv[7] = v1.w;
        } else {
            #pragma unroll
            for (int e = 0; e < 8; ++e) vv[e] = 0.f;
        }
        union { unsigned short u[8]; u32x4 v; } ph, pl;
        #pragma unroll
        for (int e = 0; e < 8; ++e) {
            unsigned short h = f2bf(vv[e]);
            ph.u[e] = h;
            pl.u[e] = f2bf(vv[e] - bf2f(h));
        }
        *(u32x4*)&Ah[ar * 40 + akc] = ph.v;
        *(u32x4*)&Al[ar * 40 + akc] = pl.v;

        {
            long long boff = (long long)(bn + bnr) * K + k0 + bkc;
            *(u32x4*)&Bh[bnr * 40 + bkc]     = *(const u32x4*)&Bth[boff];
            *(u32x4*)&Bh[bnr * 40 + bkc + 8] = *(const u32x4*)&Bth[boff + 8];
            *(u32x4*)&Bl[bnr * 40 + bkc]     = *(const u32x4*)&Btl[boff];
            *(u32x4*)&Bl[bnr * 40 + bkc + 8] = *(const u32x4*)&Btl[boff + 8];
        }
        __syncthreads();

        bf16x8 af[2], alf[2], bfj[4], blf[4];
        #pragma unroll
        for (int i = 0; i < 2; ++i) {
            int row = wm * 32 + i * 16 + fr;
            af[i]  = *(const bf16x8*)&Ah[row * 40 + kg];
            alf[i] = *(const bf16x8*)&Al[row * 40 + kg];
        }
        #pragma unroll
        for (int j = 0; j < 4; ++j) {
            int row = wn * 64 + j * 16 + fr;
            bfj[j] = *(const bf16x8*)&Bh[row * 40 + kg];
            blf[j] = *(const bf16x8*)&Bl[row * 40 + kg];
        }
        #pragma unroll
        for (int i = 0; i < 2; ++i)
        #pragma unroll
        for (int j = 0; j < 4; ++j) {
            acc[i][j] = __builtin_amdgcn_mfma_f32_16x16x32_bf16(af[i],  bfj[j], acc[i][j], 0, 0, 0);
            acc[i][j] = __builtin_amdgcn_mfma_f32_16x16x32_bf16(af[i],  blf[j], acc[i][j], 0, 0, 0);
            acc[i][j] = __builtin_amdgcn_mfma_f32_16x16x32_bf16(alf[i], bfj[j], acc[i][j], 0, 0, 0);
        }
        __syncthreads();
    }

    #pragma unroll
    for (int i = 0; i < 2; ++i) {
        int rbase = bm + wm * 32 + i * 16 + ((lane >> 4) << 2);
        #pragma unroll
        for (int j = 0; j < 4; ++j) {
            int ccol = bn + wn * 64 + j * 16 + fr;
            float bv = bias[ccol];
            #pragma unroll
            for (int r = 0; r < 4; ++r) {
                int row = rbase + r;
                if (row < M) {
                    float val = acc[i][j][r] + bv;
                    if (SPLIT) {
                        if (ccol < nhl) {
                            unsigned short hh = f2bf(val);
                            Chi[(long long)row * ldhl + ccol] = hh;
                            Clo[(long long)row * ldhl + ccol] = f2bf(val - bf2f(hh));
                        } else {
                            C[(long long)row * ldc + (ccol - voff)] = val;
                        }
                    } else {
                        if (EPI == 1) val = mishf(val);
                        C[(long long)row * ldc + ccol] = val;
                    }
                }
            }
        }
    }
}

// ---------------------------------------------------------------------------
// Weight prep: transpose + split to bf16 hi/lo, [N][K] layout.
// ---------------------------------------------------------------------------
__global__ __launch_bounds__(256) void prep_wqkv(
    const float* __restrict__ wq, const float* __restrict__ wk,
    const float* __restrict__ wv,
    unsigned short* __restrict__ whi, unsigned short* __restrict__ wlo, int o)
{
    int idx = blockIdx.x * 256 + threadIdx.x;
    if (idx >= 1536 * 512) return;
    int k = idx / 1536, n = idx % 1536;
    int sel = n >> 9, col = n & 511;
    const float* W = sel == 0 ? wq : (sel == 1 ? wk : wv);
    float v = W[(long long)o * 262144 + k * 512 + col];
    unsigned short h = f2bf(v);
    whi[n * 512 + k] = h;
    wlo[n * 512 + k] = f2bf(v - bf2f(h));
}

__global__ __launch_bounds__(256) void prep_woiw(
    const float* __restrict__ wo, const float* __restrict__ wi,
    const float* __restrict__ wout,
    unsigned short* __restrict__ whi, unsigned short* __restrict__ wlo, int o)
{
    int idx = blockIdx.x * 256 + threadIdx.x;
    if (idx >= 655360) return;
    const float* W; int N, nk, base;
    if (idx < 262144)      { W = wo + (long long)o * 262144; N = 512; nk = idx; base = 0; }
    else if (idx < 524288) { W = wi + (long long)o * 262144; N = 512; nk = idx - 262144; base = 262144; }
    else                   { W = wout + (long long)o * 131072; N = 256; nk = idx - 524288; base = 524288; }
    int k = nk / N, n = nk % N;
    float v = W[k * N + n];
    unsigned short h = f2bf(v);
    whi[base + n * 512 + k] = h;
    wlo[base + n * 512 + k] = f2bf(v - bf2f(h));
}

__global__ void pack_bqkv(const float* __restrict__ bq, const float* __restrict__ bk,
                          const float* __restrict__ bv, float* __restrict__ bqkv)
{
    int idx = blockIdx.x * 256 + threadIdx.x;
    if (idx >= 6144) return;
    int o = idx / 1536, n = idx % 1536;
    float v;
    if (n < 512) v = bq[o * 512 + n];
    else if (n < 1024) v = bk[o * 512 + n - 512];
    else v = bv[o * 512 + n - 1024];
    bqkv[idx] = v;
}

// ---------------------------------------------------------------------------
// Conv1d k=3 SAME
// ---------------------------------------------------------------------------
__global__ __launch_bounds__(256) void conv_kernel(
    const float* __restrict__ feats, const float* __restrict__ w,
    const float* __restrict__ bias, float* __restrict__ fo)
{
    int bl = blockIdx.x; int b = bl / 400, l = bl % 400;
    int t = threadIdx.x;
    __shared__ float xr[768];
    #pragma unroll
    for (int dl = 0; dl < 3; ++dl) {
        int ls = l + dl - 1;
        float vv = 0.f;
        if (ls >= 0 && ls < 400) vv = feats[((long long)(b * 400 + ls)) * 512 + t];
        xr[dl * 256 + t] = vv;
    }
    __syncthreads();
    float acc = bias[t];
    #pragma unroll 4
    for (int j = 0; j < 768; ++j) acc += xr[j] * w[j * 256 + t];
    fo[((long long)bl) * 512 + 256 + t] = fmaxf(acc, 0.f);
}

__global__ void masks_kernel(const float* __restrict__ x, float* __restrict__ mk)
{
    int i = blockIdx.x * 256 + threadIdx.x;
    if (i >= 3200) return;
    const float* xr = x + (long long)i * 128;
    mk[0 * 3200 + i] = xr[4];
    mk[1 * 3200 + i] = fmaxf(xr[2], xr[3]);
    mk[2 * 3200 + i] = xr[0];
    mk[3 * 3200 + i] = xr[1];
}

__global__ void relidx_kernel(int* __restrict__ T)
{
    int i = blockIdx.x * blockDim.x + threadIdx.x;
    if (i >= 799) return;
    int rel = i - 399;
    int sgn = (rel > 0) - (rel < 0);
    int ab = (rel < 300 && rel > -300) ? 299 : (rel < 0 ? -rel : rel);
    long long bpos;
    if (ab <= 300) bpos = rel;
    else {
        double lp = ceil(log((double)ab / 300.0) / log(599.0 / 300.0) * 299.0) + 300.0;
        bpos = (long long)lp * sgn;
    }
    long long c2p = bpos + 600;
    c2p = c2p < 0 ? 0 : (c2p > 1199 ? 1199 : c2p);
    T[i] = (int)c2p;
}

// ---------------------------------------------------------------------------
// LayerNorm (eps 1e-7)
// ---------------------------------------------------------------------------
template<bool RES>
__global__ __launch_bounds__(256) void ln_kernel(
    const float* __restrict__ X, const float* __restrict__ R,
    const float* __restrict__ g, const float* __restrict__ be,
    float* __restrict__ Y, int Hd)
{
    long long row = blockIdx.x;
    int t = threadIdx.x;
    __shared__ float buf[512];
    __shared__ float red[256];
    const float* x = X + row * Hd;
    float s = 0.f;
    for (int j = t; j < Hd; j += 256) {
        float vv = x[j];
        if (RES) vv += R[row * Hd + j];
        buf[j] = vv; s += vv;
    }
    red[t] = s; __syncthreads();
    for (int k = 128; k; k >>= 1) { if (t < k) red[t] += red[t + k]; __syncthreads(); }
    float mean = red[0] / (float)Hd;
    __syncthreads();
    float s2 = 0.f;
    for (int j = t; j < Hd; j += 256) { float d = buf[j] - mean; s2 += d * d; }
    red[t] = s2; __syncthreads();
    for (int k = 128; k; k >>= 1) { if (t < k) red[t] += red[t + k]; __syncthreads(); }
    float inv = 1.f / sqrtf(red[0] / (float)Hd + 1e-7f);
    for (int j = t; j < Hd; j += 256)
        Y[row * Hd + j] = (buf[j] - mean) * inv * g[j] + be[j];
}

// ---------------------------------------------------------------------------
// MFMA fused disentangled flash attention.
// Block = (l-tile 32, head, batch), 256 thr = 4 waves.
// T1 = Q@K^T (32x32), T2 = Q@PKband^T (32x64), T3 = K@PQband^T (32x64),
// score(i,j) = (T1[i][j] + T2[i][i-j+31] + T3[j][i-j+31])*scale.
// Q/K from pre-split bf16 hi/lo (x3 MFMA); V fp32; softmax+PV SIMT.
// qk_hi/lo: [3200][1024] (q@0,k@512). pkg_hi/lo: [799][1024] (pq@0,pk@512).
// ---------------------------------------------------------------------------
__global__ __launch_bounds__(256) void attn_kernel(
    const unsigned short* __restrict__ qk_hi, const unsigned short* __restrict__ qk_lo,
    const float* __restrict__ vbuf,
    const unsigned short* __restrict__ pkg_hi, const unsigned short* __restrict__ pkg_lo,
    const float* __restrict__ mask, float* __restrict__ ctx)
{
    const float scale = 0.07216878364870322f;       // 1/sqrt(64*3)
    const float NEGMIN = -3.402823466e38f;
    int lt = blockIdx.x, h = blockIdx.y, b = blockIdx.z;
    int l0 = lt * 32;
    int tid = threadIdx.x;
    int lane = tid & 63, w = tid >> 6;
    int wrf = w >> 1;      // Q row-frag (T1/T2 rows)
    int wcf = w & 1;       // K row-frag (T1 cols / T3 rows)
    int fr = lane & 15, kg8 = (lane >> 4) << 3;

    __shared__ unsigned short Kh[32 * 72], Kl[32 * 72];
    __shared__ float Vs[32 * 68];
    __shared__ float T2s[32 * 68], T3s[32 * 68];
    __shared__ float St[32 * 33];
    __shared__ float mstate[32], lstate[32], corrs[32], wlv[32], wmv[32];

    // Q frags: registers, loaded once from global (valid rows only)
    bf16x8 qfh[2], qfl[2];
    {
        int qi = l0 + wrf * 16 + fr;
        bool valid = qi < 400;
        long long base = ((long long)(b * 400 + (valid ? qi : 0))) * 1024 + h * 64 + kg8;
        #pragma unroll
        for (int kk = 0; kk < 2; ++kk) {
            qfh[kk] = load_bf8(qk_hi + base + kk * 32, valid);
            qfl[kk] = load_bf8(qk_lo + base + kk * 32, valid);
        }
    }
    if (tid < 32) {
        int lg = l0 + tid;
        wlv[tid] = (lg < 400) ? mask[b * 400 + lg] : 0.f;
        mstate[tid] = -INFINITY;
        lstate[tid] = 0.f;
    }
    float O[2][4] = {};
    int ty = tid >> 4, tx = tid & 15, i0 = ty * 2;

    for (int mt = 0; mt < 13; ++mt) {
        int m0 = mt * 32;
        int D0 = l0 - m0 + 368;
        __syncthreads();
        // stage K hi/lo (row, 8-ushort segment per thread)
        {
            int row = tid >> 3, seg = (tid & 7) << 3;
            bool valid = (m0 + row) < 400;
            long long src = ((long long)(b * 400 + (valid ? m0 + row : 0))) * 1024 + 512 + h * 64 + seg;
            bf16x8 vh = load_bf8(qk_hi + src, valid);
            bf16x8 vl = load_bf8(qk_lo + src, valid);
            *(bf16x8*)&Kh[row * 72 + seg] = vh;
            *(bf16x8*)&Kl[row * 72 + seg] = vl;
        }
        // stage V fp32
        #pragma unroll
        for (int p = 0; p < 2; ++p) {
            int it = tid + p * 256;
            int row = it >> 4, seg = (it & 15) << 2;
            float4 vv = make_float4(0.f, 0.f, 0.f, 0.f);
            if (m0 + row < 400)
                vv = *(const float4*)&vbuf[((long long)(b * 400 + m0 + row)) * 512 + h * 64 + seg];
            *(float4*)&Vs[row * 68 + seg] = vv;
        }
        if (tid < 32) wmv[tid] = (m0 + tid < 400) ? mask[b * 400 + m0 + tid] : 0.f;
        __syncthreads();

        // K frags from LDS (used as T1-B and T3-A)
        bf16x8 kfh[2], kfl[2];
        #pragma unroll
        for (int kk = 0; kk < 2; ++kk) {
            kfh[kk] = *(const bf16x8*)&Kh[(wcf * 16 + fr) * 72 + kk * 32 + kg8];
            kfl[kk] = *(const bf16x8*)&Kl[(wcf * 16 + fr) * 72 + kk * 32 + kg8];
        }
        // T1
        f32x4 aT1 = {};
        #pragma unroll
        for (int kk = 0; kk < 2; ++kk) {
            aT1 = __builtin_amdgcn_mfma_f32_16x16x32_bf16(qfh[kk], kfh[kk], aT1, 0, 0, 0);
            aT1 = __builtin_amdgcn_mfma_f32_16x16x32_bf16(qfh[kk], kfl[kk], aT1, 0, 0, 0);
            aT1 = __builtin_amdgcn_mfma_f32_16x16x32_bf16(qfl[kk], kfh[kk], aT1, 0, 0, 0);
        }
        // T2 (A=Q, B=PK band) and T3 (A=K, B=PQ band); band frags from global (L2)
        f32x4 aT2[2] = {{0.f,0.f,0.f,0.f},{0.f,0.f,0.f,0.f}};
        f32x4 aT3[2] = {{0.f,0.f,0.f,0.f},{0.f,0.f,0.f,0.f}};
        #pragma unroll
        for (int c = 0; c < 2; ++c) {
            int cf2 = 2 * wcf + c;
            int cf3 = 2 * wrf + c;
            #pragma unroll
            for (int kk = 0; kk < 2; ++kk) {
                int row2 = D0 + cf2 * 16 + fr;
                bool v2 = (unsigned)row2 < 799u;
                long long b2 = (long long)(v2 ? row2 : 0) * 1024 + 512 + h * 64 + kk * 32 + kg8;
                bf16x8 bh = load_bf8(pkg_hi + b2, v2);
                bf16x8 bl = load_bf8(pkg_lo + b2, v2);
                aT2[c] = __builtin_amdgcn_mfma_f32_16x16x32_bf16(qfh[kk], bh, aT2[c], 0, 0, 0);
                aT2[c] = __builtin_amdgcn_mfma_f32_16x16x32_bf16(qfh[kk], bl, aT2[c], 0, 0, 0);
                aT2[c] = __builtin_amdgcn_mfma_f32_16x16x32_bf16(qfl[kk], bh, aT2[c], 0, 0, 0);
                int row3 = D0 + cf3 * 16 + fr;
                bool v3 = (unsigned)row3 < 799u;
                long long b3 = (long long)(v3 ? row3 : 0) * 1024 + h * 64 + kk * 32 + kg8;
                bf16x8 ch = load_bf8(pkg_hi + b3, v3);
                bf16x8 cl = load_bf8(pkg_lo + b3, v3);
                aT3[c] = __builtin_amdgcn_mfma_f32_16x16x32_bf16(kfh[kk], ch, aT3[c], 0, 0, 0);
                aT3[c] = __builtin_amdgcn_mfma_f32_16x16x32_bf16(kfh[kk], cl, aT3[c], 0, 0, 0);
                aT3[c] = __builtin_amdgcn_mfma_f32_16x16x32_bf16(kfl[kk], ch, aT3[c], 0, 0, 0);
            }
        }
        // write T2/T3 frags to LDS
        {
            int rB2 = wrf * 16 + ((lane >> 4) << 2);
            int rB3 = wcf * 16 + ((lane >> 4) << 2);
            #pragma unroll
            for (int c = 0; c < 2; ++c) {
                int cc2 = (2 * wcf + c) * 16 + fr;
                int cc3 = (2 * wrf + c) * 16 + fr;
                #pragma unroll
                for (int r = 0; r < 4; ++r) {
                    T2s[(rB2 + r) * 68 + cc2] = aT2[c][r];
                    T3s[(rB3 + r) * 68 + cc3] = aT3[c][r];
                }
            }
        }
        __syncthreads();
        // assemble scores -> St[j*33+i]
        {
            int ib = wrf * 16 + ((lane >> 4) << 2);
            int j  = wcf * 16 + fr;
            bool jv = (m0 + j) < 400;
            float wm = wmv[j];
            #pragma unroll
            for (int r = 0; r < 4; ++r) {
                int i = ib + r;
                int rr = i - j + 31;
                float s;
                if (!jv) s = -INFINITY;
                else if (wlv[i] != 0.f && wm != 0.f)
                    s = (aT1[r] + T2s[i * 68 + rr] + T3s[j * 68 + rr]) * scale;
                else s = NEGMIN;
                St[j * 33 + i] = s;
            }
        }
        __syncthreads();
        // flash softmax per l-row
        if (tid < 32) {
            int i = tid;
            float mtile = -INFINITY;
            for (int j = 0; j < 32; ++j) mtile = fmaxf(mtile, St[j * 33 + i]);
            float mo = mstate[i];
            float mn = fmaxf(mo, mtile);
            float corr = expf(mo - mn);
            float rs = 0.f;
            for (int j = 0; j < 32; ++j) {
                float p = expf(St[j * 33 + i] - mn);
                St[j * 33 + i] = p;
                rs += p;
            }
            lstate[i] = lstate[i] * corr + rs;
            mstate[i] = mn;
            corrs[i] = corr;
        }
        __syncthreads();
        // PV (SIMT)
        float c0 = corrs[i0], c1 = corrs[i0 + 1];
        #pragma unroll
        for (int u = 0; u < 4; ++u) { O[0][u] *= c0; O[1][u] *= c1; }
        int dcol = tx << 2;
        #pragma unroll 8
        for (int kk2 = 0; kk2 < 32; ++kk2) {
            float a0 = St[kk2 * 33 + i0], a1 = St[kk2 * 33 + i0 + 1];
            float4 bv = *(const float4*)&Vs[kk2 * 68 + dcol];
            O[0][0] += a0 * bv.x; O[0][1] += a0 * bv.y;
            O[0][2] += a0 * bv.z; O[0][3] += a0 * bv.w;
            O[1][0] += a1 * bv.x; O[1][1] += a1 * bv.y;
            O[1][2] += a1 * bv.z; O[1][3] += a1 * bv.w;
        }
    }
    int lg0 = l0 + i0;
    if (lg0 < 400) {
        float inv = 1.f / lstate[i0];
        *(float4*)&ctx[((long long)(b * 400 + lg0)) * 512 + h * 64 + (tx << 2)] =
            make_float4(O[0][0] * inv, O[0][1] * inv, O[0][2] * inv, O[0][3] * inv);
    }
    if (lg0 + 1 < 400) {
        float inv = 1.f / lstate[i0 + 1];
        *(float4*)&ctx[((long long)(b * 400 + lg0 + 1)) * 512 + h * 64 + (tx << 2)] =
            make_float4(O[1][0] * inv, O[1][1] * inv, O[1][2] * inv, O[1][3] * inv);
    }
}

// ---------------------------------------------------------------------------
// Pool / meanmax / heads
// ---------------------------------------------------------------------------
__global__ __launch_bounds__(256) void pool_kernel(
    const float* __restrict__ oenc, const float* __restrict__ mk,
    float* __restrict__ pooled)
{
    int b = blockIdx.x; int t = threadIdx.x;
    float acc = 0.f, mxv = -INFINITY, sw = 0.f;
    for (int l = 0; l < 400; ++l) {
        float w = mk[b * 400 + l];
        float vv = oenc[((long long)(b * 400 + l)) * 256 + t] * w;
        acc += vv; mxv = fmaxf(mxv, vv); sw += w;
    }
    pooled[b * 512 + t] = acc / (sw + 1e-6f);
    pooled[b * 512 + 256 + t] = mxv;
}

__global__ __launch_bounds__(512) void meanmax_kernel(
    const float* __restrict__ feats, float* __restrict__ mm)
{
    int b = blockIdx.x; int t = threadIdx.x;
    float s = 0.f, mx = -INFINITY;
    for (int l = 0; l < 400; ++l) {
        float vv = feats[((long long)(b * 400 + l)) * 512 + t];
        s += vv; mx = fmaxf(mx, vv);
    }
    mm[b * 1024 + t] = s / 400.f;
    mm[b * 1024 + 512 + t] = mx;
}

__global__ __launch_bounds__(256) void heads_kernel(
    const float* __restrict__ pooled, const float* __restrict__ mm,
    const float* __restrict__ w_bow1, const float* __restrict__ b_bow1,
    const float* __restrict__ w_bow2, const float* __restrict__ b_bow2,
    const float* __restrict__ w_ext1, const float* __restrict__ b_ext1,
    const float* __restrict__ w_ext2, const float* __restrict__ b_ext2,
    const float* __restrict__ w_org1, const float* __restrict__ b_org1,
    const float* __restrict__ w_org2, const float* __restrict__ b_org2,
    float* __restrict__ out)
{
    int b = blockIdx.x, role = blockIdx.y;
    int t = threadIdx.x;
    __shared__ float inb[1024];
    __shared__ float red[256];
    __shared__ float hid[256];
    if (role == 0) {
        inb[t] = pooled[b * 512 + t];
        inb[256 + t] = pooled[b * 512 + 256 + t];
        __syncthreads();
        float acc = b_bow1[t];
        for (int j = 0; j < 512; ++j) acc += inb[j] * w_bow1[j * 256 + t];
        red[t] = mishf(acc) * w_bow2[t];
        __syncthreads();
        for (int s = 128; s; s >>= 1) { if (t < s) red[t] += red[t + s]; __syncthreads(); }
        if (t == 0) out[b * 11 + 0] = red[0] + b_bow2[0];
    } else if (role == 1) {
        inb[t] = mm[b * 1024 + t];
        inb[256 + t] = mm[b * 1024 + 256 + t];
        inb[512 + t] = mm[b * 1024 + 512 + t];
        inb[768 + t] = mm[b * 1024 + 768 + t];
        __syncthreads();
        float acc = b_ext1[t];
        for (int j = 0; j < 1024; ++j) acc += inb[j] * w_ext1[j * 256 + t];
        red[t] = mishf(acc) * w_ext2[t];
        __syncthreads();
        for (int s = 128; s; s >>= 1) { if (t < s) red[t] += red[t + s]; __syncthreads(); }
        if (t == 0) { out[b * 11 + 1] = red[0] + b_ext2[0]; out[88 + b] = 0.f; }
    } else {
        int i = role - 2;
        inb[t] = pooled[((1 + i) * 8 + b) * 512 + t];
        inb[256 + t] = pooled[((1 + i) * 8 + b) * 512 + 256 + t];
        __syncthreads();
        float acc = b_org1[i * 256 + t];
        for (int j = 0; j < 512; ++j)
            acc += inb[j] * w_org1[((long long)i * 512 + j) * 256 + t];
        hid[t] = mishf(acc);
        __syncthreads();
        for (int c = 0; c < 3; ++c) {
            red[t] = hid[t] * w_org2[(i * 256 + t) * 3 + c];
            __syncthreads();
            for (int s = 128; s; s >>= 1) { if (t < s) red[t] += red[t + s]; __syncthreads(); }
            if (t == 0) out[b * 11 + 2 + i * 3 + c] = red[0] + b_org2[i * 3 + c];
            __syncthreads();
        }
    }
}

// ---------------------------------------------------------------------------
// Launch
// ---------------------------------------------------------------------------
extern "C" void kernel_launch(void* const* d_in, const int* in_sizes, int n_in,
                              void* d_out, int out_size, void* d_ws, size_t ws_size,
                              hipStream_t stream)
{
    const float* x      = (const float*)d_in[0];
    const float* w_mlp  = (const float*)d_in[1];
    const float* b_mlp  = (const float*)d_in[2];
    const float* w_cnn  = (const float*)d_in[3];
    const float* b_cnn  = (const float*)d_in[4];
    const float* rel_emb= (const float*)d_in[5];
    const float* rel_g  = (const float*)d_in[6];
    const float* rel_b  = (const float*)d_in[7];
    const float* wq     = (const float*)d_in[8];
    const float* wk     = (const float*)d_in[9];
    const float* wv     = (const float*)d_in[10];
    const float* wo     = (const float*)d_in[11];
    const float* wi     = (const float*)d_in[12];
    const float* bq     = (const float*)d_in[13];
    const float* bk     = (const float*)d_in[14];
    const float* bv     = (const float*)d_in[15];
    const float* bo     = (const float*)d_in[16];
    const float* bi     = (const float*)d_in[17];
    const float* wout   = (const float*)d_in[18];
    const float* bout   = (const float*)d_in[19];
    const float* ln1g   = (const float*)d_in[20];
    const float* ln1b   = (const float*)d_in[21];
    const float* ln2g   = (const float*)d_in[22];
    const float* ln2b   = (const float*)d_in[23];
    const float* w_bow1 = (const float*)d_in[24];
    const float* b_bow1 = (const float*)d_in[25];
    const float* w_bow2 = (const float*)d_in[26];
    const float* b_bow2 = (const float*)d_in[27];
    const float* w_ext1 = (const float*)d_in[28];
    const float* b_ext1 = (const float*)d_in[29];
    const float* w_ext2 = (const float*)d_in[30];
    const float* b_ext2 = (const float*)d_in[31];
    const float* w_org1 = (const float*)d_in[32];
    const float* b_org1 = (const float*)d_in[33];
    const float* w_org2 = (const float*)d_in[34];
    const float* b_org2 = (const float*)d_in[35];

    float* ws = (float*)d_ws;
    // workspace layout (float offsets), total ~10.46M floats = 41.8 MB
    float* featsb  = ws + 0;           // 1,638,400
    float* vbuf    = ws + 1638400;     // 1,638,400 (V fp32 / WO-out / WI-out)
    float* ctxB    = ws + 3276800;     // 1,638,400 (ctx / h1 / outenc@0 / outln@819200)
    float* rellnb  = ws + 4915200;     //   614,400
    unsigned short* qkv_hi = (unsigned short*)(ws + 5529600);   // 3200x1024 ushort
    unsigned short* qkv_lo = (unsigned short*)(ws + 7168000);
    unsigned short* pkg_hi = (unsigned short*)(ws + 8806400);   // 799x1024 ushort
    unsigned short* pkg_lo = (unsigned short*)(ws + 9216000);
    unsigned short* whi    = (unsigned short*)(ws + 9625600);   // 786,432 ushort
    unsigned short* wlo    = (unsigned short*)(ws + 10018816);
    float* bqkvb   = ws + 10412032;    //     6,144
    float* masksb  = ws + 10418176;    //    12,800
    float* pooledb = ws + 10430976;    //    16,384
    float* mmb     = ws + 10447360;    //     8,192
    int*   relidx  = (int*)(ws + 10455552); // 800 ints
    float* outf    = (float*)d_out;

    // front
    gemm_bias<1><<<dim3(4, 50), 256, 0, stream>>>(x, w_mlp, b_mlp, featsb,
                                                  3200, 256, 128, 512);
    conv_kernel<<<3200, 256, 0, stream>>>(featsb, w_cnn, b_cnn, featsb);
    masks_kernel<<<13, 256, 0, stream>>>(x, masksb);
    relidx_kernel<<<4, 256, 0, stream>>>(relidx);
    pack_bqkv<<<24, 256, 0, stream>>>(bq, bk, bv, bqkvb);

    for (int o = 0; o < 4; ++o) {
        // rel layernorm
        ln_kernel<false><<<1200, 256, 0, stream>>>(rel_emb + (long long)o * 614400,
            nullptr, rel_g + o * 512, rel_b + o * 512, rellnb, 512);
        // weight prep (qkv pack, [1536][512] hi/lo)
        prep_wqkv<<<3072, 256, 0, stream>>>(wq, wk, wv, whi, wlo, o);
        // PQK: gathered rel projections -> pkg hi/lo [799][1024] (pq|pk)
        gemm_mfma<0, true, true><<<dim3(8, 13), 256, 0, stream>>>(
            rellnb, whi, wlo, bqkvb + o * 1536, vbuf, 799, 512, 512, relidx,
            pkg_hi, pkg_lo, 1024, 1024, 1 << 30);
        // QKV: feats -> qk hi/lo [3200][1024] + v fp32 [3200][512]
        gemm_mfma<0, false, true><<<dim3(12, 50), 256, 0, stream>>>(
            featsb, whi, wlo, bqkvb + o * 1536, vbuf, 3200, 512, 512, nullptr,
            qkv_hi, qkv_lo, 1024, 1024, 1024);
        // weight prep for wo/wi/wout (overwrites whi/wlo)
        prep_woiw<<<2560, 256, 0, stream>>>(wo, wi, wout, whi, wlo, o);
        // fused MFMA attention
        attn_kernel<<<dim3(13, 8, 8), 256, 0, stream>>>(qkv_hi, qkv_lo, vbuf,
            pkg_hi, pkg_lo, masksb + o * 3200, ctxB);
        // WO: ctx @ wo -> vbuf (tmp)
        gemm_mfma<0, false, false><<<dim3(4, 50), 256, 0, stream>>>(
            ctxB, whi, wlo, bo + o * 512, vbuf, 3200, 512, 512, nullptr,
            nullptr, nullptr, 0, 0, 0);
        // LN1(tmp + feats) -> ctxB (h1)
        ln_kernel<true><<<3200, 256, 0, stream>>>(vbuf, featsb, ln1g + o * 512,
                                                  ln1b + o * 512, ctxB, 512);
        // WI (mish): h1 @ wi -> vbuf (inter)
        gemm_mfma<1, false, false><<<dim3(4, 50), 256, 0, stream>>>(
            ctxB, whi + 262144, wlo + 262144, bi + o * 512, vbuf, 3200, 512, 512,
            nullptr, nullptr, nullptr, 0, 0, 0);
        // WOUT: inter @ wout -> ctxB (outenc, [3200][256])
        gemm_mfma<0, false, false><<<dim3(2, 50), 256, 0, stream>>>(
            vbuf, whi + 524288, wlo + 524288, bout + o * 256, ctxB, 3200, 512, 256,
            nullptr, nullptr, nullptr, 0, 0, 0);
        // LN2 -> ctxB+819200
        ln_kernel<false><<<3200, 256, 0, stream>>>(ctxB, nullptr, ln2g + o * 256,
                                                   ln2b + o * 256, ctxB + 819200, 256);
        // pooling
        pool_kernel<<<8, 256, 0, stream>>>(ctxB + 819200, masksb + o * 3200,
                                           pooledb + o * 4096);
    }

    meanmax_kernel<<<8, 512, 0, stream>>>(featsb, mmb);
    heads_kernel<<<dim3(8, 5), 256, 0, stream>>>(pooledb, mmb,
        w_bow1, b_bow1, w_bow2, b_bow2, w_ext1, b_ext1, w_ext2, b_ext2,
        w_org1, b_org1, w_org2, b_org2, outf);
}

// Round 4
// 1483.133 us; speedup vs baseline: 1.8071x; 1.1343x over previous
//
#include <hip/hip_runtime.h>
#include <math.h>

// ---------------------------------------------------------------------------
// Model dims (fixed): B=8 L=400 F=128 D=256 T=256 H=512 NH=8 HD=64 P=1200
// ---------------------------------------------------------------------------

typedef __attribute__((ext_vector_type(8))) short bf16x8;
typedef __attribute__((ext_vector_type(4))) float f32x4;
typedef __attribute__((ext_vector_type(4))) unsigned int u32x4;

__device__ __forceinline__ float mishf(float x) {
    float sp = fmaxf(x, 0.f) + log1pf(expf(-fabsf(x)));   // stable softplus
    return x * tanhf(sp);
}

__device__ __forceinline__ unsigned short f2bf(float f) {
    unsigned int u = __float_as_uint(f);
    u = (u + 0x7fffu + ((u >> 16) & 1u)) >> 16;           // RNE
    return (unsigned short)u;
}
__device__ __forceinline__ float bf2f(unsigned short h) {
    return __uint_as_float(((unsigned int)h) << 16);
}

__device__ __forceinline__ bf16x8 load_bf8(const unsigned short* p, bool valid) {
    bf16x8 z = {0, 0, 0, 0, 0, 0, 0, 0};
    if (valid) z = *(const bf16x8*)p;
    return z;
}

// ---------------------------------------------------------------------------
// fp32 GEMM (front MLP, K=128)
// ---------------------------------------------------------------------------
template<int EPI>
__global__ __launch_bounds__(256) void gemm_bias(
    const float* __restrict__ A, const float* __restrict__ Bm,
    const float* __restrict__ bias, float* __restrict__ C,
    int M, int N, int K, int ldc)
{
    __shared__ float As[16][68];
    __shared__ float Bs[16][68];
    int bm = blockIdx.y << 6, bn = blockIdx.x << 6;
    int tid = threadIdx.x;
    int tm = (tid >> 4) << 2, tn = (tid & 15) << 2;
    int ar = tid >> 2, ac4 = (tid & 3) << 2;
    int br = tid >> 4, bc4 = (tid & 15) << 2;
    float acc[4][4] = {};
    for (int k0 = 0; k0 < K; k0 += 16) {
        float4 av = make_float4(0.f, 0.f, 0.f, 0.f);
        if (bm + ar < M)
            av = *(const float4*)&A[(long long)(bm + ar) * K + k0 + ac4];
        As[ac4][ar] = av.x; As[ac4 + 1][ar] = av.y;
        As[ac4 + 2][ar] = av.z; As[ac4 + 3][ar] = av.w;
        *(float4*)&Bs[br][bc4] =
            *(const float4*)&Bm[(long long)(k0 + br) * N + bn + bc4];
        __syncthreads();
        #pragma unroll
        for (int kk = 0; kk < 16; ++kk) {
            float4 a4 = *(const float4*)&As[kk][tm];
            float4 b4 = *(const float4*)&Bs[kk][tn];
            acc[0][0] += a4.x * b4.x; acc[0][1] += a4.x * b4.y;
            acc[0][2] += a4.x * b4.z; acc[0][3] += a4.x * b4.w;
            acc[1][0] += a4.y * b4.x; acc[1][1] += a4.y * b4.y;
            acc[1][2] += a4.y * b4.z; acc[1][3] += a4.y * b4.w;
            acc[2][0] += a4.z * b4.x; acc[2][1] += a4.z * b4.y;
            acc[2][2] += a4.z * b4.z; acc[2][3] += a4.z * b4.w;
            acc[3][0] += a4.w * b4.x; acc[3][1] += a4.w * b4.y;
            acc[3][2] += a4.w * b4.z; acc[3][3] += a4.w * b4.w;
        }
        __syncthreads();
    }
    #pragma unroll
    for (int i = 0; i < 4; ++i) {
        int r = bm + tm + i;
        if (r < M) {
            float v0 = acc[i][0] + bias[bn + tn + 0];
            float v1 = acc[i][1] + bias[bn + tn + 1];
            float v2 = acc[i][2] + bias[bn + tn + 2];
            float v3 = acc[i][3] + bias[bn + tn + 3];
            if (EPI == 1) { v0 = mishf(v0); v1 = mishf(v1); v2 = mishf(v2); v3 = mishf(v3); }
            float4 o; o.x = v0; o.y = v1; o.z = v2; o.w = v3;
            *(float4*)&C[(long long)r * ldc + bn + tn] = o;
        }
    }
}

// ---------------------------------------------------------------------------
// MFMA bf16x3-split GEMM. B pre-transposed+split [N][K] bf16 hi/lo.
// ---------------------------------------------------------------------------
template<int EPI, bool GATHER, bool SPLIT>
__global__ __launch_bounds__(256) void gemm_mfma(
    const float* __restrict__ A,
    const unsigned short* __restrict__ Bth, const unsigned short* __restrict__ Btl,
    const float* __restrict__ bias, float* __restrict__ C,
    int M, int K, int ldc, const int* __restrict__ gidx,
    unsigned short* __restrict__ Chi, unsigned short* __restrict__ Clo,
    int ldhl, int nhl, int voff)
{
    __shared__ unsigned short Ah[64 * 40];
    __shared__ unsigned short Al[64 * 40];
    __shared__ unsigned short Bh[128 * 40];
    __shared__ unsigned short Bl[128 * 40];

    int bm = blockIdx.y << 6, bn = blockIdx.x << 7;
    int tid = threadIdx.x;
    int lane = tid & 63, wid = tid >> 6;
    int wm = wid >> 1, wn = wid & 1;
    int fr = lane & 15, kg = (lane >> 4) << 3;

    int ar = tid >> 2, akc = (tid & 3) << 3;
    int bnr = tid >> 1, bkc = (tid & 1) << 4;

    long long arow; bool avalid;
    {
        int gr = bm + ar;
        avalid = gr < M;
        if (GATHER) arow = avalid ? (long long)gidx[gr] : 0;
        else        arow = avalid ? (long long)gr : 0;
    }

    f32x4 acc[2][4] = {};

    for (int k0 = 0; k0 < K; k0 += 32) {
        float vv[8];
        if (avalid) {
            float4 v0 = *(const float4*)&A[arow * K + k0 + akc];
            float4 v1 = *(const float4*)&A[arow * K + k0 + akc + 4];
            vv[0] = v0.x; vv[1] = v0.y; vv[2] = v0.z; vv[3] = v0.w;
            vv[4] = v1.x; vv[5] = v1.y; vv[6] = v1.z; vv[7] = v1.w;
        } else {
            #pragma unroll
            for (int e = 0; e < 8; ++e) vv[e] = 0.f;
        }
        union { unsigned short u[8]; u32x4 v; } ph, pl;
        #pragma unroll
        for (int e = 0; e < 8; ++e) {
            unsigned short h = f2bf(vv[e]);
            ph.u[e] = h;
            pl.u[e] = f2bf(vv[e] - bf2f(h));
        }
        *(u32x4*)&Ah[ar * 40 + akc] = ph.v;
        *(u32x4*)&Al[ar * 40 + akc] = pl.v;

        {
            long long boff = (long long)(bn + bnr) * K + k0 + bkc;
            *(u32x4*)&Bh[bnr * 40 + bkc]     = *(const u32x4*)&Bth[boff];
            *(u32x4*)&Bh[bnr * 40 + bkc + 8] = *(const u32x4*)&Bth[boff + 8];
            *(u32x4*)&Bl[bnr * 40 + bkc]     = *(const u32x4*)&Btl[boff];
            *(u32x4*)&Bl[bnr * 40 + bkc + 8] = *(const u32x4*)&Btl[boff + 8];
        }
        __syncthreads();

        bf16x8 af[2], alf[2], bfj[4], blf[4];
        #pragma unroll
        for (int i = 0; i < 2; ++i) {
            int row = wm * 32 + i * 16 + fr;
            af[i]  = *(const bf16x8*)&Ah[row * 40 + kg];
            alf[i] = *(const bf16x8*)&Al[row * 40 + kg];
        }
        #pragma unroll
        for (int j = 0; j < 4; ++j) {
            int row = wn * 64 + j * 16 + fr;
            bfj[j] = *(const bf16x8*)&Bh[row * 40 + kg];
            blf[j] = *(const bf16x8*)&Bl[row * 40 + kg];
        }
        #pragma unroll
        for (int i = 0; i < 2; ++i)
        #pragma unroll
        for (int j = 0; j < 4; ++j) {
            acc[i][j] = __builtin_amdgcn_mfma_f32_16x16x32_bf16(af[i],  bfj[j], acc[i][j], 0, 0, 0);
            acc[i][j] = __builtin_amdgcn_mfma_f32_16x16x32_bf16(af[i],  blf[j], acc[i][j], 0, 0, 0);
            acc[i][j] = __builtin_amdgcn_mfma_f32_16x16x32_bf16(alf[i], bfj[j], acc[i][j], 0, 0, 0);
        }
        __syncthreads();
    }

    #pragma unroll
    for (int i = 0; i < 2; ++i) {
        int rbase = bm + wm * 32 + i * 16 + ((lane >> 4) << 2);
        #pragma unroll
        for (int j = 0; j < 4; ++j) {
            int ccol = bn + wn * 64 + j * 16 + fr;
            float bv = bias[ccol];
            #pragma unroll
            for (int r = 0; r < 4; ++r) {
                int row = rbase + r;
                if (row < M) {
                    float val = acc[i][j][r] + bv;
                    if (SPLIT) {
                        if (ccol < nhl) {
                            unsigned short hh = f2bf(val);
                            Chi[(long long)row * ldhl + ccol] = hh;
                            Clo[(long long)row * ldhl + ccol] = f2bf(val - bf2f(hh));
                        } else {
                            C[(long long)row * ldc + (ccol - voff)] = val;
                        }
                    } else {
                        if (EPI == 1) val = mishf(val);
                        C[(long long)row * ldc + ccol] = val;
                    }
                }
            }
        }
    }
}

// ---------------------------------------------------------------------------
// Weight prep kernels
// ---------------------------------------------------------------------------
__global__ __launch_bounds__(256) void prep_wqkv(
    const float* __restrict__ wq, const float* __restrict__ wk,
    const float* __restrict__ wv,
    unsigned short* __restrict__ whi, unsigned short* __restrict__ wlo, int o)
{
    int idx = blockIdx.x * 256 + threadIdx.x;
    if (idx >= 1536 * 512) return;
    int k = idx / 1536, n = idx % 1536;
    int sel = n >> 9, col = n & 511;
    const float* W = sel == 0 ? wq : (sel == 1 ? wk : wv);
    float v = W[(long long)o * 262144 + k * 512 + col];
    unsigned short h = f2bf(v);
    whi[n * 512 + k] = h;
    wlo[n * 512 + k] = f2bf(v - bf2f(h));
}

__global__ __launch_bounds__(256) void prep_woiw(
    const float* __restrict__ wo, const float* __restrict__ wi,
    const float* __restrict__ wout,
    unsigned short* __restrict__ whi, unsigned short* __restrict__ wlo, int o)
{
    int idx = blockIdx.x * 256 + threadIdx.x;
    if (idx >= 655360) return;
    const float* W; int N, nk, base;
    if (idx < 262144)      { W = wo + (long long)o * 262144; N = 512; nk = idx; base = 0; }
    else if (idx < 524288) { W = wi + (long long)o * 262144; N = 512; nk = idx - 262144; base = 262144; }
    else                   { W = wout + (long long)o * 131072; N = 256; nk = idx - 524288; base = 524288; }
    int k = nk / N, n = nk % N;
    float v = W[k * N + n];
    unsigned short h = f2bf(v);
    whi[base + n * 512 + k] = h;
    wlo[base + n * 512 + k] = f2bf(v - bf2f(h));
}

__global__ void pack_bqkv(const float* __restrict__ bq, const float* __restrict__ bk,
                          const float* __restrict__ bv, float* __restrict__ bqkv)
{
    int idx = blockIdx.x * 256 + threadIdx.x;
    if (idx >= 6144) return;
    int o = idx / 1536, n = idx % 1536;
    float v;
    if (n < 512) v = bq[o * 512 + n];
    else if (n < 1024) v = bk[o * 512 + n - 512];
    else v = bv[o * 512 + n - 1024];
    bqkv[idx] = v;
}

// ---------------------------------------------------------------------------
// Conv1d k=3 SAME
// ---------------------------------------------------------------------------
__global__ __launch_bounds__(256) void conv_kernel(
    const float* __restrict__ feats, const float* __restrict__ w,
    const float* __restrict__ bias, float* __restrict__ fo)
{
    int bl = blockIdx.x; int b = bl / 400, l = bl % 400;
    int t = threadIdx.x;
    __shared__ float xr[768];
    #pragma unroll
    for (int dl = 0; dl < 3; ++dl) {
        int ls = l + dl - 1;
        float vv = 0.f;
        if (ls >= 0 && ls < 400) vv = feats[((long long)(b * 400 + ls)) * 512 + t];
        xr[dl * 256 + t] = vv;
    }
    __syncthreads();
    float acc = bias[t];
    #pragma unroll 4
    for (int j = 0; j < 768; ++j) acc += xr[j] * w[j * 256 + t];
    fo[((long long)bl) * 512 + 256 + t] = fmaxf(acc, 0.f);
}

__global__ void masks_kernel(const float* __restrict__ x, float* __restrict__ mk)
{
    int i = blockIdx.x * 256 + threadIdx.x;
    if (i >= 3200) return;
    const float* xr = x + (long long)i * 128;
    mk[0 * 3200 + i] = xr[4];
    mk[1 * 3200 + i] = fmaxf(xr[2], xr[3]);
    mk[2 * 3200 + i] = xr[0];
    mk[3 * 3200 + i] = xr[1];
}

__global__ void relidx_kernel(int* __restrict__ T)
{
    int i = blockIdx.x * blockDim.x + threadIdx.x;
    if (i >= 799) return;
    int rel = i - 399;
    int sgn = (rel > 0) - (rel < 0);
    int ab = (rel < 300 && rel > -300) ? 299 : (rel < 0 ? -rel : rel);
    long long bpos;
    if (ab <= 300) bpos = rel;
    else {
        double lp = ceil(log((double)ab / 300.0) / log(599.0 / 300.0) * 299.0) + 300.0;
        bpos = (long long)lp * sgn;
    }
    long long c2p = bpos + 600;
    c2p = c2p < 0 ? 0 : (c2p > 1199 ? 1199 : c2p);
    T[i] = (int)c2p;
}

// ---------------------------------------------------------------------------
// LayerNorm (eps 1e-7)
// ---------------------------------------------------------------------------
template<bool RES>
__global__ __launch_bounds__(256) void ln_kernel(
    const float* __restrict__ X, const float* __restrict__ R,
    const float* __restrict__ g, const float* __restrict__ be,
    float* __restrict__ Y, int Hd)
{
    long long row = blockIdx.x;
    int t = threadIdx.x;
    __shared__ float buf[512];
    __shared__ float red[256];
    const float* x = X + row * Hd;
    float s = 0.f;
    for (int j = t; j < Hd; j += 256) {
        float vv = x[j];
        if (RES) vv += R[row * Hd + j];
        buf[j] = vv; s += vv;
    }
    red[t] = s; __syncthreads();
    for (int k = 128; k; k >>= 1) { if (t < k) red[t] += red[t + k]; __syncthreads(); }
    float mean = red[0] / (float)Hd;
    __syncthreads();
    float s2 = 0.f;
    for (int j = t; j < Hd; j += 256) { float d = buf[j] - mean; s2 += d * d; }
    red[t] = s2; __syncthreads();
    for (int k = 128; k; k >>= 1) { if (t < k) red[t] += red[t + k]; __syncthreads(); }
    float inv = 1.f / sqrtf(red[0] / (float)Hd + 1e-7f);
    for (int j = t; j < Hd; j += 256)
        Y[row * Hd + j] = (buf[j] - mean) * inv * g[j] + be[j];
}

// ---------------------------------------------------------------------------
// MFMA fused disentangled flash attention, round 4:
//  - wave-parallel softmax (32 rows x 8 groups)
//  - MFMA PV with transposed split-V in LDS
//  - band fragments batched into registers before MFMA section
// Block = (l-tile 32, head, batch), 256 thr = 4 waves.
// ---------------------------------------------------------------------------
__global__ __launch_bounds__(256) void attn_kernel(
    const unsigned short* __restrict__ qk_hi, const unsigned short* __restrict__ qk_lo,
    const float* __restrict__ vbuf,
    const unsigned short* __restrict__ pkg_hi, const unsigned short* __restrict__ pkg_lo,
    const float* __restrict__ mask, float* __restrict__ ctx)
{
    const float scale = 0.07216878364870322f;       // 1/sqrt(64*3)
    const float NEGMIN = -3.402823466e38f;
    int lt = blockIdx.x, h = blockIdx.y, b = blockIdx.z;
    int l0 = lt * 32;
    int tid = threadIdx.x;
    int lane = tid & 63, w = tid >> 6;
    int wrf = w >> 1;      // Q row-frag index
    int wcf = w & 1;       // K row-frag index
    int fr = lane & 15, kg8 = (lane >> 4) << 3;
    int rbase = (lane >> 4) << 2;

    __shared__ unsigned short Kh[32 * 72], Kl[32 * 72];
    __shared__ unsigned short Vth[64 * 40], Vtl[64 * 40];
    __shared__ float T2s[32 * 68], T3s[32 * 68];
    __shared__ float St[32 * 36];
    __shared__ float redl[32 * 9];
    __shared__ float mrow[32], mstate[32], lstate[32], corrs[32], wlv[32], wmv[32];

    // Q frags once
    bf16x8 qfh[2], qfl[2];
    {
        int qi = l0 + wrf * 16 + fr;
        bool valid = qi < 400;
        long long base = ((long long)(b * 400 + (valid ? qi : 0))) * 1024 + h * 64 + kg8;
        #pragma unroll
        for (int kk = 0; kk < 2; ++kk) {
            qfh[kk] = load_bf8(qk_hi + base + kk * 32, valid);
            qfl[kk] = load_bf8(qk_lo + base + kk * 32, valid);
        }
    }
    if (tid < 32) {
        int lg = l0 + tid;
        wlv[tid] = (lg < 400) ? mask[b * 400 + lg] : 0.f;
        mstate[tid] = -INFINITY;
        lstate[tid] = 0.f;
    }
    // PV accumulators: rows [wrf*16,+16), cols [wcf*32 + f*16,+16)
    f32x4 O[2] = {};
    int smi = tid & 31, smg = tid >> 5;   // softmax row / group

    for (int mt = 0; mt < 13; ++mt) {
        int m0 = mt * 32;
        int D0 = l0 - m0 + 368;
        __syncthreads();   // s1: prev PV done
        // ---- stage K hi/lo ----
        {
            int row = tid >> 3, seg = (tid & 7) << 3;
            bool valid = (m0 + row) < 400;
            long long src = ((long long)(b * 400 + (valid ? m0 + row : 0))) * 1024 + 512 + h * 64 + seg;
            *(bf16x8*)&Kh[row * 72 + seg] = load_bf8(qk_hi + src, valid);
            *(bf16x8*)&Kl[row * 72 + seg] = load_bf8(qk_lo + src, valid);
        }
        // ---- stage V transposed + split ----
        {
            int j = tid >> 3, dseg = (tid & 7) << 3;
            bool valid = (m0 + j) < 400;
            float4 a = make_float4(0.f, 0.f, 0.f, 0.f), c = a;
            if (valid) {
                const float* vp = &vbuf[((long long)(b * 400 + m0 + j)) * 512 + h * 64 + dseg];
                a = *(const float4*)vp; c = *(const float4*)(vp + 4);
            }
            float fv[8] = {a.x, a.y, a.z, a.w, c.x, c.y, c.z, c.w};
            #pragma unroll
            for (int e = 0; e < 8; ++e) {
                unsigned short hh = f2bf(fv[e]);
                Vth[(dseg + e) * 40 + j] = hh;
                Vtl[(dseg + e) * 40 + j] = f2bf(fv[e] - bf2f(hh));
            }
        }
        if (tid < 32) wmv[tid] = (m0 + tid < 400) ? mask[b * 400 + m0 + tid] : 0.f;
        // ---- band fragments -> registers (16 independent loads) ----
        bf16x8 b2h[2][2], b2l[2][2], b3h[2][2], b3l[2][2];
        #pragma unroll
        for (int c = 0; c < 2; ++c) {
            int row2 = D0 + (2 * wcf + c) * 16 + fr;
            int row3 = D0 + (2 * wrf + c) * 16 + fr;
            bool v2 = (unsigned)row2 < 799u;
            bool v3 = (unsigned)row3 < 799u;
            #pragma unroll
            for (int kk = 0; kk < 2; ++kk) {
                long long o2 = (long long)(v2 ? row2 : 0) * 1024 + 512 + h * 64 + kk * 32 + kg8;
                long long o3 = (long long)(v3 ? row3 : 0) * 1024 + h * 64 + kk * 32 + kg8;
                b2h[c][kk] = load_bf8(pkg_hi + o2, v2);
                b2l[c][kk] = load_bf8(pkg_lo + o2, v2);
                b3h[c][kk] = load_bf8(pkg_hi + o3, v3);
                b3l[c][kk] = load_bf8(pkg_lo + o3, v3);
            }
        }
        __syncthreads();   // s2: staging visible
        // ---- K frags from LDS ----
        bf16x8 kfh[2], kfl[2];
        #pragma unroll
        for (int kk = 0; kk < 2; ++kk) {
            kfh[kk] = *(const bf16x8*)&Kh[(wcf * 16 + fr) * 72 + kk * 32 + kg8];
            kfl[kk] = *(const bf16x8*)&Kl[(wcf * 16 + fr) * 72 + kk * 32 + kg8];
        }
        // ---- T1 = Q@K^T ----
        f32x4 aT1 = {};
        #pragma unroll
        for (int kk = 0; kk < 2; ++kk) {
            aT1 = __builtin_amdgcn_mfma_f32_16x16x32_bf16(qfh[kk], kfh[kk], aT1, 0, 0, 0);
            aT1 = __builtin_amdgcn_mfma_f32_16x16x32_bf16(qfh[kk], kfl[kk], aT1, 0, 0, 0);
            aT1 = __builtin_amdgcn_mfma_f32_16x16x32_bf16(qfl[kk], kfh[kk], aT1, 0, 0, 0);
        }
        // ---- T2 = Q@PKband^T, T3 = K@PQband^T ----
        f32x4 aT2[2] = {{0.f,0.f,0.f,0.f},{0.f,0.f,0.f,0.f}};
        f32x4 aT3[2] = {{0.f,0.f,0.f,0.f},{0.f,0.f,0.f,0.f}};
        #pragma unroll
        for (int c = 0; c < 2; ++c)
        #pragma unroll
        for (int kk = 0; kk < 2; ++kk) {
            aT2[c] = __builtin_amdgcn_mfma_f32_16x16x32_bf16(qfh[kk], b2h[c][kk], aT2[c], 0, 0, 0);
            aT2[c] = __builtin_amdgcn_mfma_f32_16x16x32_bf16(qfh[kk], b2l[c][kk], aT2[c], 0, 0, 0);
            aT2[c] = __builtin_amdgcn_mfma_f32_16x16x32_bf16(qfl[kk], b2h[c][kk], aT2[c], 0, 0, 0);
            aT3[c] = __builtin_amdgcn_mfma_f32_16x16x32_bf16(kfh[kk], b3h[c][kk], aT3[c], 0, 0, 0);
            aT3[c] = __builtin_amdgcn_mfma_f32_16x16x32_bf16(kfh[kk], b3l[c][kk], aT3[c], 0, 0, 0);
            aT3[c] = __builtin_amdgcn_mfma_f32_16x16x32_bf16(kfl[kk], b3h[c][kk], aT3[c], 0, 0, 0);
        }
        // ---- write T2/T3 frags to LDS ----
        {
            int rB2 = wrf * 16 + rbase;
            int rB3 = wcf * 16 + rbase;
            #pragma unroll
            for (int c = 0; c < 2; ++c) {
                int cc2 = (2 * wcf + c) * 16 + fr;
                int cc3 = (2 * wrf + c) * 16 + fr;
                #pragma unroll
                for (int r = 0; r < 4; ++r) {
                    T2s[(rB2 + r) * 68 + cc2] = aT2[c][r];
                    T3s[(rB3 + r) * 68 + cc3] = aT3[c][r];
                }
            }
        }
        __syncthreads();   // s3
        // ---- assemble scores: St[i*36+j] ----
        {
            int ib = wrf * 16 + rbase;
            int j  = wcf * 16 + fr;
            bool jv = (m0 + j) < 400;
            float wm = wmv[j];
            #pragma unroll
            for (int r = 0; r < 4; ++r) {
                int i = ib + r;
                int rr = i - j + 31;
                float s;
                if (!jv) s = -INFINITY;
                else if (wlv[i] != 0.f && wm != 0.f)
                    s = (aT1[r] + T2s[i * 68 + rr] + T3s[j * 68 + rr]) * scale;
                else s = NEGMIN;
                St[i * 36 + j] = s;
            }
        }
        __syncthreads();   // s4
        // ---- softmax phase A: partial max (32 rows x 8 groups) ----
        {
            float4 v = *(const float4*)&St[smi * 36 + (smg << 2)];
            redl[smi * 9 + smg] = fmaxf(fmaxf(v.x, v.y), fmaxf(v.z, v.w));
        }
        __syncthreads();   // s5
        if (tid < 32) {
            int i = tid;
            float mtile = redl[i * 9];
            #pragma unroll
            for (int g = 1; g < 8; ++g) mtile = fmaxf(mtile, redl[i * 9 + g]);
            float mo = mstate[i];
            float mn = fmaxf(mo, mtile);
            corrs[i] = expf(mo - mn);
            mstate[i] = mn;
            mrow[i] = mn;
        }
        __syncthreads();   // s6
        // ---- exp + partial sum ----
        {
            float mn = mrow[smi];
            float* sp = &St[smi * 36 + (smg << 2)];
            float4 v = *(const float4*)sp;
            v.x = expf(v.x - mn); v.y = expf(v.y - mn);
            v.z = expf(v.z - mn); v.w = expf(v.w - mn);
            *(float4*)sp = v;
            redl[smi * 9 + smg] = v.x + v.y + v.z + v.w;
        }
        __syncthreads();   // s7
        if (tid < 32) {
            int i = tid;
            float rs = redl[i * 9];
            #pragma unroll
            for (int g = 1; g < 8; ++g) rs += redl[i * 9 + g];
            lstate[i] = lstate[i] * corrs[i] + rs;
        }
        // ---- PV via MFMA ----
        {
            float cr[4];
            #pragma unroll
            for (int r = 0; r < 4; ++r) cr[r] = corrs[wrf * 16 + rbase + r];
            #pragma unroll
            for (int f = 0; f < 2; ++f)
            #pragma unroll
            for (int r = 0; r < 4; ++r) O[f][r] *= cr[r];
            // P frag: row wrf*16+fr, k = kg8..kg8+7
            const float* prow = &St[(wrf * 16 + fr) * 36 + kg8];
            float4 p0 = *(const float4*)prow;
            float4 p1 = *(const float4*)(prow + 4);
            float pvv[8] = {p0.x, p0.y, p0.z, p0.w, p1.x, p1.y, p1.z, p1.w};
            union { unsigned short u[8]; bf16x8 v; } Ph, Pl;
            #pragma unroll
            for (int e = 0; e < 8; ++e) {
                unsigned short hh = f2bf(pvv[e]);
                Ph.u[e] = hh;
                Pl.u[e] = f2bf(pvv[e] - bf2f(hh));
            }
            #pragma unroll
            for (int f = 0; f < 2; ++f) {
                int d = wcf * 32 + f * 16 + fr;
                bf16x8 Vh = *(const bf16x8*)&Vth[d * 40 + kg8];
                bf16x8 Vl = *(const bf16x8*)&Vtl[d * 40 + kg8];
                O[f] = __builtin_amdgcn_mfma_f32_16x16x32_bf16(Ph.v, Vh, O[f], 0, 0, 0);
                O[f] = __builtin_amdgcn_mfma_f32_16x16x32_bf16(Ph.v, Vl, O[f], 0, 0, 0);
                O[f] = __builtin_amdgcn_mfma_f32_16x16x32_bf16(Pl.v, Vh, O[f], 0, 0, 0);
            }
        }
    }
    __syncthreads();   // lstate final
    // ---- write ctx ----
    #pragma unroll
    for (int f = 0; f < 2; ++f) {
        int colg = h * 64 + wcf * 32 + f * 16 + fr;
        #pragma unroll
        for (int r = 0; r < 4; ++r) {
            int li = wrf * 16 + rbase + r;
            int lg = l0 + li;
            if (lg < 400)
                ctx[((long long)(b * 400 + lg)) * 512 + colg] = O[f][r] / lstate[li];
        }
    }
}

// ---------------------------------------------------------------------------
// Pool / meanmax / heads
// ---------------------------------------------------------------------------
__global__ __launch_bounds__(256) void pool_kernel(
    const float* __restrict__ oenc, const float* __restrict__ mk,
    float* __restrict__ pooled)
{
    int b = blockIdx.x; int t = threadIdx.x;
    float acc = 0.f, mxv = -INFINITY, sw = 0.f;
    for (int l = 0; l < 400; ++l) {
        float w = mk[b * 400 + l];
        float vv = oenc[((long long)(b * 400 + l)) * 256 + t] * w;
        acc += vv; mxv = fmaxf(mxv, vv); sw += w;
    }
    pooled[b * 512 + t] = acc / (sw + 1e-6f);
    pooled[b * 512 + 256 + t] = mxv;
}

__global__ __launch_bounds__(512) void meanmax_kernel(
    const float* __restrict__ feats, float* __restrict__ mm)
{
    int b = blockIdx.x; int t = threadIdx.x;
    float s = 0.f, mx = -INFINITY;
    for (int l = 0; l < 400; ++l) {
        float vv = feats[((long long)(b * 400 + l)) * 512 + t];
        s += vv; mx = fmaxf(mx, vv);
    }
    mm[b * 1024 + t] = s / 400.f;
    mm[b * 1024 + 512 + t] = mx;
}

__global__ __launch_bounds__(256) void heads_kernel(
    const float* __restrict__ pooled, const float* __restrict__ mm,
    const float* __restrict__ w_bow1, const float* __restrict__ b_bow1,
    const float* __restrict__ w_bow2, const float* __restrict__ b_bow2,
    const float* __restrict__ w_ext1, const float* __restrict__ b_ext1,
    const float* __restrict__ w_ext2, const float* __restrict__ b_ext2,
    const float* __restrict__ w_org1, const float* __restrict__ b_org1,
    const float* __restrict__ w_org2, const float* __restrict__ b_org2,
    float* __restrict__ out)
{
    int b = blockIdx.x, role = blockIdx.y;
    int t = threadIdx.x;
    __shared__ float inb[1024];
    __shared__ float red[256];
    __shared__ float hid[256];
    if (role == 0) {
        inb[t] = pooled[b * 512 + t];
        inb[256 + t] = pooled[b * 512 + 256 + t];
        __syncthreads();
        float acc = b_bow1[t];
        for (int j = 0; j < 512; ++j) acc += inb[j] * w_bow1[j * 256 + t];
        red[t] = mishf(acc) * w_bow2[t];
        __syncthreads();
        for (int s = 128; s; s >>= 1) { if (t < s) red[t] += red[t + s]; __syncthreads(); }
        if (t == 0) out[b * 11 + 0] = red[0] + b_bow2[0];
    } else if (role == 1) {
        inb[t] = mm[b * 1024 + t];
        inb[256 + t] = mm[b * 1024 + 256 + t];
        inb[512 + t] = mm[b * 1024 + 512 + t];
        inb[768 + t] = mm[b * 1024 + 768 + t];
        __syncthreads();
        float acc = b_ext1[t];
        for (int j = 0; j < 1024; ++j) acc += inb[j] * w_ext1[j * 256 + t];
        red[t] = mishf(acc) * w_ext2[t];
        __syncthreads();
        for (int s = 128; s; s >>= 1) { if (t < s) red[t] += red[t + s]; __syncthreads(); }
        if (t == 0) { out[b * 11 + 1] = red[0] + b_ext2[0]; out[88 + b] = 0.f; }
    } else {
        int i = role - 2;
        inb[t] = pooled[((1 + i) * 8 + b) * 512 + t];
        inb[256 + t] = pooled[((1 + i) * 8 + b) * 512 + 256 + t];
        __syncthreads();
        float acc = b_org1[i * 256 + t];
        for (int j = 0; j < 512; ++j)
            acc += inb[j] * w_org1[((long long)i * 512 + j) * 256 + t];
        hid[t] = mishf(acc);
        __syncthreads();
        for (int c = 0; c < 3; ++c) {
            red[t] = hid[t] * w_org2[(i * 256 + t) * 3 + c];
            __syncthreads();
            for (int s = 128; s; s >>= 1) { if (t < s) red[t] += red[t + s]; __syncthreads(); }
            if (t == 0) out[b * 11 + 2 + i * 3 + c] = red[0] + b_org2[i * 3 + c];
            __syncthreads();
        }
    }
}

// ---------------------------------------------------------------------------
// Launch
// ---------------------------------------------------------------------------
extern "C" void kernel_launch(void* const* d_in, const int* in_sizes, int n_in,
                              void* d_out, int out_size, void* d_ws, size_t ws_size,
                              hipStream_t stream)
{
    const float* x      = (const float*)d_in[0];
    const float* w_mlp  = (const float*)d_in[1];
    const float* b_mlp  = (const float*)d_in[2];
    const float* w_cnn  = (const float*)d_in[3];
    const float* b_cnn  = (const float*)d_in[4];
    const float* rel_emb= (const float*)d_in[5];
    const float* rel_g  = (const float*)d_in[6];
    const float* rel_b  = (const float*)d_in[7];
    const float* wq     = (const float*)d_in[8];
    const float* wk     = (const float*)d_in[9];
    const float* wv     = (const float*)d_in[10];
    const float* wo     = (const float*)d_in[11];
    const float* wi     = (const float*)d_in[12];
    const float* bq     = (const float*)d_in[13];
    const float* bk     = (const float*)d_in[14];
    const float* bv     = (const float*)d_in[15];
    const float* bo     = (const float*)d_in[16];
    const float* bi     = (const float*)d_in[17];
    const float* wout   = (const float*)d_in[18];
    const float* bout   = (const float*)d_in[19];
    const float* ln1g   = (const float*)d_in[20];
    const float* ln1b   = (const float*)d_in[21];
    const float* ln2g   = (const float*)d_in[22];
    const float* ln2b   = (const float*)d_in[23];
    const float* w_bow1 = (const float*)d_in[24];
    const float* b_bow1 = (const float*)d_in[25];
    const float* w_bow2 = (const float*)d_in[26];
    const float* b_bow2 = (const float*)d_in[27];
    const float* w_ext1 = (const float*)d_in[28];
    const float* b_ext1 = (const float*)d_in[29];
    const float* w_ext2 = (const float*)d_in[30];
    const float* b_ext2 = (const float*)d_in[31];
    const float* w_org1 = (const float*)d_in[32];
    const float* b_org1 = (const float*)d_in[33];
    const float* w_org2 = (const float*)d_in[34];
    const float* b_org2 = (const float*)d_in[35];

    float* ws = (float*)d_ws;
    float* featsb  = ws + 0;           // 1,638,400
    float* vbuf    = ws + 1638400;     // 1,638,400 (V fp32 / WO-out / WI-out)
    float* ctxB    = ws + 3276800;     // 1,638,400 (ctx / h1 / outenc@0 / outln@819200)
    float* rellnb  = ws + 4915200;     //   614,400
    unsigned short* qkv_hi = (unsigned short*)(ws + 5529600);   // 3200x1024 ushort
    unsigned short* qkv_lo = (unsigned short*)(ws + 7168000);
    unsigned short* pkg_hi = (unsigned short*)(ws + 8806400);   // 799x1024 ushort
    unsigned short* pkg_lo = (unsigned short*)(ws + 9216000);
    unsigned short* whi    = (unsigned short*)(ws + 9625600);   // 786,432 ushort
    unsigned short* wlo    = (unsigned short*)(ws + 10018816);
    float* bqkvb   = ws + 10412032;    //     6,144
    float* masksb  = ws + 10418176;    //    12,800
    float* pooledb = ws + 10430976;    //    16,384
    float* mmb     = ws + 10447360;    //     8,192
    int*   relidx  = (int*)(ws + 10455552); // 800 ints
    float* outf    = (float*)d_out;

    // front
    gemm_bias<1><<<dim3(4, 50), 256, 0, stream>>>(x, w_mlp, b_mlp, featsb,
                                                  3200, 256, 128, 512);
    conv_kernel<<<3200, 256, 0, stream>>>(featsb, w_cnn, b_cnn, featsb);
    masks_kernel<<<13, 256, 0, stream>>>(x, masksb);
    relidx_kernel<<<4, 256, 0, stream>>>(relidx);
    pack_bqkv<<<24, 256, 0, stream>>>(bq, bk, bv, bqkvb);

    for (int o = 0; o < 4; ++o) {
        ln_kernel<false><<<1200, 256, 0, stream>>>(rel_emb + (long long)o * 614400,
            nullptr, rel_g + o * 512, rel_b + o * 512, rellnb, 512);
        prep_wqkv<<<3072, 256, 0, stream>>>(wq, wk, wv, whi, wlo, o);
        gemm_mfma<0, true, true><<<dim3(8, 13), 256, 0, stream>>>(
            rellnb, whi, wlo, bqkvb + o * 1536, vbuf, 799, 512, 512, relidx,
            pkg_hi, pkg_lo, 1024, 1024, 1 << 30);
        gemm_mfma<0, false, true><<<dim3(12, 50), 256, 0, stream>>>(
            featsb, whi, wlo, bqkvb + o * 1536, vbuf, 3200, 512, 512, nullptr,
            qkv_hi, qkv_lo, 1024, 1024, 1024);
        prep_woiw<<<2560, 256, 0, stream>>>(wo, wi, wout, whi, wlo, o);
        attn_kernel<<<dim3(13, 8, 8), 256, 0, stream>>>(qkv_hi, qkv_lo, vbuf,
            pkg_hi, pkg_lo, masksb + o * 3200, ctxB);
        gemm_mfma<0, false, false><<<dim3(4, 50), 256, 0, stream>>>(
            ctxB, whi, wlo, bo + o * 512, vbuf, 3200, 512, 512, nullptr,
            nullptr, nullptr, 0, 0, 0);
        ln_kernel<true><<<3200, 256, 0, stream>>>(vbuf, featsb, ln1g + o * 512,
                                                  ln1b + o * 512, ctxB, 512);
        gemm_mfma<1, false, false><<<dim3(4, 50), 256, 0, stream>>>(
            ctxB, whi + 262144, wlo + 262144, bi + o * 512, vbuf, 3200, 512, 512,
            nullptr, nullptr, nullptr, 0, 0, 0);
        gemm_mfma<0, false, false><<<dim3(2, 50), 256, 0, stream>>>(
            vbuf, whi + 524288, wlo + 524288, bout + o * 256, ctxB, 3200, 512, 256,
            nullptr, nullptr, nullptr, 0, 0, 0);
        ln_kernel<false><<<3200, 256, 0, stream>>>(ctxB, nullptr, ln2g + o * 256,
                                                   ln2b + o * 256, ctxB + 819200, 256);
        pool_kernel<<<8, 256, 0, stream>>>(ctxB + 819200, masksb + o * 3200,
                                           pooledb + o * 4096);
    }

    meanmax_kernel<<<8, 512, 0, stream>>>(featsb, mmb);
    heads_kernel<<<dim3(8, 5), 256, 0, stream>>>(pooledb, mmb,
        w_bow1, b_bow1, w_bow2, b_bow2, w_ext1, b_ext1, w_ext2, b_ext2,
        w_org1, b_org1, w_org2, b_org2, outf);
}

// Round 5
// 1385.729 us; speedup vs baseline: 1.9342x; 1.0703x over previous
//
#include <hip/hip_runtime.h>
#include <math.h>

// ---------------------------------------------------------------------------
// Model dims (fixed): B=8 L=400 F=128 D=256 T=256 H=512 NH=8 HD=64 P=1200
// ---------------------------------------------------------------------------

typedef __attribute__((ext_vector_type(8))) short bf16x8;
typedef __attribute__((ext_vector_type(4))) float f32x4;
typedef __attribute__((ext_vector_type(4))) unsigned int u32x4;

__device__ __forceinline__ float mishf(float x) {
    float sp = fmaxf(x, 0.f) + log1pf(expf(-fabsf(x)));   // stable softplus
    return x * tanhf(sp);
}

__device__ __forceinline__ unsigned short f2bf(float f) {
    unsigned int u = __float_as_uint(f);
    u = (u + 0x7fffu + ((u >> 16) & 1u)) >> 16;           // RNE
    return (unsigned short)u;
}
__device__ __forceinline__ float bf2f(unsigned short h) {
    return __uint_as_float(((unsigned int)h) << 16);
}

__device__ __forceinline__ bf16x8 load_bf8(const unsigned short* p, bool valid) {
    bf16x8 z = {0, 0, 0, 0, 0, 0, 0, 0};
    if (valid) z = *(const bf16x8*)p;
    return z;
}

// ---------------------------------------------------------------------------
// fp32 GEMM (front MLP, K=128). DUAL: also write result to C2 in padded
// conv layout (row -> (r/400)*402 + r%400 + 1, ld 256).
// ---------------------------------------------------------------------------
template<int EPI, bool DUAL>
__global__ __launch_bounds__(256) void gemm_bias(
    const float* __restrict__ A, const float* __restrict__ Bm,
    const float* __restrict__ bias, float* __restrict__ C,
    float* __restrict__ C2,
    int M, int N, int K, int ldc)
{
    __shared__ float As[16][68];
    __shared__ float Bs[16][68];
    int bm = blockIdx.y << 6, bn = blockIdx.x << 6;
    int tid = threadIdx.x;
    int tm = (tid >> 4) << 2, tn = (tid & 15) << 2;
    int ar = tid >> 2, ac4 = (tid & 3) << 2;
    int br = tid >> 4, bc4 = (tid & 15) << 2;
    float acc[4][4] = {};
    for (int k0 = 0; k0 < K; k0 += 16) {
        float4 av = make_float4(0.f, 0.f, 0.f, 0.f);
        if (bm + ar < M)
            av = *(const float4*)&A[(long long)(bm + ar) * K + k0 + ac4];
        As[ac4][ar] = av.x; As[ac4 + 1][ar] = av.y;
        As[ac4 + 2][ar] = av.z; As[ac4 + 3][ar] = av.w;
        *(float4*)&Bs[br][bc4] =
            *(const float4*)&Bm[(long long)(k0 + br) * N + bn + bc4];
        __syncthreads();
        #pragma unroll
        for (int kk = 0; kk < 16; ++kk) {
            float4 a4 = *(const float4*)&As[kk][tm];
            float4 b4 = *(const float4*)&Bs[kk][tn];
            acc[0][0] += a4.x * b4.x; acc[0][1] += a4.x * b4.y;
            acc[0][2] += a4.x * b4.z; acc[0][3] += a4.x * b4.w;
            acc[1][0] += a4.y * b4.x; acc[1][1] += a4.y * b4.y;
            acc[1][2] += a4.y * b4.z; acc[1][3] += a4.y * b4.w;
            acc[2][0] += a4.z * b4.x; acc[2][1] += a4.z * b4.y;
            acc[2][2] += a4.z * b4.z; acc[2][3] += a4.z * b4.w;
            acc[3][0] += a4.w * b4.x; acc[3][1] += a4.w * b4.y;
            acc[3][2] += a4.w * b4.z; acc[3][3] += a4.w * b4.w;
        }
        __syncthreads();
    }
    #pragma unroll
    for (int i = 0; i < 4; ++i) {
        int r = bm + tm + i;
        if (r < M) {
            float v0 = acc[i][0] + bias[bn + tn + 0];
            float v1 = acc[i][1] + bias[bn + tn + 1];
            float v2 = acc[i][2] + bias[bn + tn + 2];
            float v3 = acc[i][3] + bias[bn + tn + 3];
            if (EPI == 1) { v0 = mishf(v0); v1 = mishf(v1); v2 = mishf(v2); v3 = mishf(v3); }
            float4 o; o.x = v0; o.y = v1; o.z = v2; o.w = v3;
            *(float4*)&C[(long long)r * ldc + bn + tn] = o;
            if (DUAL) {
                int rr2 = (r / 400) * 402 + (r % 400) + 1;
                *(float4*)&C2[(long long)rr2 * 256 + bn + tn] = o;
            }
        }
    }
}

// ---------------------------------------------------------------------------
// MFMA bf16x3-split GEMM. B pre-transposed+split [N][K] bf16 hi/lo.
// lda = A row stride (lda=K normally; conv uses lda=256 with K=768 spanning
// 3 consecutive rows of the padded f1 buffer).
// EPI: 0 none, 1 mish, 2 relu.
// ---------------------------------------------------------------------------
template<int EPI, bool GATHER, bool SPLIT>
__global__ __launch_bounds__(256) void gemm_mfma(
    const float* __restrict__ A,
    const unsigned short* __restrict__ Bth, const unsigned short* __restrict__ Btl,
    const float* __restrict__ bias, float* __restrict__ C,
    int M, int K, int lda, int ldc, const int* __restrict__ gidx,
    unsigned short* __restrict__ Chi, unsigned short* __restrict__ Clo,
    int ldhl, int nhl, int voff)
{
    __shared__ unsigned short Ah[64 * 40];
    __shared__ unsigned short Al[64 * 40];
    __shared__ unsigned short Bh[128 * 40];
    __shared__ unsigned short Bl[128 * 40];

    int bm = blockIdx.y << 6, bn = blockIdx.x << 7;
    int tid = threadIdx.x;
    int lane = tid & 63, wid = tid >> 6;
    int wm = wid >> 1, wn = wid & 1;
    int fr = lane & 15, kg = (lane >> 4) << 3;

    int ar = tid >> 2, akc = (tid & 3) << 3;
    int bnr = tid >> 1, bkc = (tid & 1) << 4;

    long long arow; bool avalid;
    {
        int gr = bm + ar;
        avalid = gr < M;
        if (GATHER) arow = avalid ? (long long)gidx[gr] : 0;
        else        arow = avalid ? (long long)gr : 0;
    }

    f32x4 acc[2][4] = {};

    for (int k0 = 0; k0 < K; k0 += 32) {
        float vv[8];
        if (avalid) {
            float4 v0 = *(const float4*)&A[arow * lda + k0 + akc];
            float4 v1 = *(const float4*)&A[arow * lda + k0 + akc + 4];
            vv[0] = v0.x; vv[1] = v0.y; vv[2] = v0.z; vv[3] = v0.w;
            vv[4] = v1.x; vv[5] = v1.y; vv[6] = v1.z; vv[7] = v1.w;
        } else {
            #pragma unroll
            for (int e = 0; e < 8; ++e) vv[e] = 0.f;
        }
        union { unsigned short u[8]; u32x4 v; } ph, pl;
        #pragma unroll
        for (int e = 0; e < 8; ++e) {
            unsigned short h = f2bf(vv[e]);
            ph.u[e] = h;
            pl.u[e] = f2bf(vv[e] - bf2f(h));
        }
        *(u32x4*)&Ah[ar * 40 + akc] = ph.v;
        *(u32x4*)&Al[ar * 40 + akc] = pl.v;

        {
            long long boff = (long long)(bn + bnr) * K + k0 + bkc;
            *(u32x4*)&Bh[bnr * 40 + bkc]     = *(const u32x4*)&Bth[boff];
            *(u32x4*)&Bh[bnr * 40 + bkc + 8] = *(const u32x4*)&Bth[boff + 8];
            *(u32x4*)&Bl[bnr * 40 + bkc]     = *(const u32x4*)&Btl[boff];
            *(u32x4*)&Bl[bnr * 40 + bkc + 8] = *(const u32x4*)&Btl[boff + 8];
        }
        __syncthreads();

        bf16x8 af[2], alf[2], bfj[4], blf[4];
        #pragma unroll
        for (int i = 0; i < 2; ++i) {
            int row = wm * 32 + i * 16 + fr;
            af[i]  = *(const bf16x8*)&Ah[row * 40 + kg];
            alf[i] = *(const bf16x8*)&Al[row * 40 + kg];
        }
        #pragma unroll
        for (int j = 0; j < 4; ++j) {
            int row = wn * 64 + j * 16 + fr;
            bfj[j] = *(const bf16x8*)&Bh[row * 40 + kg];
            blf[j] = *(const bf16x8*)&Bl[row * 40 + kg];
        }
        #pragma unroll
        for (int i = 0; i < 2; ++i)
        #pragma unroll
        for (int j = 0; j < 4; ++j) {
            acc[i][j] = __builtin_amdgcn_mfma_f32_16x16x32_bf16(af[i],  bfj[j], acc[i][j], 0, 0, 0);
            acc[i][j] = __builtin_amdgcn_mfma_f32_16x16x32_bf16(af[i],  blf[j], acc[i][j], 0, 0, 0);
            acc[i][j] = __builtin_amdgcn_mfma_f32_16x16x32_bf16(alf[i], bfj[j], acc[i][j], 0, 0, 0);
        }
        __syncthreads();
    }

    #pragma unroll
    for (int i = 0; i < 2; ++i) {
        int rbase = bm + wm * 32 + i * 16 + ((lane >> 4) << 2);
        #pragma unroll
        for (int j = 0; j < 4; ++j) {
            int ccol = bn + wn * 64 + j * 16 + fr;
            float bv = bias[ccol];
            #pragma unroll
            for (int r = 0; r < 4; ++r) {
                int row = rbase + r;
                if (row < M) {
                    float val = acc[i][j][r] + bv;
                    if (SPLIT) {
                        if (ccol < nhl) {
                            unsigned short hh = f2bf(val);
                            Chi[(long long)row * ldhl + ccol] = hh;
                            Clo[(long long)row * ldhl + ccol] = f2bf(val - bf2f(hh));
                        } else {
                            C[(long long)row * ldc + (ccol - voff)] = val;
                        }
                    } else {
                        if (EPI == 1) val = mishf(val);
                        if (EPI == 2) val = fmaxf(val, 0.f);
                        C[(long long)row * ldc + ccol] = val;
                    }
                }
            }
        }
    }
}

// ---------------------------------------------------------------------------
// Weight prep kernels (write-coalesced: consecutive threads -> consecutive k)
// ---------------------------------------------------------------------------
__global__ __launch_bounds__(256) void prep_wqkv(
    const float* __restrict__ wq, const float* __restrict__ wk,
    const float* __restrict__ wv,
    unsigned short* __restrict__ whi, unsigned short* __restrict__ wlo, int o)
{
    int idx = blockIdx.x * 256 + threadIdx.x;
    if (idx >= 1536 * 512) return;
    int n = idx >> 9, k = idx & 511;
    int sel = n >> 9, col = n & 511;
    const float* W = sel == 0 ? wq : (sel == 1 ? wk : wv);
    float v = W[(long long)o * 262144 + k * 512 + col];
    unsigned short h = f2bf(v);
    whi[idx] = h;
    wlo[idx] = f2bf(v - bf2f(h));
}

__global__ __launch_bounds__(256) void prep_woiw(
    const float* __restrict__ wo, const float* __restrict__ wi,
    const float* __restrict__ wout,
    unsigned short* __restrict__ whi, unsigned short* __restrict__ wlo, int o)
{
    int idx = blockIdx.x * 256 + threadIdx.x;
    if (idx >= 655360) return;
    float v;
    if (idx < 262144) {
        int n = idx >> 9, k = idx & 511;
        v = wo[(long long)o * 262144 + k * 512 + n];
    } else if (idx < 524288) {
        int nk = idx - 262144;
        int n = nk >> 9, k = nk & 511;
        v = wi[(long long)o * 262144 + k * 512 + n];
    } else {
        int nk = idx - 524288;
        int n = nk >> 9, k = nk & 511;   // n < 256
        v = wout[(long long)o * 131072 + k * 256 + n];
    }
    unsigned short h = f2bf(v);
    whi[idx] = h;
    wlo[idx] = f2bf(v - bf2f(h));
}

// conv weights: [3][256][256] -> [256][768] hi/lo
__global__ __launch_bounds__(256) void prep_wcnn(
    const float* __restrict__ w,
    unsigned short* __restrict__ whi, unsigned short* __restrict__ wlo)
{
    int idx = blockIdx.x * 256 + threadIdx.x;
    if (idx >= 256 * 768) return;
    int n = idx / 768, k = idx % 768;
    float v = w[k * 256 + n];
    unsigned short h = f2bf(v);
    whi[idx] = h;
    wlo[idx] = f2bf(v - bf2f(h));
}

__global__ void pack_bqkv(const float* __restrict__ bq, const float* __restrict__ bk,
                          const float* __restrict__ bv, float* __restrict__ bqkv)
{
    int idx = blockIdx.x * 256 + threadIdx.x;
    if (idx >= 6144) return;
    int o = idx / 1536, n = idx % 1536;
    float v;
    if (n < 512) v = bq[o * 512 + n];
    else if (n < 1024) v = bk[o * 512 + n - 512];
    else v = bv[o * 512 + n - 1024];
    bqkv[idx] = v;
}

__global__ void zero_guards(float* __restrict__ f1pad)
{
    int i = blockIdx.x * 256 + threadIdx.x;
    if (i >= 4096) return;
    int b = i >> 9, rem = i & 511;
    int row = b * 402 + (rem < 256 ? 0 : 401);
    f1pad[(long long)row * 256 + (rem & 255)] = 0.f;
}

__global__ void conv_gidx_kernel(int* __restrict__ g)
{
    int i = blockIdx.x * 256 + threadIdx.x;
    if (i < 3200) g[i] = (i / 400) * 402 + (i % 400);
}

__global__ void masks_kernel(const float* __restrict__ x, float* __restrict__ mk)
{
    int i = blockIdx.x * 256 + threadIdx.x;
    if (i >= 3200) return;
    const float* xr = x + (long long)i * 128;
    mk[0 * 3200 + i] = xr[4];
    mk[1 * 3200 + i] = fmaxf(xr[2], xr[3]);
    mk[2 * 3200 + i] = xr[0];
    mk[3 * 3200 + i] = xr[1];
}

__global__ void relidx_kernel(int* __restrict__ T)
{
    int i = blockIdx.x * blockDim.x + threadIdx.x;
    if (i >= 799) return;
    int rel = i - 399;
    int sgn = (rel > 0) - (rel < 0);
    int ab = (rel < 300 && rel > -300) ? 299 : (rel < 0 ? -rel : rel);
    long long bpos;
    if (ab <= 300) bpos = rel;
    else {
        double lp = ceil(log((double)ab / 300.0) / log(599.0 / 300.0) * 299.0) + 300.0;
        bpos = (long long)lp * sgn;
    }
    long long c2p = bpos + 600;
    c2p = c2p < 0 ? 0 : (c2p > 1199 ? 1199 : c2p);
    T[i] = (int)c2p;
}

// ---------------------------------------------------------------------------
// LayerNorm, wave-per-row (4 rows/block). eps 1e-7.
// ---------------------------------------------------------------------------
template<bool RES, int HD>
__global__ __launch_bounds__(256) void ln2_kernel(
    const float* __restrict__ X, const float* __restrict__ R,
    const float* __restrict__ g, const float* __restrict__ be,
    float* __restrict__ Y, int rows)
{
    constexpr int EPL = HD / 64;
    int wv = threadIdx.x >> 6, lane = threadIdx.x & 63;
    long long row = (long long)blockIdx.x * 4 + wv;
    if (row >= rows) return;
    const float* x = X + row * HD;
    float v[EPL];
    #pragma unroll
    for (int q = 0; q < EPL / 4; ++q) {
        float4 a = *(const float4*)&x[lane * EPL + q * 4];
        v[q*4+0] = a.x; v[q*4+1] = a.y; v[q*4+2] = a.z; v[q*4+3] = a.w;
        if (RES) {
            float4 rr = *(const float4*)&R[row * HD + lane * EPL + q * 4];
            v[q*4+0] += rr.x; v[q*4+1] += rr.y; v[q*4+2] += rr.z; v[q*4+3] += rr.w;
        }
    }
    float s = 0.f;
    #pragma unroll
    for (int e = 0; e < EPL; ++e) s += v[e];
    #pragma unroll
    for (int d = 1; d < 64; d <<= 1) s += __shfl_xor(s, d, 64);
    float mean = s * (1.f / HD);
    float s2 = 0.f;
    #pragma unroll
    for (int e = 0; e < EPL; ++e) { float d0 = v[e] - mean; s2 += d0 * d0; }
    #pragma unroll
    for (int d = 1; d < 64; d <<= 1) s2 += __shfl_xor(s2, d, 64);
    float inv = 1.f / sqrtf(s2 * (1.f / HD) + 1e-7f);
    #pragma unroll
    for (int q = 0; q < EPL / 4; ++q) {
        int c = lane * EPL + q * 4;
        float4 gg = *(const float4*)&g[c];
        float4 bb = *(const float4*)&be[c];
        float4 o;
        o.x = (v[q*4+0] - mean) * inv * gg.x + bb.x;
        o.y = (v[q*4+1] - mean) * inv * gg.y + bb.y;
        o.z = (v[q*4+2] - mean) * inv * gg.z + bb.z;
        o.w = (v[q*4+3] - mean) * inv * gg.w + bb.w;
        *(float4*)&Y[row * HD + c] = o;
    }
}

// ---------------------------------------------------------------------------
// MFMA fused disentangled flash attention, round 5:
//  - 5 barriers/tile (was 7), register softmax via shfl_xor row reductions
//  - P stored bf16-split in LDS (PV reads fragments directly)
//  - V staged transposed with packed u32 writes
// Block = (l-tile 32, head, batch), 256 thr = 4 waves.
// ---------------------------------------------------------------------------
__global__ __launch_bounds__(256) void attn_kernel(
    const unsigned short* __restrict__ qk_hi, const unsigned short* __restrict__ qk_lo,
    const float* __restrict__ vbuf,
    const unsigned short* __restrict__ pkg_hi, const unsigned short* __restrict__ pkg_lo,
    const float* __restrict__ mask, float* __restrict__ ctx)
{
    const float scale = 0.07216878364870322f;       // 1/sqrt(64*3)
    const float NEGMIN = -3.402823466e38f;
    int lt = blockIdx.x, h = blockIdx.y, b = blockIdx.z;
    int l0 = lt * 32;
    int tid = threadIdx.x;
    int lane = tid & 63, w = tid >> 6;
    int wrf = w >> 1;      // Q row-frag index
    int wcf = w & 1;       // K col-frag index
    int fr = lane & 15, kg8 = (lane >> 4) << 3;
    int rbase = (lane >> 4) << 2;

    __shared__ unsigned short Kh[32 * 72], Kl[32 * 72];
    __shared__ unsigned short Vth[64 * 40], Vtl[64 * 40];
    __shared__ float T2s[32 * 68], T3s[32 * 68];
    __shared__ unsigned short Sth[32 * 40], Stl[32 * 40];
    __shared__ float redmx[2][32], redsum[2][32];
    __shared__ float mstate[32], lstate[32], wlv[32], wmv[32];

    // Q frags once
    bf16x8 qfh[2], qfl[2];
    {
        int qi = l0 + wrf * 16 + fr;
        bool valid = qi < 400;
        long long base = ((long long)(b * 400 + (valid ? qi : 0))) * 1024 + h * 64 + kg8;
        #pragma unroll
        for (int kk = 0; kk < 2; ++kk) {
            qfh[kk] = load_bf8(qk_hi + base + kk * 32, valid);
            qfl[kk] = load_bf8(qk_lo + base + kk * 32, valid);
        }
    }
    if (tid < 32) {
        int lg = l0 + tid;
        wlv[tid] = (lg < 400) ? mask[b * 400 + lg] : 0.f;
        mstate[tid] = -INFINITY;
        lstate[tid] = 0.f;
    }
    f32x4 O[2] = {};
    int irow[4];
    #pragma unroll
    for (int r = 0; r < 4; ++r) irow[r] = wrf * 16 + rbase + r;
    int jcol = wcf * 16 + fr;

    for (int mt = 0; mt < 13; ++mt) {
        int m0 = mt * 32;
        int D0 = l0 - m0 + 368;
        __syncthreads();   // s1: prev PV done
        // ---- stage K hi/lo (row = tid&31, seg = (tid>>5)*8) ----
        {
            int row = tid & 31, seg = (tid >> 5) << 3;
            bool valid = (m0 + row) < 400;
            long long src = ((long long)(b * 400 + (valid ? m0 + row : 0))) * 1024 + 512 + h * 64 + seg;
            *(bf16x8*)&Kh[row * 72 + seg] = load_bf8(qk_hi + src, valid);
            *(bf16x8*)&Kl[row * 72 + seg] = load_bf8(qk_lo + src, valid);
        }
        // ---- stage V transposed, packed-pair u32 writes ----
        {
            int jj = tid & 15;            // j pair
            int dg = tid >> 4;            // 0..15 -> d group of 4
            int j0g = jj << 1;
            bool v0 = (m0 + j0g) < 400, v1 = (m0 + j0g + 1) < 400;
            float4 va = make_float4(0.f, 0.f, 0.f, 0.f), vb = va;
            const float* vp0 = &vbuf[((long long)(b * 400 + m0 + j0g)) * 512 + h * 64 + (dg << 2)];
            if (v0) va = *(const float4*)vp0;
            if (v1) vb = *(const float4*)(vp0 + 512);
            float fa[4] = {va.x, va.y, va.z, va.w};
            float fb[4] = {vb.x, vb.y, vb.z, vb.w};
            #pragma unroll
            for (int e = 0; e < 4; ++e) {
                int d = (dg << 2) + e;
                unsigned short h0 = f2bf(fa[e]), h1 = f2bf(fb[e]);
                *(unsigned int*)&Vth[d * 40 + j0g] = (unsigned int)h0 | ((unsigned int)h1 << 16);
                unsigned short l0v = f2bf(fa[e] - bf2f(h0)), l1v = f2bf(fb[e] - bf2f(h1));
                *(unsigned int*)&Vtl[d * 40 + j0g] = (unsigned int)l0v | ((unsigned int)l1v << 16);
            }
        }
        if (tid < 32) wmv[tid] = (m0 + tid < 400) ? mask[b * 400 + m0 + tid] : 0.f;
        // ---- band fragments -> registers ----
        bf16x8 b2h[2][2], b2l[2][2], b3h[2][2], b3l[2][2];
        #pragma unroll
        for (int c = 0; c < 2; ++c) {
            int row2 = D0 + (2 * wcf + c) * 16 + fr;
            int row3 = D0 + (2 * wrf + c) * 16 + fr;
            bool v2 = (unsigned)row2 < 799u;
            bool v3 = (unsigned)row3 < 799u;
            #pragma unroll
            for (int kk = 0; kk < 2; ++kk) {
                long long o2 = (long long)(v2 ? row2 : 0) * 1024 + 512 + h * 64 + kk * 32 + kg8;
                long long o3 = (long long)(v3 ? row3 : 0) * 1024 + h * 64 + kk * 32 + kg8;
                b2h[c][kk] = load_bf8(pkg_hi + o2, v2);
                b2l[c][kk] = load_bf8(pkg_lo + o2, v2);
                b3h[c][kk] = load_bf8(pkg_hi + o3, v3);
                b3l[c][kk] = load_bf8(pkg_lo + o3, v3);
            }
        }
        __syncthreads();   // s2: staging visible
        // ---- K frags from LDS ----
        bf16x8 kfh[2], kfl[2];
        #pragma unroll
        for (int kk = 0; kk < 2; ++kk) {
            kfh[kk] = *(const bf16x8*)&Kh[(wcf * 16 + fr) * 72 + kk * 32 + kg8];
            kfl[kk] = *(const bf16x8*)&Kl[(wcf * 16 + fr) * 72 + kk * 32 + kg8];
        }
        // ---- T1 = Q@K^T ----
        f32x4 aT1 = {};
        #pragma unroll
        for (int kk = 0; kk < 2; ++kk) {
            aT1 = __builtin_amdgcn_mfma_f32_16x16x32_bf16(qfh[kk], kfh[kk], aT1, 0, 0, 0);
            aT1 = __builtin_amdgcn_mfma_f32_16x16x32_bf16(qfh[kk], kfl[kk], aT1, 0, 0, 0);
            aT1 = __builtin_amdgcn_mfma_f32_16x16x32_bf16(qfl[kk], kfh[kk], aT1, 0, 0, 0);
        }
        // ---- T2 = Q@PKband^T, T3 = K@PQband^T ----
        f32x4 aT2[2] = {{0.f,0.f,0.f,0.f},{0.f,0.f,0.f,0.f}};
        f32x4 aT3[2] = {{0.f,0.f,0.f,0.f},{0.f,0.f,0.f,0.f}};
        #pragma unroll
        for (int c = 0; c < 2; ++c)
        #pragma unroll
        for (int kk = 0; kk < 2; ++kk) {
            aT2[c] = __builtin_amdgcn_mfma_f32_16x16x32_bf16(qfh[kk], b2h[c][kk], aT2[c], 0, 0, 0);
            aT2[c] = __builtin_amdgcn_mfma_f32_16x16x32_bf16(qfh[kk], b2l[c][kk], aT2[c], 0, 0, 0);
            aT2[c] = __builtin_amdgcn_mfma_f32_16x16x32_bf16(qfl[kk], b2h[c][kk], aT2[c], 0, 0, 0);
            aT3[c] = __builtin_amdgcn_mfma_f32_16x16x32_bf16(kfh[kk], b3h[c][kk], aT3[c], 0, 0, 0);
            aT3[c] = __builtin_amdgcn_mfma_f32_16x16x32_bf16(kfh[kk], b3l[c][kk], aT3[c], 0, 0, 0);
            aT3[c] = __builtin_amdgcn_mfma_f32_16x16x32_bf16(kfl[kk], b3h[c][kk], aT3[c], 0, 0, 0);
        }
        // ---- write T2/T3 frags to LDS ----
        {
            int rB2 = wrf * 16 + rbase;
            int rB3 = wcf * 16 + rbase;
            #pragma unroll
            for (int c = 0; c < 2; ++c) {
                int cc2 = (2 * wcf + c) * 16 + fr;
                int cc3 = (2 * wrf + c) * 16 + fr;
                #pragma unroll
                for (int r = 0; r < 4; ++r) {
                    T2s[(rB2 + r) * 68 + cc2] = aT2[c][r];
                    T3s[(rB3 + r) * 68 + cc3] = aT3[c][r];
                }
            }
        }
        __syncthreads();   // s3
        // ---- assemble scores in registers ----
        float sc[4], mo[4];
        bool jv = (m0 + jcol) < 400;
        float wmj = wmv[jcol];
        #pragma unroll
        for (int r = 0; r < 4; ++r) {
            int i = irow[r];
            int rr = i - jcol + 31;
            float s;
            if (!jv) s = -INFINITY;
            else if (wlv[i] != 0.f && wmj != 0.f)
                s = (aT1[r] + T2s[i * 68 + rr] + T3s[jcol * 68 + rr]) * scale;
            else s = NEGMIN;
            sc[r] = s;
            mo[r] = mstate[i];
        }
        // ---- wave row-max over fr (16 lanes) ----
        float mx[4] = {sc[0], sc[1], sc[2], sc[3]};
        #pragma unroll
        for (int d = 1; d < 16; d <<= 1) {
            #pragma unroll
            for (int r = 0; r < 4; ++r) mx[r] = fmaxf(mx[r], __shfl_xor(mx[r], d, 64));
        }
        if (fr == 0) {
            #pragma unroll
            for (int r = 0; r < 4; ++r) redmx[wcf][irow[r]] = mx[r];
        }
        __syncthreads();   // s4
        float corr[4], mn[4];
        #pragma unroll
        for (int r = 0; r < 4; ++r) {
            int i = irow[r];
            float pm = fmaxf(redmx[0][i], redmx[1][i]);
            mn[r] = fmaxf(mo[r], pm);
            corr[r] = expf(mo[r] - mn[r]);
        }
        if (wcf == 0 && fr == 0) {
            #pragma unroll
            for (int r = 0; r < 4; ++r) mstate[irow[r]] = mn[r];
        }
        // ---- exp + wave row-sum; write P bf16 split ----
        float p[4], rs[4];
        #pragma unroll
        for (int r = 0; r < 4; ++r) { p[r] = expf(sc[r] - mn[r]); rs[r] = p[r]; }
        #pragma unroll
        for (int d = 1; d < 16; d <<= 1) {
            #pragma unroll
            for (int r = 0; r < 4; ++r) rs[r] += __shfl_xor(rs[r], d, 64);
        }
        if (fr == 0) {
            #pragma unroll
            for (int r = 0; r < 4; ++r) redsum[wcf][irow[r]] = rs[r];
        }
        #pragma unroll
        for (int r = 0; r < 4; ++r) {
            unsigned short hh = f2bf(p[r]);
            Sth[irow[r] * 40 + jcol] = hh;
            Stl[irow[r] * 40 + jcol] = f2bf(p[r] - bf2f(hh));
        }
        __syncthreads();   // s5
        if (wcf == 0 && fr == 0) {
            #pragma unroll
            for (int r = 0; r < 4; ++r) {
                int i = irow[r];
                lstate[i] = lstate[i] * corr[r] + redsum[0][i] + redsum[1][i];
            }
        }
        // ---- PV via MFMA ----
        #pragma unroll
        for (int f = 0; f < 2; ++f)
        #pragma unroll
        for (int r = 0; r < 4; ++r) O[f][r] *= corr[r];
        bf16x8 Pha = *(const bf16x8*)&Sth[(wrf * 16 + fr) * 40 + kg8];
        bf16x8 Pla = *(const bf16x8*)&Stl[(wrf * 16 + fr) * 40 + kg8];
        #pragma unroll
        for (int f = 0; f < 2; ++f) {
            int d = wcf * 32 + f * 16 + fr;
            bf16x8 Vh = *(const bf16x8*)&Vth[d * 40 + kg8];
            bf16x8 Vl = *(const bf16x8*)&Vtl[d * 40 + kg8];
            O[f] = __builtin_amdgcn_mfma_f32_16x16x32_bf16(Pha, Vh, O[f], 0, 0, 0);
            O[f] = __builtin_amdgcn_mfma_f32_16x16x32_bf16(Pha, Vl, O[f], 0, 0, 0);
            O[f] = __builtin_amdgcn_mfma_f32_16x16x32_bf16(Pla, Vh, O[f], 0, 0, 0);
        }
    }
    __syncthreads();
    // ---- write ctx ----
    #pragma unroll
    for (int f = 0; f < 2; ++f) {
        int colg = h * 64 + wcf * 32 + f * 16 + fr;
        #pragma unroll
        for (int r = 0; r < 4; ++r) {
            int li = irow[r];
            int lg = l0 + li;
            if (lg < 400)
                ctx[((long long)(b * 400 + lg)) * 512 + colg] = O[f][r] / lstate[li];
        }
    }
}

// ---------------------------------------------------------------------------
// Pool / meanmax / heads
// ---------------------------------------------------------------------------
__global__ __launch_bounds__(256) void pool_kernel(
    const float* __restrict__ oenc, const float* __restrict__ mk,
    float* __restrict__ pooled)
{
    int b = blockIdx.x; int t = threadIdx.x;
    float acc = 0.f, mxv = -INFINITY, sw = 0.f;
    for (int l = 0; l < 400; ++l) {
        float w = mk[b * 400 + l];
        float vv = oenc[((long long)(b * 400 + l)) * 256 + t] * w;
        acc += vv; mxv = fmaxf(mxv, vv); sw += w;
    }
    pooled[b * 512 + t] = acc / (sw + 1e-6f);
    pooled[b * 512 + 256 + t] = mxv;
}

__global__ __launch_bounds__(512) void meanmax_kernel(
    const float* __restrict__ feats, float* __restrict__ mm)
{
    int b = blockIdx.x; int t = threadIdx.x;
    float s = 0.f, mx = -INFINITY;
    for (int l = 0; l < 400; ++l) {
        float vv = feats[((long long)(b * 400 + l)) * 512 + t];
        s += vv; mx = fmaxf(mx, vv);
    }
    mm[b * 1024 + t] = s / 400.f;
    mm[b * 1024 + 512 + t] = mx;
}

__global__ __launch_bounds__(256) void heads_kernel(
    const float* __restrict__ pooled, const float* __restrict__ mm,
    const float* __restrict__ w_bow1, const float* __restrict__ b_bow1,
    const float* __restrict__ w_bow2, const float* __restrict__ b_bow2,
    const float* __restrict__ w_ext1, const float* __restrict__ b_ext1,
    const float* __restrict__ w_ext2, const float* __restrict__ b_ext2,
    const float* __restrict__ w_org1, const float* __restrict__ b_org1,
    const float* __restrict__ w_org2, const float* __restrict__ b_org2,
    float* __restrict__ out)
{
    int b = blockIdx.x, role = blockIdx.y;
    int t = threadIdx.x;
    __shared__ float inb[1024];
    __shared__ float red[256];
    __shared__ float hid[256];
    if (role == 0) {
        inb[t] = pooled[b * 512 + t];
        inb[256 + t] = pooled[b * 512 + 256 + t];
        __syncthreads();
        float acc = b_bow1[t];
        for (int j = 0; j < 512; ++j) acc += inb[j] * w_bow1[j * 256 + t];
        red[t] = mishf(acc) * w_bow2[t];
        __syncthreads();
        for (int s = 128; s; s >>= 1) { if (t < s) red[t] += red[t + s]; __syncthreads(); }
        if (t == 0) out[b * 11 + 0] = red[0] + b_bow2[0];
    } else if (role == 1) {
        inb[t] = mm[b * 1024 + t];
        inb[256 + t] = mm[b * 1024 + 256 + t];
        inb[512 + t] = mm[b * 1024 + 512 + t];
        inb[768 + t] = mm[b * 1024 + 768 + t];
        __syncthreads();
        float acc = b_ext1[t];
        for (int j = 0; j < 1024; ++j) acc += inb[j] * w_ext1[j * 256 + t];
        red[t] = mishf(acc) * w_ext2[t];
        __syncthreads();
        for (int s = 128; s; s >>= 1) { if (t < s) red[t] += red[t + s]; __syncthreads(); }
        if (t == 0) { out[b * 11 + 1] = red[0] + b_ext2[0]; out[88 + b] = 0.f; }
    } else {
        int i = role - 2;
        inb[t] = pooled[((1 + i) * 8 + b) * 512 + t];
        inb[256 + t] = pooled[((1 + i) * 8 + b) * 512 + 256 + t];
        __syncthreads();
        float acc = b_org1[i * 256 + t];
        for (int j = 0; j < 512; ++j)
            acc += inb[j] * w_org1[((long long)i * 512 + j) * 256 + t];
        hid[t] = mishf(acc);
        __syncthreads();
        for (int c = 0; c < 3; ++c) {
            red[t] = hid[t] * w_org2[(i * 256 + t) * 3 + c];
            __syncthreads();
            for (int s = 128; s; s >>= 1) { if (t < s) red[t] += red[t + s]; __syncthreads(); }
            if (t == 0) out[b * 11 + 2 + i * 3 + c] = red[0] + b_org2[i * 3 + c];
            __syncthreads();
        }
    }
}

// ---------------------------------------------------------------------------
// Launch
// ---------------------------------------------------------------------------
extern "C" void kernel_launch(void* const* d_in, const int* in_sizes, int n_in,
                              void* d_out, int out_size, void* d_ws, size_t ws_size,
                              hipStream_t stream)
{
    const float* x      = (const float*)d_in[0];
    const float* w_mlp  = (const float*)d_in[1];
    const float* b_mlp  = (const float*)d_in[2];
    const float* w_cnn  = (const float*)d_in[3];
    const float* b_cnn  = (const float*)d_in[4];
    const float* rel_emb= (const float*)d_in[5];
    const float* rel_g  = (const float*)d_in[6];
    const float* rel_b  = (const float*)d_in[7];
    const float* wq     = (const float*)d_in[8];
    const float* wk     = (const float*)d_in[9];
    const float* wv     = (const float*)d_in[10];
    const float* wo     = (const float*)d_in[11];
    const float* wi     = (const float*)d_in[12];
    const float* bq     = (const float*)d_in[13];
    const float* bk     = (const float*)d_in[14];
    const float* bv     = (const float*)d_in[15];
    const float* bo     = (const float*)d_in[16];
    const float* bi     = (const float*)d_in[17];
    const float* wout   = (const float*)d_in[18];
    const float* bout   = (const float*)d_in[19];
    const float* ln1g   = (const float*)d_in[20];
    const float* ln1b   = (const float*)d_in[21];
    const float* ln2g   = (const float*)d_in[22];
    const float* ln2b   = (const float*)d_in[23];
    const float* w_bow1 = (const float*)d_in[24];
    const float* b_bow1 = (const float*)d_in[25];
    const float* w_bow2 = (const float*)d_in[26];
    const float* b_bow2 = (const float*)d_in[27];
    const float* w_ext1 = (const float*)d_in[28];
    const float* b_ext1 = (const float*)d_in[29];
    const float* w_ext2 = (const float*)d_in[30];
    const float* b_ext2 = (const float*)d_in[31];
    const float* w_org1 = (const float*)d_in[32];
    const float* b_org1 = (const float*)d_in[33];
    const float* w_org2 = (const float*)d_in[34];
    const float* b_org2 = (const float*)d_in[35];

    float* ws = (float*)d_ws;
    float* featsb  = ws + 0;           // 1,638,400
    float* vbuf    = ws + 1638400;     // 1,638,400 (V fp32 / WO-out / WI-out)
    float* ctxB    = ws + 3276800;     // 1,638,400 (f1pad first, then ctx/outenc/outln)
    float* rellnb  = ws + 4915200;     //   614,400
    unsigned short* qkv_hi = (unsigned short*)(ws + 5529600);   // 3200x1024 ushort
    unsigned short* qkv_lo = (unsigned short*)(ws + 7168000);
    unsigned short* pkg_hi = (unsigned short*)(ws + 8806400);   // 799x1024 ushort
    unsigned short* pkg_lo = (unsigned short*)(ws + 9216000);
    unsigned short* whi    = (unsigned short*)(ws + 9625600);   // 786,432 ushort
    unsigned short* wlo    = (unsigned short*)(ws + 10018816);
    float* bqkvb   = ws + 10412032;    //     6,144
    float* masksb  = ws + 10418176;    //    12,800
    float* pooledb = ws + 10430976;    //    16,384
    float* mmb     = ws + 10447360;    //     8,192
    int*   relidx  = (int*)(ws + 10455552);  //   800 ints
    unsigned short* wcnn_hi = (unsigned short*)(ws + 10456448); // 196,608 ushort
    unsigned short* wcnn_lo = (unsigned short*)(ws + 10554752); // 196,608 ushort
    int*   convidx = (int*)(ws + 10653056);  // 3,200 ints
    float* f1pad   = ctxB;             // 3216 x 256 (aliased; used before attn)
    float* outf    = (float*)d_out;

    // front: f1 -> featsb cols 0..255 AND f1pad (padded conv layout)
    gemm_bias<1, true><<<dim3(4, 50), 256, 0, stream>>>(
        x, w_mlp, b_mlp, featsb, f1pad, 3200, 256, 128, 512);
    zero_guards<<<16, 256, 0, stream>>>(f1pad);
    conv_gidx_kernel<<<13, 256, 0, stream>>>(convidx);
    masks_kernel<<<13, 256, 0, stream>>>(x, masksb);
    relidx_kernel<<<4, 256, 0, stream>>>(relidx);
    pack_bqkv<<<24, 256, 0, stream>>>(bq, bk, bv, bqkvb);
    prep_wcnn<<<768, 256, 0, stream>>>(w_cnn, wcnn_hi, wcnn_lo);
    // conv as MFMA GEMM: feats cols 256..511 = relu(f1pad-window @ wcnn^T)
    gemm_mfma<2, true, false><<<dim3(2, 50), 256, 0, stream>>>(
        f1pad, wcnn_hi, wcnn_lo, b_cnn, featsb + 256, 3200, 768, 256, 512, convidx,
        nullptr, nullptr, 0, 0, 0);

    for (int o = 0; o < 4; ++o) {
        ln2_kernel<false, 512><<<300, 256, 0, stream>>>(
            rel_emb + (long long)o * 614400, nullptr,
            rel_g + o * 512, rel_b + o * 512, rellnb, 1200);
        prep_wqkv<<<3072, 256, 0, stream>>>(wq, wk, wv, whi, wlo, o);
        // PQK: gathered rel projections -> pkg hi/lo [799][1024] (pq|pk)
        gemm_mfma<0, true, true><<<dim3(8, 13), 256, 0, stream>>>(
            rellnb, whi, wlo, bqkvb + o * 1536, vbuf, 799, 512, 512, 512, relidx,
            pkg_hi, pkg_lo, 1024, 1024, 1 << 30);
        // QKV: feats -> qk hi/lo [3200][1024] + v fp32 [3200][512]
        gemm_mfma<0, false, true><<<dim3(12, 50), 256, 0, stream>>>(
            featsb, whi, wlo, bqkvb + o * 1536, vbuf, 3200, 512, 512, 512, nullptr,
            qkv_hi, qkv_lo, 1024, 1024, 1024);
        prep_woiw<<<2560, 256, 0, stream>>>(wo, wi, wout, whi, wlo, o);
        attn_kernel<<<dim3(13, 8, 8), 256, 0, stream>>>(qkv_hi, qkv_lo, vbuf,
            pkg_hi, pkg_lo, masksb + o * 3200, ctxB);
        // WO
        gemm_mfma<0, false, false><<<dim3(4, 50), 256, 0, stream>>>(
            ctxB, whi, wlo, bo + o * 512, vbuf, 3200, 512, 512, 512, nullptr,
            nullptr, nullptr, 0, 0, 0);
        ln2_kernel<true, 512><<<800, 256, 0, stream>>>(
            vbuf, featsb, ln1g + o * 512, ln1b + o * 512, ctxB, 3200);
        // WI (mish)
        gemm_mfma<1, false, false><<<dim3(4, 50), 256, 0, stream>>>(
            ctxB, whi + 262144, wlo + 262144, bi + o * 512, vbuf, 3200, 512, 512, 512,
            nullptr, nullptr, nullptr, 0, 0, 0);
        // WOUT
        gemm_mfma<0, false, false><<<dim3(2, 50), 256, 0, stream>>>(
            vbuf, whi + 524288, wlo + 524288, bout + o * 256, ctxB, 3200, 512, 512, 256,
            nullptr, nullptr, nullptr, 0, 0, 0);
        ln2_kernel<false, 256><<<800, 256, 0, stream>>>(
            ctxB, nullptr, ln2g + o * 256, ln2b + o * 256, ctxB + 819200, 3200);
        pool_kernel<<<8, 256, 0, stream>>>(ctxB + 819200, masksb + o * 3200,
                                           pooledb + o * 4096);
    }

    meanmax_kernel<<<8, 512, 0, stream>>>(featsb, mmb);
    heads_kernel<<<dim3(8, 5), 256, 0, stream>>>(pooledb, mmb,
        w_bow1, b_bow1, w_bow2, b_bow2, w_ext1, b_ext1, w_ext2, b_ext2,
        w_org1, b_org1, w_org2, b_org2, outf);
}

// Round 6
// 1253.463 us; speedup vs baseline: 2.1383x; 1.1055x over previous
//
#include <hip/hip_runtime.h>
#include <math.h>

// ---------------------------------------------------------------------------
// Model dims (fixed): B=8 L=400 F=128 D=256 T=256 H=512 NH=8 HD=64 P=1200
// ---------------------------------------------------------------------------

typedef __attribute__((ext_vector_type(8))) short bf16x8;
typedef __attribute__((ext_vector_type(4))) float f32x4;
typedef __attribute__((ext_vector_type(4))) unsigned int u32x4;

__device__ __forceinline__ float mishf(float x) {
    float sp = fmaxf(x, 0.f) + log1pf(expf(-fabsf(x)));   // stable softplus
    return x * tanhf(sp);
}

__device__ __forceinline__ unsigned short f2bf(float f) {
    unsigned int u = __float_as_uint(f);
    u = (u + 0x7fffu + ((u >> 16) & 1u)) >> 16;           // RNE
    return (unsigned short)u;
}
__device__ __forceinline__ float bf2f(unsigned short h) {
    return __uint_as_float(((unsigned int)h) << 16);
}

__device__ __forceinline__ bf16x8 load_bf8(const unsigned short* p, bool valid) {
    bf16x8 z = {0, 0, 0, 0, 0, 0, 0, 0};
    if (valid) z = *(const bf16x8*)p;
    return z;
}

// ---------------------------------------------------------------------------
// fp32 GEMM (front MLP, K=128). DUAL: also write to padded conv layout.
// ---------------------------------------------------------------------------
template<int EPI, bool DUAL>
__global__ __launch_bounds__(256) void gemm_bias(
    const float* __restrict__ A, const float* __restrict__ Bm,
    const float* __restrict__ bias, float* __restrict__ C,
    float* __restrict__ C2,
    int M, int N, int K, int ldc)
{
    __shared__ float As[16][68];
    __shared__ float Bs[16][68];
    int bm = blockIdx.y << 6, bn = blockIdx.x << 6;
    int tid = threadIdx.x;
    int tm = (tid >> 4) << 2, tn = (tid & 15) << 2;
    int ar = tid >> 2, ac4 = (tid & 3) << 2;
    int br = tid >> 4, bc4 = (tid & 15) << 2;
    float acc[4][4] = {};
    for (int k0 = 0; k0 < K; k0 += 16) {
        float4 av = make_float4(0.f, 0.f, 0.f, 0.f);
        if (bm + ar < M)
            av = *(const float4*)&A[(long long)(bm + ar) * K + k0 + ac4];
        As[ac4][ar] = av.x; As[ac4 + 1][ar] = av.y;
        As[ac4 + 2][ar] = av.z; As[ac4 + 3][ar] = av.w;
        *(float4*)&Bs[br][bc4] =
            *(const float4*)&Bm[(long long)(k0 + br) * N + bn + bc4];
        __syncthreads();
        #pragma unroll
        for (int kk = 0; kk < 16; ++kk) {
            float4 a4 = *(const float4*)&As[kk][tm];
            float4 b4 = *(const float4*)&Bs[kk][tn];
            acc[0][0] += a4.x * b4.x; acc[0][1] += a4.x * b4.y;
            acc[0][2] += a4.x * b4.z; acc[0][3] += a4.x * b4.w;
            acc[1][0] += a4.y * b4.x; acc[1][1] += a4.y * b4.y;
            acc[1][2] += a4.y * b4.z; acc[1][3] += a4.y * b4.w;
            acc[2][0] += a4.z * b4.x; acc[2][1] += a4.z * b4.y;
            acc[2][2] += a4.z * b4.z; acc[2][3] += a4.z * b4.w;
            acc[3][0] += a4.w * b4.x; acc[3][1] += a4.w * b4.y;
            acc[3][2] += a4.w * b4.z; acc[3][3] += a4.w * b4.w;
        }
        __syncthreads();
    }
    #pragma unroll
    for (int i = 0; i < 4; ++i) {
        int r = bm + tm + i;
        if (r < M) {
            float v0 = acc[i][0] + bias[bn + tn + 0];
            float v1 = acc[i][1] + bias[bn + tn + 1];
            float v2 = acc[i][2] + bias[bn + tn + 2];
            float v3 = acc[i][3] + bias[bn + tn + 3];
            if (EPI == 1) { v0 = mishf(v0); v1 = mishf(v1); v2 = mishf(v2); v3 = mishf(v3); }
            float4 o; o.x = v0; o.y = v1; o.z = v2; o.w = v3;
            *(float4*)&C[(long long)r * ldc + bn + tn] = o;
            if (DUAL) {
                int rr2 = (r / 400) * 402 + (r % 400) + 1;
                *(float4*)&C2[(long long)rr2 * 256 + bn + tn] = o;
            }
        }
    }
}

// ---------------------------------------------------------------------------
// MFMA bf16x3-split GEMM. B pre-transposed+split [N][K] bf16 hi/lo.
// SPLIT epilogue: cols < nhl -> qk hi/lo [row][col] (ld ldhl);
//                 cols >= nhl (=1024) -> V transposed split vt[(b*512+c-1024)][m] ld 416.
// EPI: 0 none, 1 mish, 2 relu.
// ---------------------------------------------------------------------------
template<int EPI, bool GATHER, bool SPLIT>
__global__ __launch_bounds__(256) void gemm_mfma(
    const float* __restrict__ A,
    const unsigned short* __restrict__ Bth, const unsigned short* __restrict__ Btl,
    const float* __restrict__ bias, float* __restrict__ C,
    int M, int K, int lda, int ldc, const int* __restrict__ gidx,
    unsigned short* __restrict__ Chi, unsigned short* __restrict__ Clo,
    int ldhl, int nhl,
    unsigned short* __restrict__ vthi, unsigned short* __restrict__ vtlo)
{
    __shared__ unsigned short Ah[64 * 40];
    __shared__ unsigned short Al[64 * 40];
    __shared__ unsigned short Bh[128 * 40];
    __shared__ unsigned short Bl[128 * 40];

    int bm = blockIdx.y << 6, bn = blockIdx.x << 7;
    int tid = threadIdx.x;
    int lane = tid & 63, wid = tid >> 6;
    int wm = wid >> 1, wn = wid & 1;
    int fr = lane & 15, kg = (lane >> 4) << 3;

    int ar = tid >> 2, akc = (tid & 3) << 3;
    int bnr = tid >> 1, bkc = (tid & 1) << 4;

    long long arow; bool avalid;
    {
        int gr = bm + ar;
        avalid = gr < M;
        if (GATHER) arow = avalid ? (long long)gidx[gr] : 0;
        else        arow = avalid ? (long long)gr : 0;
    }

    f32x4 acc[2][4] = {};

    for (int k0 = 0; k0 < K; k0 += 32) {
        float vv[8];
        if (avalid) {
            float4 v0 = *(const float4*)&A[arow * lda + k0 + akc];
            float4 v1 = *(const float4*)&A[arow * lda + k0 + akc + 4];
            vv[0] = v0.x; vv[1] = v0.y; vv[2] = v0.z; vv[3] = v0.w;
            vv[4] = v1.x; vv[5] = v1.y; vv[6] = v1.z; vv[7] = v1.w;
        } else {
            #pragma unroll
            for (int e = 0; e < 8; ++e) vv[e] = 0.f;
        }
        union { unsigned short u[8]; u32x4 v; } ph, pl;
        #pragma unroll
        for (int e = 0; e < 8; ++e) {
            unsigned short h = f2bf(vv[e]);
            ph.u[e] = h;
            pl.u[e] = f2bf(vv[e] - bf2f(h));
        }
        *(u32x4*)&Ah[ar * 40 + akc] = ph.v;
        *(u32x4*)&Al[ar * 40 + akc] = pl.v;

        {
            long long boff = (long long)(bn + bnr) * K + k0 + bkc;
            *(u32x4*)&Bh[bnr * 40 + bkc]     = *(const u32x4*)&Bth[boff];
            *(u32x4*)&Bh[bnr * 40 + bkc + 8] = *(const u32x4*)&Bth[boff + 8];
            *(u32x4*)&Bl[bnr * 40 + bkc]     = *(const u32x4*)&Btl[boff];
            *(u32x4*)&Bl[bnr * 40 + bkc + 8] = *(const u32x4*)&Btl[boff + 8];
        }
        __syncthreads();

        bf16x8 af[2], alf[2], bfj[4], blf[4];
        #pragma unroll
        for (int i = 0; i < 2; ++i) {
            int row = wm * 32 + i * 16 + fr;
            af[i]  = *(const bf16x8*)&Ah[row * 40 + kg];
            alf[i] = *(const bf16x8*)&Al[row * 40 + kg];
        }
        #pragma unroll
        for (int j = 0; j < 4; ++j) {
            int row = wn * 64 + j * 16 + fr;
            bfj[j] = *(const bf16x8*)&Bh[row * 40 + kg];
            blf[j] = *(const bf16x8*)&Bl[row * 40 + kg];
        }
        #pragma unroll
        for (int i = 0; i < 2; ++i)
        #pragma unroll
        for (int j = 0; j < 4; ++j) {
            acc[i][j] = __builtin_amdgcn_mfma_f32_16x16x32_bf16(af[i],  bfj[j], acc[i][j], 0, 0, 0);
            acc[i][j] = __builtin_amdgcn_mfma_f32_16x16x32_bf16(af[i],  blf[j], acc[i][j], 0, 0, 0);
            acc[i][j] = __builtin_amdgcn_mfma_f32_16x16x32_bf16(alf[i], bfj[j], acc[i][j], 0, 0, 0);
        }
        __syncthreads();
    }

    #pragma unroll
    for (int i = 0; i < 2; ++i) {
        int rbase = bm + wm * 32 + i * 16 + ((lane >> 4) << 2);
        #pragma unroll
        for (int j = 0; j < 4; ++j) {
            int ccol = bn + wn * 64 + j * 16 + fr;
            float bv = bias[ccol];
            #pragma unroll
            for (int r = 0; r < 4; ++r) {
                int row = rbase + r;
                if (row < M) {
                    float val = acc[i][j][r] + bv;
                    if (SPLIT) {
                        unsigned short hh = f2bf(val);
                        unsigned short ll = f2bf(val - bf2f(hh));
                        if (ccol < nhl) {
                            Chi[(long long)row * ldhl + ccol] = hh;
                            Clo[(long long)row * ldhl + ccol] = ll;
                        } else {
                            int bb = row / 400, m = row - bb * 400;
                            long long vi = ((long long)(bb * 512 + (ccol - 1024))) * 416 + m;
                            vthi[vi] = hh;
                            vtlo[vi] = ll;
                        }
                    } else {
                        if (EPI == 1) val = mishf(val);
                        if (EPI == 2) val = fmaxf(val, 0.f);
                        C[(long long)row * ldc + ccol] = val;
                    }
                }
            }
        }
    }
}

// ---------------------------------------------------------------------------
// Weight prep kernels (write-coalesced)
// ---------------------------------------------------------------------------
__global__ __launch_bounds__(256) void prep_wqkv(
    const float* __restrict__ wq, const float* __restrict__ wk,
    const float* __restrict__ wv,
    unsigned short* __restrict__ whi, unsigned short* __restrict__ wlo, int o)
{
    int idx = blockIdx.x * 256 + threadIdx.x;
    if (idx >= 1536 * 512) return;
    int n = idx >> 9, k = idx & 511;
    int sel = n >> 9, col = n & 511;
    const float* W = sel == 0 ? wq : (sel == 1 ? wk : wv);
    float v = W[(long long)o * 262144 + k * 512 + col];
    unsigned short h = f2bf(v);
    whi[idx] = h;
    wlo[idx] = f2bf(v - bf2f(h));
}

__global__ __launch_bounds__(256) void prep_woiw(
    const float* __restrict__ wo, const float* __restrict__ wi,
    const float* __restrict__ wout,
    unsigned short* __restrict__ whi, unsigned short* __restrict__ wlo, int o)
{
    int idx = blockIdx.x * 256 + threadIdx.x;
    if (idx >= 655360) return;
    float v;
    if (idx < 262144) {
        int n = idx >> 9, k = idx & 511;
        v = wo[(long long)o * 262144 + k * 512 + n];
    } else if (idx < 524288) {
        int nk = idx - 262144;
        int n = nk >> 9, k = nk & 511;
        v = wi[(long long)o * 262144 + k * 512 + n];
    } else {
        int nk = idx - 524288;
        int n = nk >> 9, k = nk & 511;   // n < 256
        v = wout[(long long)o * 131072 + k * 256 + n];
    }
    unsigned short h = f2bf(v);
    whi[idx] = h;
    wlo[idx] = f2bf(v - bf2f(h));
}

// conv weights: [3][256][256] -> [256][768] hi/lo
__global__ __launch_bounds__(256) void prep_wcnn(
    const float* __restrict__ w,
    unsigned short* __restrict__ whi, unsigned short* __restrict__ wlo)
{
    int idx = blockIdx.x * 256 + threadIdx.x;
    if (idx >= 256 * 768) return;
    int n = idx / 768, k = idx % 768;
    float v = w[k * 256 + n];
    unsigned short h = f2bf(v);
    whi[idx] = h;
    wlo[idx] = f2bf(v - bf2f(h));
}

// ---------------------------------------------------------------------------
// Fused setup: masks, convidx, relidx, f1pad guards, bqkv pack, vt pad zero
// ---------------------------------------------------------------------------
__global__ __launch_bounds__(256) void setup_kernel(
    const float* __restrict__ x,
    const float* __restrict__ bq, const float* __restrict__ bk,
    const float* __restrict__ bv,
    float* __restrict__ mk, int* __restrict__ relT, int* __restrict__ convidx,
    float* __restrict__ f1pad, float* __restrict__ bqkv,
    unsigned short* __restrict__ vt_hi, unsigned short* __restrict__ vt_lo)
{
    int i = blockIdx.x * 256 + threadIdx.x;
    if (i < 3200) {
        const float* xr = x + (long long)i * 128;
        mk[i] = xr[4];
        mk[3200 + i] = fmaxf(xr[2], xr[3]);
        mk[6400 + i] = xr[0];
        mk[9600 + i] = xr[1];
        convidx[i] = (i / 400) * 402 + (i % 400);
    }
    int j = i - 3200;
    if (j >= 0 && j < 799) {
        int rel = j - 399;
        int sgn = (rel > 0) - (rel < 0);
        int ab = (rel < 300 && rel > -300) ? 299 : (rel < 0 ? -rel : rel);
        long long bpos;
        if (ab <= 300) bpos = rel;
        else {
            double lp = ceil(log((double)ab / 300.0) / log(599.0 / 300.0) * 299.0) + 300.0;
            bpos = (long long)lp * sgn;
        }
        long long c2p = bpos + 600;
        c2p = c2p < 0 ? 0 : (c2p > 1199 ? 1199 : c2p);
        relT[j] = (int)c2p;
    }
    int k = i - 4000;
    if (k >= 0 && k < 4096) {
        int b = k >> 9, rem = k & 511;
        int row = b * 402 + (rem < 256 ? 0 : 401);
        f1pad[(long long)row * 256 + (rem & 255)] = 0.f;
    }
    int m = i - 8100;
    if (m >= 0 && m < 6144) {
        int o = m / 1536, n = m % 1536;
        float v;
        if (n < 512) v = bq[o * 512 + n];
        else if (n < 1024) v = bk[o * 512 + n - 512];
        else v = bv[o * 512 + n - 1024];
        bqkv[m] = v;
    }
    int v = i - 14244;
    if (v >= 0 && v < 65536) {   // vt pad [m 400..416) zero, as u32
        int vb = v & 32767;
        int row = vb >> 3, c = vb & 7;
        unsigned int* p = (unsigned int*)(v < 32768 ? vt_hi : vt_lo);
        p[row * 208 + 200 + c] = 0u;
    }
}

// ---------------------------------------------------------------------------
// LayerNorm, wave-per-row (4 rows/block). eps 1e-7.
// ---------------------------------------------------------------------------
template<bool RES, int HD>
__global__ __launch_bounds__(256) void ln2_kernel(
    const float* __restrict__ X, const float* __restrict__ R,
    const float* __restrict__ g, const float* __restrict__ be,
    float* __restrict__ Y, int rows)
{
    constexpr int EPL = HD / 64;
    int wv = threadIdx.x >> 6, lane = threadIdx.x & 63;
    long long row = (long long)blockIdx.x * 4 + wv;
    if (row >= rows) return;
    const float* x = X + row * HD;
    float v[EPL];
    #pragma unroll
    for (int q = 0; q < EPL / 4; ++q) {
        float4 a = *(const float4*)&x[lane * EPL + q * 4];
        v[q*4+0] = a.x; v[q*4+1] = a.y; v[q*4+2] = a.z; v[q*4+3] = a.w;
        if (RES) {
            float4 rr = *(const float4*)&R[row * HD + lane * EPL + q * 4];
            v[q*4+0] += rr.x; v[q*4+1] += rr.y; v[q*4+2] += rr.z; v[q*4+3] += rr.w;
        }
    }
    float s = 0.f;
    #pragma unroll
    for (int e = 0; e < EPL; ++e) s += v[e];
    #pragma unroll
    for (int d = 1; d < 64; d <<= 1) s += __shfl_xor(s, d, 64);
    float mean = s * (1.f / HD);
    float s2 = 0.f;
    #pragma unroll
    for (int e = 0; e < EPL; ++e) { float d0 = v[e] - mean; s2 += d0 * d0; }
    #pragma unroll
    for (int d = 1; d < 64; d <<= 1) s2 += __shfl_xor(s2, d, 64);
    float inv = 1.f / sqrtf(s2 * (1.f / HD) + 1e-7f);
    #pragma unroll
    for (int q = 0; q < EPL / 4; ++q) {
        int c = lane * EPL + q * 4;
        float4 gg = *(const float4*)&g[c];
        float4 bb = *(const float4*)&be[c];
        float4 o;
        o.x = (v[q*4+0] - mean) * inv * gg.x + bb.x;
        o.y = (v[q*4+1] - mean) * inv * gg.y + bb.y;
        o.z = (v[q*4+2] - mean) * inv * gg.z + bb.z;
        o.w = (v[q*4+3] - mean) * inv * gg.w + bb.w;
        *(float4*)&Y[row * HD + c] = o;
    }
}

// ---------------------------------------------------------------------------
// MFMA fused disentangled flash attention, round 6:
//  - 2 waves/block, each wave owns 16 q-rows -> wave-local softmax (shfl),
//    mstate/lstate in registers, 2 barriers/tile
//  - K / band / V fragments loaded DIRECTLY from global (no staging LDS)
//  - V pre-transposed+split (vt[d][m]) by the QKV GEMM epilogue
//  - LDS only for T2/T3 diagonal gather + wave-private P transpose
// ---------------------------------------------------------------------------
__global__ __launch_bounds__(128) void attn_kernel(
    const unsigned short* __restrict__ qk_hi, const unsigned short* __restrict__ qk_lo,
    const unsigned short* __restrict__ vt_hi, const unsigned short* __restrict__ vt_lo,
    const unsigned short* __restrict__ pkg_hi, const unsigned short* __restrict__ pkg_lo,
    const float* __restrict__ mask, float* __restrict__ ctx)
{
    const float scale = 0.07216878364870322f;       // 1/sqrt(64*3)
    const float NEGMIN = -3.402823466e38f;
    int lt = blockIdx.x, h = blockIdx.y, b = blockIdx.z;
    int l0 = lt * 32;
    int tid = threadIdx.x;
    int lane = tid & 63, w = tid >> 6;
    int fr = lane & 15, kg8 = (lane >> 4) << 3, g4 = (lane >> 4) << 2;

    __shared__ float T2s[32 * 68];
    __shared__ float T3s[32 * 68];
    __shared__ unsigned short Sth[32 * 40], Stl[32 * 40];

    // Q frags (A rows = l0 + 16w + fr), loaded once
    bf16x8 qfh[2], qfl[2];
    {
        int qi = l0 + w * 16 + fr;
        bool valid = qi < 400;
        long long base = ((long long)(b * 400 + (valid ? qi : 0))) * 1024 + h * 64 + kg8;
        #pragma unroll
        for (int kk = 0; kk < 2; ++kk) {
            qfh[kk] = load_bf8(qk_hi + base + kk * 32, valid);
            qfl[kk] = load_bf8(qk_lo + base + kk * 32, valid);
        }
    }
    // own C-rows: i = 16w + g4 + r
    float wlv_r[4], ms[4], ls[4];
    #pragma unroll
    for (int r = 0; r < 4; ++r) {
        int lg = l0 + w * 16 + g4 + r;
        wlv_r[r] = (lg < 400) ? mask[b * 400 + lg] : 0.f;
        ms[r] = -INFINITY;
        ls[r] = 0.f;
    }
    f32x4 O[4] = {};
    long long vtbase = ((long long)(b * 512 + h * 64)) * 416;

    for (int mt = 0; mt < 13; ++mt) {
        int m0 = mt * 32;
        int D0 = l0 - m0 + 368;
        // ---- K frags (rows j = jf*16+fr) direct from global ----
        bf16x8 kfh[2][2], kfl[2][2];
        #pragma unroll
        for (int jf = 0; jf < 2; ++jf) {
            int kr = m0 + jf * 16 + fr;
            bool valid = kr < 400;
            long long base = ((long long)(b * 400 + (valid ? kr : 0))) * 1024 + 512 + h * 64 + kg8;
            #pragma unroll
            for (int kk = 0; kk < 2; ++kk) {
                kfh[jf][kk] = load_bf8(qk_hi + base + kk * 32, valid);
                kfl[jf][kk] = load_bf8(qk_lo + base + kk * 32, valid);
            }
        }
        // ---- T2 band frags (pk @ +512), rr = 16w + 16c + fr ----
        bf16x8 b2h[3][2], b2l[3][2];
        #pragma unroll
        for (int c = 0; c < 3; ++c) {
            int dd = D0 + w * 16 + c * 16 + fr;
            bool vv = (unsigned)dd < 799u;
            long long base = (long long)(vv ? dd : 0) * 1024 + 512 + h * 64 + kg8;
            #pragma unroll
            for (int kk = 0; kk < 2; ++kk) {
                b2h[c][kk] = load_bf8(pkg_hi + base + kk * 32, vv);
                b2l[c][kk] = load_bf8(pkg_lo + base + kk * 32, vv);
            }
        }
        __builtin_amdgcn_s_setprio(1);
        // ---- T1 = Q@K^T ----
        f32x4 aT1[2] = {};
        #pragma unroll
        for (int jf = 0; jf < 2; ++jf)
        #pragma unroll
        for (int kk = 0; kk < 2; ++kk) {
            aT1[jf] = __builtin_amdgcn_mfma_f32_16x16x32_bf16(qfh[kk], kfh[jf][kk], aT1[jf], 0, 0, 0);
            aT1[jf] = __builtin_amdgcn_mfma_f32_16x16x32_bf16(qfh[kk], kfl[jf][kk], aT1[jf], 0, 0, 0);
            aT1[jf] = __builtin_amdgcn_mfma_f32_16x16x32_bf16(qfl[kk], kfh[jf][kk], aT1[jf], 0, 0, 0);
        }
        // ---- T2 = Q@PKband^T ----
        f32x4 aT2[3] = {};
        #pragma unroll
        for (int c = 0; c < 3; ++c)
        #pragma unroll
        for (int kk = 0; kk < 2; ++kk) {
            aT2[c] = __builtin_amdgcn_mfma_f32_16x16x32_bf16(qfh[kk], b2h[c][kk], aT2[c], 0, 0, 0);
            aT2[c] = __builtin_amdgcn_mfma_f32_16x16x32_bf16(qfh[kk], b2l[c][kk], aT2[c], 0, 0, 0);
            aT2[c] = __builtin_amdgcn_mfma_f32_16x16x32_bf16(qfl[kk], b2h[c][kk], aT2[c], 0, 0, 0);
        }
        __builtin_amdgcn_s_setprio(0);
        // ---- T3 band frags (pq @ +0), rr = 32w + 16c2 + fr ----
        bf16x8 b3h[2][2], b3l[2][2];
        #pragma unroll
        for (int c2 = 0; c2 < 2; ++c2) {
            int dd = D0 + w * 32 + c2 * 16 + fr;
            bool vv = (unsigned)dd < 799u;
            long long base = (long long)(vv ? dd : 0) * 1024 + h * 64 + kg8;
            #pragma unroll
            for (int kk = 0; kk < 2; ++kk) {
                b3h[c2][kk] = load_bf8(pkg_hi + base + kk * 32, vv);
                b3l[c2][kk] = load_bf8(pkg_lo + base + kk * 32, vv);
            }
        }
        __builtin_amdgcn_s_setprio(1);
        // ---- T3 = K@PQband^T ----
        f32x4 aT3[2][2] = {};
        #pragma unroll
        for (int jf = 0; jf < 2; ++jf)
        #pragma unroll
        for (int c2 = 0; c2 < 2; ++c2)
        #pragma unroll
        for (int kk = 0; kk < 2; ++kk) {
            aT3[jf][c2] = __builtin_amdgcn_mfma_f32_16x16x32_bf16(kfh[jf][kk], b3h[c2][kk], aT3[jf][c2], 0, 0, 0);
            aT3[jf][c2] = __builtin_amdgcn_mfma_f32_16x16x32_bf16(kfh[jf][kk], b3l[c2][kk], aT3[jf][c2], 0, 0, 0);
            aT3[jf][c2] = __builtin_amdgcn_mfma_f32_16x16x32_bf16(kfl[jf][kk], b3h[c2][kk], aT3[jf][c2], 0, 0, 0);
        }
        __builtin_amdgcn_s_setprio(0);
        __syncthreads();   // Bw: prev tile's T2s/T3s reads complete
        // ---- scatter T2/T3 fragments to LDS ----
        #pragma unroll
        for (int c = 0; c < 3; ++c) {
            int cc = w * 16 + c * 16 + fr;
            #pragma unroll
            for (int r = 0; r < 4; ++r)
                T2s[(w * 16 + g4 + r) * 68 + cc] = aT2[c][r];
        }
        #pragma unroll
        for (int jf = 0; jf < 2; ++jf)
        #pragma unroll
        for (int c2 = 0; c2 < 2; ++c2) {
            int cc = w * 32 + c2 * 16 + fr;
            #pragma unroll
            for (int r = 0; r < 4; ++r)
                T3s[(jf * 16 + g4 + r) * 68 + cc] = aT3[jf][c2][r];
        }
        __syncthreads();   // Br: writes visible
        // ---- V frags (PV B) direct from vt ----
        bf16x8 vfh[4], vfl[4];
        #pragma unroll
        for (int f = 0; f < 4; ++f) {
            long long a = vtbase + (long long)(f * 16 + fr) * 416 + m0 + kg8;
            vfh[f] = *(const bf16x8*)&vt_hi[a];
            vfl[f] = *(const bf16x8*)&vt_lo[a];
        }
        float wm_c[2];
        #pragma unroll
        for (int cf = 0; cf < 2; ++cf) {
            int mg = m0 + cf * 16 + fr;
            wm_c[cf] = (mg < 400) ? mask[b * 400 + mg] : 0.f;
        }
        // ---- assemble scores ----
        float sc0[4], sc1[4];
        #pragma unroll
        for (int r = 0; r < 4; ++r) {
            int i = w * 16 + g4 + r;
            {
                int j = fr, rr = i - j + 31;
                bool jv = (m0 + j) < 400;
                sc0[r] = !jv ? -INFINITY :
                    ((wlv_r[r] != 0.f && wm_c[0] != 0.f) ?
                     (aT1[0][r] + T2s[i * 68 + rr] + T3s[j * 68 + rr]) * scale : NEGMIN);
            }
            {
                int j = 16 + fr, rr = i - j + 31;
                bool jv = (m0 + j) < 400;
                sc1[r] = !jv ? -INFINITY :
                    ((wlv_r[r] != 0.f && wm_c[1] != 0.f) ?
                     (aT1[1][r] + T2s[i * 68 + rr] + T3s[j * 68 + rr]) * scale : NEGMIN);
            }
        }
        // ---- wave-local flash softmax ----
        float corr[4];
        #pragma unroll
        for (int r = 0; r < 4; ++r) {
            float mx = fmaxf(sc0[r], sc1[r]);
            #pragma unroll
            for (int d = 1; d < 16; d <<= 1) mx = fmaxf(mx, __shfl_xor(mx, d, 64));
            float mn = fmaxf(ms[r], mx);
            corr[r] = expf(ms[r] - mn);
            ms[r] = mn;
            float p0 = expf(sc0[r] - mn), p1 = expf(sc1[r] - mn);
            float rs = p0 + p1;
            #pragma unroll
            for (int d = 1; d < 16; d <<= 1) rs += __shfl_xor(rs, d, 64);
            ls[r] = ls[r] * corr[r] + rs;
            int i = w * 16 + g4 + r;
            unsigned short h0 = f2bf(p0);
            Sth[i * 40 + fr] = h0;
            Stl[i * 40 + fr] = f2bf(p0 - bf2f(h0));
            unsigned short h1 = f2bf(p1);
            Sth[i * 40 + 16 + fr] = h1;
            Stl[i * 40 + 16 + fr] = f2bf(p1 - bf2f(h1));
        }
        // ---- PV (wave-private P through LDS transpose) ----
        #pragma unroll
        for (int f = 0; f < 4; ++f)
        #pragma unroll
        for (int r = 0; r < 4; ++r) O[f][r] *= corr[r];
        bf16x8 Pha = *(const bf16x8*)&Sth[(w * 16 + fr) * 40 + kg8];
        bf16x8 Pla = *(const bf16x8*)&Stl[(w * 16 + fr) * 40 + kg8];
        __builtin_amdgcn_s_setprio(1);
        #pragma unroll
        for (int f = 0; f < 4; ++f) {
            O[f] = __builtin_amdgcn_mfma_f32_16x16x32_bf16(Pha, vfh[f], O[f], 0, 0, 0);
            O[f] = __builtin_amdgcn_mfma_f32_16x16x32_bf16(Pha, vfl[f], O[f], 0, 0, 0);
            O[f] = __builtin_amdgcn_mfma_f32_16x16x32_bf16(Pla, vfh[f], O[f], 0, 0, 0);
        }
        __builtin_amdgcn_s_setprio(0);
    }
    // ---- write ctx ----
    #pragma unroll
    for (int f = 0; f < 4; ++f) {
        int colg = h * 64 + f * 16 + fr;
        #pragma unroll
        for (int r = 0; r < 4; ++r) {
            int lg = l0 + w * 16 + g4 + r;
            if (lg < 400)
                ctx[((long long)(b * 400 + lg)) * 512 + colg] = O[f][r] / ls[r];
        }
    }
}

// ---------------------------------------------------------------------------
// Pool / meanmax / heads
// ---------------------------------------------------------------------------
__global__ __launch_bounds__(256) void pool_kernel(
    const float* __restrict__ oenc, const float* __restrict__ mk,
    float* __restrict__ pooled)
{
    int b = blockIdx.x; int t = threadIdx.x;
    float acc = 0.f, mxv = -INFINITY, sw = 0.f;
    for (int l = 0; l < 400; ++l) {
        float w = mk[b * 400 + l];
        float vv = oenc[((long long)(b * 400 + l)) * 256 + t] * w;
        acc += vv; mxv = fmaxf(mxv, vv); sw += w;
    }
    pooled[b * 512 + t] = acc / (sw + 1e-6f);
    pooled[b * 512 + 256 + t] = mxv;
}

__global__ __launch_bounds__(512) void meanmax_kernel(
    const float* __restrict__ feats, float* __restrict__ mm)
{
    int b = blockIdx.x; int t = threadIdx.x;
    float s = 0.f, mx = -INFINITY;
    for (int l = 0; l < 400; ++l) {
        float vv = feats[((long long)(b * 400 + l)) * 512 + t];
        s += vv; mx = fmaxf(mx, vv);
    }
    mm[b * 1024 + t] = s / 400.f;
    mm[b * 1024 + 512 + t] = mx;
}

__global__ __launch_bounds__(256) void heads_kernel(
    const float* __restrict__ pooled, const float* __restrict__ mm,
    const float* __restrict__ w_bow1, const float* __restrict__ b_bow1,
    const float* __restrict__ w_bow2, const float* __restrict__ b_bow2,
    const float* __restrict__ w_ext1, const float* __restrict__ b_ext1,
    const float* __restrict__ w_ext2, const float* __restrict__ b_ext2,
    const float* __restrict__ w_org1, const float* __restrict__ b_org1,
    const float* __restrict__ w_org2, const float* __restrict__ b_org2,
    float* __restrict__ out)
{
    int b = blockIdx.x, role = blockIdx.y;
    int t = threadIdx.x;
    __shared__ float inb[1024];
    __shared__ float red[256];
    __shared__ float hid[256];
    if (role == 0) {
        inb[t] = pooled[b * 512 + t];
        inb[256 + t] = pooled[b * 512 + 256 + t];
        __syncthreads();
        float acc = b_bow1[t];
        for (int j = 0; j < 512; ++j) acc += inb[j] * w_bow1[j * 256 + t];
        red[t] = mishf(acc) * w_bow2[t];
        __syncthreads();
        for (int s = 128; s; s >>= 1) { if (t < s) red[t] += red[t + s]; __syncthreads(); }
        if (t == 0) out[b * 11 + 0] = red[0] + b_bow2[0];
    } else if (role == 1) {
        inb[t] = mm[b * 1024 + t];
        inb[256 + t] = mm[b * 1024 + 256 + t];
        inb[512 + t] = mm[b * 1024 + 512 + t];
        inb[768 + t] = mm[b * 1024 + 768 + t];
        __syncthreads();
        float acc = b_ext1[t];
        for (int j = 0; j < 1024; ++j) acc += inb[j] * w_ext1[j * 256 + t];
        red[t] = mishf(acc) * w_ext2[t];
        __syncthreads();
        for (int s = 128; s; s >>= 1) { if (t < s) red[t] += red[t + s]; __syncthreads(); }
        if (t == 0) { out[b * 11 + 1] = red[0] + b_ext2[0]; out[88 + b] = 0.f; }
    } else {
        int i = role - 2;
        inb[t] = pooled[((1 + i) * 8 + b) * 512 + t];
        inb[256 + t] = pooled[((1 + i) * 8 + b) * 512 + 256 + t];
        __syncthreads();
        float acc = b_org1[i * 256 + t];
        for (int j = 0; j < 512; ++j)
            acc += inb[j] * w_org1[((long long)i * 512 + j) * 256 + t];
        hid[t] = mishf(acc);
        __syncthreads();
        for (int c = 0; c < 3; ++c) {
            red[t] = hid[t] * w_org2[(i * 256 + t) * 3 + c];
            __syncthreads();
            for (int s = 128; s; s >>= 1) { if (t < s) red[t] += red[t + s]; __syncthreads(); }
            if (t == 0) out[b * 11 + 2 + i * 3 + c] = red[0] + b_org2[i * 3 + c];
            __syncthreads();
        }
    }
}

// ---------------------------------------------------------------------------
// Launch
// ---------------------------------------------------------------------------
extern "C" void kernel_launch(void* const* d_in, const int* in_sizes, int n_in,
                              void* d_out, int out_size, void* d_ws, size_t ws_size,
                              hipStream_t stream)
{
    const float* x      = (const float*)d_in[0];
    const float* w_mlp  = (const float*)d_in[1];
    const float* b_mlp  = (const float*)d_in[2];
    const float* w_cnn  = (const float*)d_in[3];
    const float* b_cnn  = (const float*)d_in[4];
    const float* rel_emb= (const float*)d_in[5];
    const float* rel_g  = (const float*)d_in[6];
    const float* rel_b  = (const float*)d_in[7];
    const float* wq     = (const float*)d_in[8];
    const float* wk     = (const float*)d_in[9];
    const float* wv     = (const float*)d_in[10];
    const float* wo     = (const float*)d_in[11];
    const float* wi     = (const float*)d_in[12];
    const float* bq     = (const float*)d_in[13];
    const float* bk     = (const float*)d_in[14];
    const float* bv     = (const float*)d_in[15];
    const float* bo     = (const float*)d_in[16];
    const float* bi     = (const float*)d_in[17];
    const float* wout   = (const float*)d_in[18];
    const float* bout   = (const float*)d_in[19];
    const float* ln1g   = (const float*)d_in[20];
    const float* ln1b   = (const float*)d_in[21];
    const float* ln2g   = (const float*)d_in[22];
    const float* ln2b   = (const float*)d_in[23];
    const float* w_bow1 = (const float*)d_in[24];
    const float* b_bow1 = (const float*)d_in[25];
    const float* w_bow2 = (const float*)d_in[26];
    const float* b_bow2 = (const float*)d_in[27];
    const float* w_ext1 = (const float*)d_in[28];
    const float* b_ext1 = (const float*)d_in[29];
    const float* w_ext2 = (const float*)d_in[30];
    const float* b_ext2 = (const float*)d_in[31];
    const float* w_org1 = (const float*)d_in[32];
    const float* b_org1 = (const float*)d_in[33];
    const float* w_org2 = (const float*)d_in[34];
    const float* b_org2 = (const float*)d_in[35];

    float* ws = (float*)d_ws;
    // workspace layout (float offsets), total ~10.11M floats = 40.4 MB
    float* featsb  = ws + 0;                    // 1,638,400
    float* ctxB    = ws + 1638400;              // 1,638,400 (f1pad / ctx / h1 / outenc / outln)
    float* qkvA_f  = ws + 3276800;              // 1,638,400 (qk_hi; later WO/WI tmp)
    float* qkvB_f  = ws + 4915200;              // 1,638,400 (qk_lo; rellnb aliased at start)
    unsigned short* qkv_hi = (unsigned short*)qkvA_f;
    unsigned short* qkv_lo = (unsigned short*)qkvB_f;
    float* rellnb  = qkvB_f;                    // 614,400 (dead before QKV GEMM writes)
    unsigned short* pkg_hi = (unsigned short*)(ws + 6553600);   // 799x1024
    unsigned short* pkg_lo = (unsigned short*)(ws + 6963200);
    unsigned short* vt_hi  = (unsigned short*)(ws + 7372800);   // 4096x416
    unsigned short* vt_lo  = (unsigned short*)(ws + 8224768);
    unsigned short* whi    = (unsigned short*)(ws + 9076736);   // 786,432 ushort
    unsigned short* wlo    = (unsigned short*)(ws + 9469952);
    float* bqkvb   = ws + 9863168;              //     6,144
    float* masksb  = ws + 9869312;              //    12,800
    float* pooledb = ws + 9882112;              //    16,384
    float* mmb     = ws + 9898496;              //     8,192
    int*   relidx  = (int*)(ws + 9906688);      //   800 ints
    unsigned short* wcnn_hi = (unsigned short*)(ws + 9907488);  // 196,608 ushort
    unsigned short* wcnn_lo = (unsigned short*)(ws + 10005792);
    int*   convidx = (int*)(ws + 10104096);     // 3,200 ints
    float* f1pad   = ctxB;                      // 3216 x 256 (pre-attn alias)
    float* outf    = (float*)d_out;

    // front: f1 -> featsb cols 0..255 AND f1pad (padded conv layout)
    gemm_bias<1, true><<<dim3(4, 50), 256, 0, stream>>>(
        x, w_mlp, b_mlp, featsb, f1pad, 3200, 256, 128, 512);
    setup_kernel<<<312, 256, 0, stream>>>(x, bq, bk, bv, masksb, relidx, convidx,
                                          f1pad, bqkvb, vt_hi, vt_lo);
    prep_wcnn<<<768, 256, 0, stream>>>(w_cnn, wcnn_hi, wcnn_lo);
    // conv as MFMA GEMM: feats cols 256..511 = relu(f1pad-window @ wcnn^T)
    gemm_mfma<2, true, false><<<dim3(2, 50), 256, 0, stream>>>(
        f1pad, wcnn_hi, wcnn_lo, b_cnn, featsb + 256, 3200, 768, 256, 512, convidx,
        nullptr, nullptr, 0, 0, nullptr, nullptr);

    for (int o = 0; o < 4; ++o) {
        ln2_kernel<false, 512><<<300, 256, 0, stream>>>(
            rel_emb + (long long)o * 614400, nullptr,
            rel_g + o * 512, rel_b + o * 512, rellnb, 1200);
        prep_wqkv<<<3072, 256, 0, stream>>>(wq, wk, wv, whi, wlo, o);
        // PQK: gathered rel projections -> pkg hi/lo [799][1024] (pq|pk)
        gemm_mfma<0, true, true><<<dim3(8, 13), 256, 0, stream>>>(
            rellnb, whi, wlo, bqkvb + o * 1536, nullptr, 799, 512, 512, 0, relidx,
            pkg_hi, pkg_lo, 1024, 1024, nullptr, nullptr);
        // QKV: feats -> qk hi/lo [3200][1024] + vt hi/lo (transposed, ld 416)
        gemm_mfma<0, false, true><<<dim3(12, 50), 256, 0, stream>>>(
            featsb, whi, wlo, bqkvb + o * 1536, nullptr, 3200, 512, 512, 0, nullptr,
            qkv_hi, qkv_lo, 1024, 1024, vt_hi, vt_lo);
        prep_woiw<<<2560, 256, 0, stream>>>(wo, wi, wout, whi, wlo, o);
        attn_kernel<<<dim3(13, 8, 8), 128, 0, stream>>>(qkv_hi, qkv_lo, vt_hi, vt_lo,
            pkg_hi, pkg_lo, masksb + o * 3200, ctxB);
        // WO: ctx @ wo -> tmp (qkvA region; qk dead after attn)
        gemm_mfma<0, false, false><<<dim3(4, 50), 256, 0, stream>>>(
            ctxB, whi, wlo, bo + o * 512, qkvA_f, 3200, 512, 512, 512, nullptr,
            nullptr, nullptr, 0, 0, nullptr, nullptr);
        ln2_kernel<true, 512><<<800, 256, 0, stream>>>(
            qkvA_f, featsb, ln1g + o * 512, ln1b + o * 512, ctxB, 3200);
        // WI (mish): h1 @ wi -> tmp
        gemm_mfma<1, false, false><<<dim3(4, 50), 256, 0, stream>>>(
            ctxB, whi + 262144, wlo + 262144, bi + o * 512, qkvA_f, 3200, 512, 512, 512,
            nullptr, nullptr, nullptr, 0, 0, nullptr, nullptr);
        // WOUT: inter @ wout -> ctxB (outenc [3200][256])
        gemm_mfma<0, false, false><<<dim3(2, 50), 256, 0, stream>>>(
            qkvA_f, whi + 524288, wlo + 524288, bout + o * 256, ctxB, 3200, 512, 512, 256,
            nullptr, nullptr, nullptr, 0, 0, nullptr, nullptr);
        ln2_kernel<false, 256><<<800, 256, 0, stream>>>(
            ctxB, nullptr, ln2g + o * 256, ln2b + o * 256, ctxB + 819200, 3200);
        pool_kernel<<<8, 256, 0, stream>>>(ctxB + 819200, masksb + o * 3200,
                                           pooledb + o * 4096);
    }

    meanmax_kernel<<<8, 512, 0, stream>>>(featsb, mmb);
    heads_kernel<<<dim3(8, 5), 256, 0, stream>>>(pooledb, mmb,
        w_bow1, b_bow1, w_bow2, b_bow2, w_ext1, b_ext1, w_ext2, b_ext2,
        w_org1, b_org1, w_org2, b_org2, outf);
}

// Round 7
// 1003.779 us; speedup vs baseline: 2.6702x; 1.2487x over previous
//
#include <hip/hip_runtime.h>
#include <math.h>

// ---------------------------------------------------------------------------
// Model dims (fixed): B=8 L=400 F=128 D=256 T=256 H=512 NH=8 HD=64 P=1200
// ---------------------------------------------------------------------------

typedef __attribute__((ext_vector_type(8))) short bf16x8;
typedef __attribute__((ext_vector_type(4))) float f32x4;
typedef __attribute__((ext_vector_type(4))) unsigned int u32x4;

__device__ __forceinline__ float mishf(float x) {
    float sp = fmaxf(x, 0.f) + log1pf(expf(-fabsf(x)));   // stable softplus
    return x * tanhf(sp);
}

__device__ __forceinline__ unsigned short f2bf(float f) {
    unsigned int u = __float_as_uint(f);
    u = (u + 0x7fffu + ((u >> 16) & 1u)) >> 16;           // RNE
    return (unsigned short)u;
}
__device__ __forceinline__ float bf2f(unsigned short h) {
    return __uint_as_float(((unsigned int)h) << 16);
}

__device__ __forceinline__ bf16x8 load_bf8(const unsigned short* p, bool valid) {
    bf16x8 z = {0, 0, 0, 0, 0, 0, 0, 0};
    if (valid) z = *(const bf16x8*)p;
    return z;
}

// ---------------------------------------------------------------------------
// fp32 GEMM (front MLP, K=128). DUAL: also write to padded conv layout.
// ---------------------------------------------------------------------------
template<int EPI, bool DUAL>
__global__ __launch_bounds__(256) void gemm_bias(
    const float* __restrict__ A, const float* __restrict__ Bm,
    const float* __restrict__ bias, float* __restrict__ C,
    float* __restrict__ C2,
    int M, int N, int K, int ldc)
{
    __shared__ float As[16][68];
    __shared__ float Bs[16][68];
    int bm = blockIdx.y << 6, bn = blockIdx.x << 6;
    int tid = threadIdx.x;
    int tm = (tid >> 4) << 2, tn = (tid & 15) << 2;
    int ar = tid >> 2, ac4 = (tid & 3) << 2;
    int br = tid >> 4, bc4 = (tid & 15) << 2;
    float acc[4][4] = {};
    for (int k0 = 0; k0 < K; k0 += 16) {
        float4 av = make_float4(0.f, 0.f, 0.f, 0.f);
        if (bm + ar < M)
            av = *(const float4*)&A[(long long)(bm + ar) * K + k0 + ac4];
        As[ac4][ar] = av.x; As[ac4 + 1][ar] = av.y;
        As[ac4 + 2][ar] = av.z; As[ac4 + 3][ar] = av.w;
        *(float4*)&Bs[br][bc4] =
            *(const float4*)&Bm[(long long)(k0 + br) * N + bn + bc4];
        __syncthreads();
        #pragma unroll
        for (int kk = 0; kk < 16; ++kk) {
            float4 a4 = *(const float4*)&As[kk][tm];
            float4 b4 = *(const float4*)&Bs[kk][tn];
            acc[0][0] += a4.x * b4.x; acc[0][1] += a4.x * b4.y;
            acc[0][2] += a4.x * b4.z; acc[0][3] += a4.x * b4.w;
            acc[1][0] += a4.y * b4.x; acc[1][1] += a4.y * b4.y;
            acc[1][2] += a4.y * b4.z; acc[1][3] += a4.y * b4.w;
            acc[2][0] += a4.z * b4.x; acc[2][1] += a4.z * b4.y;
            acc[2][2] += a4.z * b4.z; acc[2][3] += a4.z * b4.w;
            acc[3][0] += a4.w * b4.x; acc[3][1] += a4.w * b4.y;
            acc[3][2] += a4.w * b4.z; acc[3][3] += a4.w * b4.w;
        }
        __syncthreads();
    }
    #pragma unroll
    for (int i = 0; i < 4; ++i) {
        int r = bm + tm + i;
        if (r < M) {
            float v0 = acc[i][0] + bias[bn + tn + 0];
            float v1 = acc[i][1] + bias[bn + tn + 1];
            float v2 = acc[i][2] + bias[bn + tn + 2];
            float v3 = acc[i][3] + bias[bn + tn + 3];
            if (EPI == 1) { v0 = mishf(v0); v1 = mishf(v1); v2 = mishf(v2); v3 = mishf(v3); }
            float4 o; o.x = v0; o.y = v1; o.z = v2; o.w = v3;
            *(float4*)&C[(long long)r * ldc + bn + tn] = o;
            if (DUAL) {
                int rr2 = (r / 400) * 402 + (r % 400) + 1;
                *(float4*)&C2[(long long)rr2 * 256 + bn + tn] = o;
            }
        }
    }
}

// ---------------------------------------------------------------------------
// MFMA bf16x3-split GEMM. B pre-transposed+split [N][K] bf16 hi/lo.
// MT = M-tile (64 or 32). z-strides enable organ batching via blockIdx.z.
// SPLIT: cols<nhl -> qk hi/lo; cols>=1024 -> V transposed split (ld 416).
// EPI: 0 none, 1 mish, 2 relu.
// ---------------------------------------------------------------------------
template<int EPI, bool GATHER, bool SPLIT, int MT>
__global__ __launch_bounds__(256) void gemm_mfma(
    const float* __restrict__ A,
    const unsigned short* __restrict__ Bth, const unsigned short* __restrict__ Btl,
    const float* __restrict__ bias, float* __restrict__ C,
    int M, int K, int lda, int ldc, const int* __restrict__ gidx,
    unsigned short* __restrict__ Chi, unsigned short* __restrict__ Clo,
    int ldhl, int nhl,
    unsigned short* __restrict__ vthi, unsigned short* __restrict__ vtlo,
    int zA, int zB, int zBias, int zChi, int zVt)
{
    constexpr int AI = MT / 32;
    __shared__ unsigned short Ah[MT * 40];
    __shared__ unsigned short Al[MT * 40];
    __shared__ unsigned short Bh[128 * 40];
    __shared__ unsigned short Bl[128 * 40];

    long long zz = blockIdx.z;
    A    += zz * zA;
    Bth  += zz * zB;  Btl += zz * zB;
    bias += zz * zBias;
    if (SPLIT) {
        Chi += zz * zChi; Clo += zz * zChi;
        vthi += zz * zVt; vtlo += zz * zVt;
    }

    int bm = blockIdx.y * MT, bn = blockIdx.x << 7;
    int tid = threadIdx.x;
    int lane = tid & 63, wid = tid >> 6;
    int wm = wid >> 1, wn = wid & 1;
    int fr = lane & 15, kg = (lane >> 4) << 3;

    int ar = tid >> 2, akc = (tid & 3) << 3;
    int bnr = tid >> 1, bkc = (tid & 1) << 4;
    bool astage = ar < MT;

    long long arow = 0; bool avalid = false;
    if (astage) {
        int gr = bm + ar;
        avalid = gr < M;
        if (GATHER) arow = avalid ? (long long)gidx[gr] : 0;
        else        arow = avalid ? (long long)gr : 0;
    }

    f32x4 acc[AI][4] = {};

    for (int k0 = 0; k0 < K; k0 += 32) {
        if (astage) {
            float vv[8];
            if (avalid) {
                float4 v0 = *(const float4*)&A[arow * lda + k0 + akc];
                float4 v1 = *(const float4*)&A[arow * lda + k0 + akc + 4];
                vv[0] = v0.x; vv[1] = v0.y; vv[2] = v0.z; vv[3] = v0.w;
                vv[4] = v1.x; vv[5] = v1.y; vv[6] = v1.z; vv[7] = v1.w;
            } else {
                #pragma unroll
                for (int e = 0; e < 8; ++e) vv[e] = 0.f;
            }
            union { unsigned short u[8]; u32x4 v; } ph, pl;
            #pragma unroll
            for (int e = 0; e < 8; ++e) {
                unsigned short h = f2bf(vv[e]);
                ph.u[e] = h;
                pl.u[e] = f2bf(vv[e] - bf2f(h));
            }
            *(u32x4*)&Ah[ar * 40 + akc] = ph.v;
            *(u32x4*)&Al[ar * 40 + akc] = pl.v;
        }
        {
            long long boff = (long long)(bn + bnr) * K + k0 + bkc;
            *(u32x4*)&Bh[bnr * 40 + bkc]     = *(const u32x4*)&Bth[boff];
            *(u32x4*)&Bh[bnr * 40 + bkc + 8] = *(const u32x4*)&Bth[boff + 8];
            *(u32x4*)&Bl[bnr * 40 + bkc]     = *(const u32x4*)&Btl[boff];
            *(u32x4*)&Bl[bnr * 40 + bkc + 8] = *(const u32x4*)&Btl[boff + 8];
        }
        __syncthreads();

        bf16x8 af[AI], alf[AI], bfj[4], blf[4];
        #pragma unroll
        for (int i = 0; i < AI; ++i) {
            int row = (MT == 64 ? wm * 32 + i * 16 : wm * 16) + fr;
            af[i]  = *(const bf16x8*)&Ah[row * 40 + kg];
            alf[i] = *(const bf16x8*)&Al[row * 40 + kg];
        }
        #pragma unroll
        for (int j = 0; j < 4; ++j) {
            int row = wn * 64 + j * 16 + fr;
            bfj[j] = *(const bf16x8*)&Bh[row * 40 + kg];
            blf[j] = *(const bf16x8*)&Bl[row * 40 + kg];
        }
        #pragma unroll
        for (int i = 0; i < AI; ++i)
        #pragma unroll
        for (int j = 0; j < 4; ++j) {
            acc[i][j] = __builtin_amdgcn_mfma_f32_16x16x32_bf16(af[i],  bfj[j], acc[i][j], 0, 0, 0);
            acc[i][j] = __builtin_amdgcn_mfma_f32_16x16x32_bf16(af[i],  blf[j], acc[i][j], 0, 0, 0);
            acc[i][j] = __builtin_amdgcn_mfma_f32_16x16x32_bf16(alf[i], bfj[j], acc[i][j], 0, 0, 0);
        }
        __syncthreads();
    }

    #pragma unroll
    for (int i = 0; i < AI; ++i) {
        int rbase = bm + (MT == 64 ? wm * 32 + i * 16 : wm * 16) + ((lane >> 4) << 2);
        #pragma unroll
        for (int j = 0; j < 4; ++j) {
            int ccol = bn + wn * 64 + j * 16 + fr;
            float bv = bias[ccol];
            #pragma unroll
            for (int r = 0; r < 4; ++r) {
                int row = rbase + r;
                if (row < M) {
                    float val = acc[i][j][r] + bv;
                    if (SPLIT) {
                        unsigned short hh = f2bf(val);
                        unsigned short ll = f2bf(val - bf2f(hh));
                        if (ccol < nhl) {
                            Chi[(long long)row * ldhl + ccol] = hh;
                            Clo[(long long)row * ldhl + ccol] = ll;
                        } else {
                            int bb = row / 400, m = row - bb * 400;
                            long long vi = ((long long)(bb * 512 + (ccol - 1024))) * 416 + m;
                            vthi[vi] = hh;
                            vtlo[vi] = ll;
                        }
                    } else {
                        if (EPI == 1) val = mishf(val);
                        if (EPI == 2) val = fmaxf(val, 0.f);
                        C[(long long)row * ldc + ccol] = val;
                    }
                }
            }
        }
    }
}

// ---------------------------------------------------------------------------
// Weight prep kernels (write-coalesced)
// ---------------------------------------------------------------------------
__global__ __launch_bounds__(256) void prep_wqkv(
    const float* __restrict__ wq, const float* __restrict__ wk,
    const float* __restrict__ wv,
    unsigned short* __restrict__ whi, unsigned short* __restrict__ wlo,
    int obase, int total)
{
    int idx = blockIdx.x * 256 + threadIdx.x;
    if (idx >= total) return;
    int o = obase + idx / 786432;
    int rem = idx % 786432;
    int n = rem >> 9, k = rem & 511;
    int sel = n >> 9, col = n & 511;
    const float* W = sel == 0 ? wq : (sel == 1 ? wk : wv);
    float v = W[(long long)o * 262144 + k * 512 + col];
    unsigned short h = f2bf(v);
    whi[idx] = h;
    wlo[idx] = f2bf(v - bf2f(h));
}

__global__ __launch_bounds__(256) void prep_woiw(
    const float* __restrict__ wo, const float* __restrict__ wi,
    const float* __restrict__ wout,
    unsigned short* __restrict__ whi, unsigned short* __restrict__ wlo, int o)
{
    int idx = blockIdx.x * 256 + threadIdx.x;
    if (idx >= 655360) return;
    float v;
    if (idx < 262144) {
        int n = idx >> 9, k = idx & 511;
        v = wo[(long long)o * 262144 + k * 512 + n];
    } else if (idx < 524288) {
        int nk = idx - 262144;
        int n = nk >> 9, k = nk & 511;
        v = wi[(long long)o * 262144 + k * 512 + n];
    } else {
        int nk = idx - 524288;
        int n = nk >> 9, k = nk & 511;   // n < 256
        v = wout[(long long)o * 131072 + k * 256 + n];
    }
    unsigned short h = f2bf(v);
    whi[idx] = h;
    wlo[idx] = f2bf(v - bf2f(h));
}

// conv weights: [3][256][256] -> [256][768] hi/lo
__global__ __launch_bounds__(256) void prep_wcnn(
    const float* __restrict__ w,
    unsigned short* __restrict__ whi, unsigned short* __restrict__ wlo)
{
    int idx = blockIdx.x * 256 + threadIdx.x;
    if (idx >= 256 * 768) return;
    int n = idx / 768, k = idx % 768;
    float v = w[k * 256 + n];
    unsigned short h = f2bf(v);
    whi[idx] = h;
    wlo[idx] = f2bf(v - bf2f(h));
}

// ---------------------------------------------------------------------------
// Fused setup: masks, convidx, relidx, f1pad guards, bqkv pack, vt pad zero
// ---------------------------------------------------------------------------
__global__ __launch_bounds__(256) void setup_kernel(
    const float* __restrict__ x,
    const float* __restrict__ bq, const float* __restrict__ bk,
    const float* __restrict__ bv,
    float* __restrict__ mk, int* __restrict__ relT, int* __restrict__ convidx,
    float* __restrict__ f1pad, float* __restrict__ bqkv,
    unsigned short* __restrict__ vt_hi, unsigned short* __restrict__ vt_lo,
    int nOrg)
{
    int i = blockIdx.x * 256 + threadIdx.x;
    if (i < 3200) {
        const float* xr = x + (long long)i * 128;
        mk[i] = xr[4];
        mk[3200 + i] = fmaxf(xr[2], xr[3]);
        mk[6400 + i] = xr[0];
        mk[9600 + i] = xr[1];
        convidx[i] = (i / 400) * 402 + (i % 400);
    }
    int j = i - 3200;
    if (j >= 0 && j < 799) {
        int rel = j - 399;
        int sgn = (rel > 0) - (rel < 0);
        int ab = (rel < 300 && rel > -300) ? 299 : (rel < 0 ? -rel : rel);
        long long bpos;
        if (ab <= 300) bpos = rel;
        else {
            double lp = ceil(log((double)ab / 300.0) / log(599.0 / 300.0) * 299.0) + 300.0;
            bpos = (long long)lp * sgn;
        }
        long long c2p = bpos + 600;
        c2p = c2p < 0 ? 0 : (c2p > 1199 ? 1199 : c2p);
        relT[j] = (int)c2p;
    }
    int k = i - 4000;
    if (k >= 0 && k < 4096) {
        int b = k >> 9, rem = k & 511;
        int row = b * 402 + (rem < 256 ? 0 : 401);
        f1pad[(long long)row * 256 + (rem & 255)] = 0.f;
    }
    int m = i - 8100;
    if (m >= 0 && m < 6144) {
        int o = m / 1536, n = m % 1536;
        float v;
        if (n < 512) v = bq[o * 512 + n];
        else if (n < 1024) v = bk[o * 512 + n - 512];
        else v = bv[o * 512 + n - 1024];
        bqkv[m] = v;
    }
    int v = i - 14244;
    if (v >= 0 && v < nOrg * 65536) {   // vt pad cols [400..416) zero, as u32
        int og = v >> 16, rem = v & 65535;
        int vb = rem & 32767;
        int row = vb >> 3, c = vb & 7;
        unsigned int* p = (unsigned int*)((rem < 32768) ? vt_hi : vt_lo);
        p[(long long)og * 851968 + row * 208 + 200 + c] = 0u;
    }
}

// ---------------------------------------------------------------------------
// LayerNorm, wave-per-row (4 rows/block). eps 1e-7.
// ---------------------------------------------------------------------------
template<bool RES, int HD>
__global__ __launch_bounds__(256) void ln2_kernel(
    const float* __restrict__ X, const float* __restrict__ R,
    const float* __restrict__ g, const float* __restrict__ be,
    float* __restrict__ Y, int rows)
{
    constexpr int EPL = HD / 64;
    int wv = threadIdx.x >> 6, lane = threadIdx.x & 63;
    long long row = (long long)blockIdx.x * 4 + wv;
    if (row >= rows) return;
    const float* x = X + row * HD;
    float v[EPL];
    #pragma unroll
    for (int q = 0; q < EPL / 4; ++q) {
        float4 a = *(const float4*)&x[lane * EPL + q * 4];
        v[q*4+0] = a.x; v[q*4+1] = a.y; v[q*4+2] = a.z; v[q*4+3] = a.w;
        if (RES) {
            float4 rr = *(const float4*)&R[row * HD + lane * EPL + q * 4];
            v[q*4+0] += rr.x; v[q*4+1] += rr.y; v[q*4+2] += rr.z; v[q*4+3] += rr.w;
        }
    }
    float s = 0.f;
    #pragma unroll
    for (int e = 0; e < EPL; ++e) s += v[e];
    #pragma unroll
    for (int d = 1; d < 64; d <<= 1) s += __shfl_xor(s, d, 64);
    float mean = s * (1.f / HD);
    float s2 = 0.f;
    #pragma unroll
    for (int e = 0; e < EPL; ++e) { float d0 = v[e] - mean; s2 += d0 * d0; }
    #pragma unroll
    for (int d = 1; d < 64; d <<= 1) s2 += __shfl_xor(s2, d, 64);
    float inv = 1.f / sqrtf(s2 * (1.f / HD) + 1e-7f);
    #pragma unroll
    for (int q = 0; q < EPL / 4; ++q) {
        int c = lane * EPL + q * 4;
        float4 gg = *(const float4*)&g[c];
        float4 bb = *(const float4*)&be[c];
        float4 o;
        o.x = (v[q*4+0] - mean) * inv * gg.x + bb.x;
        o.y = (v[q*4+1] - mean) * inv * gg.y + bb.y;
        o.z = (v[q*4+2] - mean) * inv * gg.z + bb.z;
        o.w = (v[q*4+3] - mean) * inv * gg.w + bb.w;
        *(float4*)&Y[row * HD + c] = o;
    }
}

// ---------------------------------------------------------------------------
// MFMA fused disentangled flash attention (round 7: organ-batchable).
// grid (13, 8, 8*nOrg): z -> b = z&7, o = z>>3. Per-organ strides are
// compile-time constants; single-organ launches use grid.z=8 (o==0).
// ---------------------------------------------------------------------------
__global__ __launch_bounds__(128) void attn_kernel(
    const unsigned short* __restrict__ qk_hi, const unsigned short* __restrict__ qk_lo,
    const unsigned short* __restrict__ vt_hi, const unsigned short* __restrict__ vt_lo,
    const unsigned short* __restrict__ pkg_hi, const unsigned short* __restrict__ pkg_lo,
    const float* __restrict__ mask, float* __restrict__ ctx)
{
    const float scale = 0.07216878364870322f;       // 1/sqrt(64*3)
    const float NEGMIN = -3.402823466e38f;
    int lt = blockIdx.x, h = blockIdx.y;
    int z = blockIdx.z;
    int b = z & 7, o = z >> 3;
    qk_hi  += (long long)o * 3276800;
    qk_lo  += (long long)o * 3276800;
    vt_hi  += (long long)o * 1703936;
    vt_lo  += (long long)o * 1703936;
    pkg_hi += (long long)o * 818176;
    pkg_lo += (long long)o * 818176;
    mask   += o * 3200;
    ctx    += (long long)o * 1638400;

    int l0 = lt * 32;
    int tid = threadIdx.x;
    int lane = tid & 63, w = tid >> 6;
    int fr = lane & 15, kg8 = (lane >> 4) << 3, g4 = (lane >> 4) << 2;

    __shared__ float T2s[32 * 68];
    __shared__ float T3s[32 * 68];
    __shared__ unsigned short Sth[32 * 40], Stl[32 * 40];

    bf16x8 qfh[2], qfl[2];
    {
        int qi = l0 + w * 16 + fr;
        bool valid = qi < 400;
        long long base = ((long long)(b * 400 + (valid ? qi : 0))) * 1024 + h * 64 + kg8;
        #pragma unroll
        for (int kk = 0; kk < 2; ++kk) {
            qfh[kk] = load_bf8(qk_hi + base + kk * 32, valid);
            qfl[kk] = load_bf8(qk_lo + base + kk * 32, valid);
        }
    }
    float wlv_r[4], ms[4], ls[4];
    #pragma unroll
    for (int r = 0; r < 4; ++r) {
        int lg = l0 + w * 16 + g4 + r;
        wlv_r[r] = (lg < 400) ? mask[b * 400 + lg] : 0.f;
        ms[r] = -INFINITY;
        ls[r] = 0.f;
    }
    f32x4 O[4] = {};
    long long vtbase = ((long long)(b * 512 + h * 64)) * 416;

    for (int mt = 0; mt < 13; ++mt) {
        int m0 = mt * 32;
        int D0 = l0 - m0 + 368;
        bf16x8 kfh[2][2], kfl[2][2];
        #pragma unroll
        for (int jf = 0; jf < 2; ++jf) {
            int kr = m0 + jf * 16 + fr;
            bool valid = kr < 400;
            long long base = ((long long)(b * 400 + (valid ? kr : 0))) * 1024 + 512 + h * 64 + kg8;
            #pragma unroll
            for (int kk = 0; kk < 2; ++kk) {
                kfh[jf][kk] = load_bf8(qk_hi + base + kk * 32, valid);
                kfl[jf][kk] = load_bf8(qk_lo + base + kk * 32, valid);
            }
        }
        bf16x8 b2h[3][2], b2l[3][2];
        #pragma unroll
        for (int c = 0; c < 3; ++c) {
            int dd = D0 + w * 16 + c * 16 + fr;
            bool vv = (unsigned)dd < 799u;
            long long base = (long long)(vv ? dd : 0) * 1024 + 512 + h * 64 + kg8;
            #pragma unroll
            for (int kk = 0; kk < 2; ++kk) {
                b2h[c][kk] = load_bf8(pkg_hi + base + kk * 32, vv);
                b2l[c][kk] = load_bf8(pkg_lo + base + kk * 32, vv);
            }
        }
        __builtin_amdgcn_s_setprio(1);
        f32x4 aT1[2] = {};
        #pragma unroll
        for (int jf = 0; jf < 2; ++jf)
        #pragma unroll
        for (int kk = 0; kk < 2; ++kk) {
            aT1[jf] = __builtin_amdgcn_mfma_f32_16x16x32_bf16(qfh[kk], kfh[jf][kk], aT1[jf], 0, 0, 0);
            aT1[jf] = __builtin_amdgcn_mfma_f32_16x16x32_bf16(qfh[kk], kfl[jf][kk], aT1[jf], 0, 0, 0);
            aT1[jf] = __builtin_amdgcn_mfma_f32_16x16x32_bf16(qfl[kk], kfh[jf][kk], aT1[jf], 0, 0, 0);
        }
        f32x4 aT2[3] = {};
        #pragma unroll
        for (int c = 0; c < 3; ++c)
        #pragma unroll
        for (int kk = 0; kk < 2; ++kk) {
            aT2[c] = __builtin_amdgcn_mfma_f32_16x16x32_bf16(qfh[kk], b2h[c][kk], aT2[c], 0, 0, 0);
            aT2[c] = __builtin_amdgcn_mfma_f32_16x16x32_bf16(qfh[kk], b2l[c][kk], aT2[c], 0, 0, 0);
            aT2[c] = __builtin_amdgcn_mfma_f32_16x16x32_bf16(qfl[kk], b2h[c][kk], aT2[c], 0, 0, 0);
        }
        __builtin_amdgcn_s_setprio(0);
        bf16x8 b3h[2][2], b3l[2][2];
        #pragma unroll
        for (int c2 = 0; c2 < 2; ++c2) {
            int dd = D0 + w * 32 + c2 * 16 + fr;
            bool vv = (unsigned)dd < 799u;
            long long base = (long long)(vv ? dd : 0) * 1024 + h * 64 + kg8;
            #pragma unroll
            for (int kk = 0; kk < 2; ++kk) {
                b3h[c2][kk] = load_bf8(pkg_hi + base + kk * 32, vv);
                b3l[c2][kk] = load_bf8(pkg_lo + base + kk * 32, vv);
            }
        }
        __builtin_amdgcn_s_setprio(1);
        f32x4 aT3[2][2] = {};
        #pragma unroll
        for (int jf = 0; jf < 2; ++jf)
        #pragma unroll
        for (int c2 = 0; c2 < 2; ++c2)
        #pragma unroll
        for (int kk = 0; kk < 2; ++kk) {
            aT3[jf][c2] = __builtin_amdgcn_mfma_f32_16x16x32_bf16(kfh[jf][kk], b3h[c2][kk], aT3[jf][c2], 0, 0, 0);
            aT3[jf][c2] = __builtin_amdgcn_mfma_f32_16x16x32_bf16(kfh[jf][kk], b3l[c2][kk], aT3[jf][c2], 0, 0, 0);
            aT3[jf][c2] = __builtin_amdgcn_mfma_f32_16x16x32_bf16(kfl[jf][kk], b3h[c2][kk], aT3[jf][c2], 0, 0, 0);
        }
        __builtin_amdgcn_s_setprio(0);
        __syncthreads();   // prev tile's T2s/T3s reads complete
        #pragma unroll
        for (int c = 0; c < 3; ++c) {
            int cc = w * 16 + c * 16 + fr;
            #pragma unroll
            for (int r = 0; r < 4; ++r)
                T2s[(w * 16 + g4 + r) * 68 + cc] = aT2[c][r];
        }
        #pragma unroll
        for (int jf = 0; jf < 2; ++jf)
        #pragma unroll
        for (int c2 = 0; c2 < 2; ++c2) {
            int cc = w * 32 + c2 * 16 + fr;
            #pragma unroll
            for (int r = 0; r < 4; ++r)
                T3s[(jf * 16 + g4 + r) * 68 + cc] = aT3[jf][c2][r];
        }
        __syncthreads();   // writes visible
        bf16x8 vfh[4], vfl[4];
        #pragma unroll
        for (int f = 0; f < 4; ++f) {
            long long a = vtbase + (long long)(f * 16 + fr) * 416 + m0 + kg8;
            vfh[f] = *(const bf16x8*)&vt_hi[a];
            vfl[f] = *(const bf16x8*)&vt_lo[a];
        }
        float wm_c[2];
        #pragma unroll
        for (int cf = 0; cf < 2; ++cf) {
            int mg = m0 + cf * 16 + fr;
            wm_c[cf] = (mg < 400) ? mask[b * 400 + mg] : 0.f;
        }
        float sc0[4], sc1[4];
        #pragma unroll
        for (int r = 0; r < 4; ++r) {
            int i = w * 16 + g4 + r;
            {
                int j = fr, rr = i - j + 31;
                bool jv = (m0 + j) < 400;
                sc0[r] = !jv ? -INFINITY :
                    ((wlv_r[r] != 0.f && wm_c[0] != 0.f) ?
                     (aT1[0][r] + T2s[i * 68 + rr] + T3s[j * 68 + rr]) * scale : NEGMIN);
            }
            {
                int j = 16 + fr, rr = i - j + 31;
                bool jv = (m0 + j) < 400;
                sc1[r] = !jv ? -INFINITY :
                    ((wlv_r[r] != 0.f && wm_c[1] != 0.f) ?
                     (aT1[1][r] + T2s[i * 68 + rr] + T3s[j * 68 + rr]) * scale : NEGMIN);
            }
        }
        float corr[4];
        #pragma unroll
        for (int r = 0; r < 4; ++r) {
            float mx = fmaxf(sc0[r], sc1[r]);
            #pragma unroll
            for (int d = 1; d < 16; d <<= 1) mx = fmaxf(mx, __shfl_xor(mx, d, 64));
            float mn = fmaxf(ms[r], mx);
            corr[r] = expf(ms[r] - mn);
            ms[r] = mn;
            float p0 = expf(sc0[r] - mn), p1 = expf(sc1[r] - mn);
            float rs = p0 + p1;
            #pragma unroll
            for (int d = 1; d < 16; d <<= 1) rs += __shfl_xor(rs, d, 64);
            ls[r] = ls[r] * corr[r] + rs;
            int i = w * 16 + g4 + r;
            unsigned short h0 = f2bf(p0);
            Sth[i * 40 + fr] = h0;
            Stl[i * 40 + fr] = f2bf(p0 - bf2f(h0));
            unsigned short h1 = f2bf(p1);
            Sth[i * 40 + 16 + fr] = h1;
            Stl[i * 40 + 16 + fr] = f2bf(p1 - bf2f(h1));
        }
        #pragma unroll
        for (int f = 0; f < 4; ++f)
        #pragma unroll
        for (int r = 0; r < 4; ++r) O[f][r] *= corr[r];
        bf16x8 Pha = *(const bf16x8*)&Sth[(w * 16 + fr) * 40 + kg8];
        bf16x8 Pla = *(const bf16x8*)&Stl[(w * 16 + fr) * 40 + kg8];
        __builtin_amdgcn_s_setprio(1);
        #pragma unroll
        for (int f = 0; f < 4; ++f) {
            O[f] = __builtin_amdgcn_mfma_f32_16x16x32_bf16(Pha, vfh[f], O[f], 0, 0, 0);
            O[f] = __builtin_amdgcn_mfma_f32_16x16x32_bf16(Pha, vfl[f], O[f], 0, 0, 0);
            O[f] = __builtin_amdgcn_mfma_f32_16x16x32_bf16(Pla, vfh[f], O[f], 0, 0, 0);
        }
        __builtin_amdgcn_s_setprio(0);
    }
    #pragma unroll
    for (int f = 0; f < 4; ++f) {
        int colg = h * 64 + f * 16 + fr;
        #pragma unroll
        for (int r = 0; r < 4; ++r) {
            int lg = l0 + w * 16 + g4 + r;
            if (lg < 400)
                ctx[((long long)(b * 400 + lg)) * 512 + colg] = O[f][r] / ls[r];
        }
    }
}

// ---------------------------------------------------------------------------
// Chunked pool / meanmax (full-chip), heads
// ---------------------------------------------------------------------------
__global__ __launch_bounds__(256) void pool_part(
    const float* __restrict__ in, long long inOStride,
    const float* __restrict__ mk, float* __restrict__ pp)
{
    int bi = blockIdx.x, c = blockIdx.y, t = threadIdx.x;
    int o = bi >> 3, b = bi & 7;
    int l0 = c * 31, l1 = min(400, l0 + 31);
    const float* ib = in + (long long)o * inOStride + (long long)(b * 400) * 256;
    const float* mkb = mk + o * 3200 + b * 400;
    float s = 0.f, mx = -INFINITY, sw = 0.f;
    for (int l = l0; l < l1; ++l) {
        float wv = mkb[l];
        float v = ib[(long long)l * 256 + t] * wv;
        s += v; mx = fmaxf(mx, v); sw += wv;
    }
    long long base = (long long)(c * gridDim.x + bi) * 514;
    pp[base + t] = s;
    pp[base + 256 + t] = mx;
    if (t == 0) pp[base + 512] = sw;
}

__global__ __launch_bounds__(256) void pool_merge(
    const float* __restrict__ pp, float* __restrict__ pooled, int nBI)
{
    int bi = blockIdx.x, t = threadIdx.x;
    float s = 0.f, mx = -INFINITY, sw = 0.f;
    for (int c = 0; c < 13; ++c) {
        long long base = (long long)(c * nBI + bi) * 514;
        s += pp[base + t];
        mx = fmaxf(mx, pp[base + 256 + t]);
        sw += pp[base + 512];
    }
    int o = bi >> 3, b = bi & 7;
    pooled[o * 4096 + b * 512 + t] = s / (sw + 1e-6f);
    pooled[o * 4096 + b * 512 + 256 + t] = mx;
}

__global__ __launch_bounds__(512) void mm_part(
    const float* __restrict__ feats, float* __restrict__ mmp)
{
    int b = blockIdx.x, c = blockIdx.y, t = threadIdx.x;
    int l0 = c * 31, l1 = min(400, l0 + 31);
    float s = 0.f, mx = -INFINITY;
    for (int l = l0; l < l1; ++l) {
        float v = feats[((long long)(b * 400 + l)) * 512 + t];
        s += v; mx = fmaxf(mx, v);
    }
    long long base = (long long)(c * 8 + b) * 1024;
    mmp[base + t] = s;
    mmp[base + 512 + t] = mx;
}

__global__ __launch_bounds__(512) void mm_merge(
    const float* __restrict__ mmp, float* __restrict__ mm)
{
    int b = blockIdx.x, t = threadIdx.x;
    float s = 0.f, mx = -INFINITY;
    for (int c = 0; c < 13; ++c) {
        long long base = (long long)(c * 8 + b) * 1024;
        s += mmp[base + t];
        mx = fmaxf(mx, mmp[base + 512 + t]);
    }
    mm[b * 1024 + t] = s / 400.f;
    mm[b * 1024 + 512 + t] = mx;
}

__global__ __launch_bounds__(256) void heads_kernel(
    const float* __restrict__ pooled, const float* __restrict__ mm,
    const float* __restrict__ w_bow1, const float* __restrict__ b_bow1,
    const float* __restrict__ w_bow2, const float* __restrict__ b_bow2,
    const float* __restrict__ w_ext1, const float* __restrict__ b_ext1,
    const float* __restrict__ w_ext2, const float* __restrict__ b_ext2,
    const float* __restrict__ w_org1, const float* __restrict__ b_org1,
    const float* __restrict__ w_org2, const float* __restrict__ b_org2,
    float* __restrict__ out)
{
    int b = blockIdx.x, role = blockIdx.y;
    int t = threadIdx.x;
    __shared__ float inb[1024];
    __shared__ float red[256];
    __shared__ float hid[256];
    if (role == 0) {
        inb[t] = pooled[b * 512 + t];
        inb[256 + t] = pooled[b * 512 + 256 + t];
        __syncthreads();
        float acc = b_bow1[t];
        for (int j = 0; j < 512; ++j) acc += inb[j] * w_bow1[j * 256 + t];
        red[t] = mishf(acc) * w_bow2[t];
        __syncthreads();
        for (int s = 128; s; s >>= 1) { if (t < s) red[t] += red[t + s]; __syncthreads(); }
        if (t == 0) out[b * 11 + 0] = red[0] + b_bow2[0];
    } else if (role == 1) {
        inb[t] = mm[b * 1024 + t];
        inb[256 + t] = mm[b * 1024 + 256 + t];
        inb[512 + t] = mm[b * 1024 + 512 + t];
        inb[768 + t] = mm[b * 1024 + 768 + t];
        __syncthreads();
        float acc = b_ext1[t];
        for (int j = 0; j < 1024; ++j) acc += inb[j] * w_ext1[j * 256 + t];
        red[t] = mishf(acc) * w_ext2[t];
        __syncthreads();
        for (int s = 128; s; s >>= 1) { if (t < s) red[t] += red[t + s]; __syncthreads(); }
        if (t == 0) { out[b * 11 + 1] = red[0] + b_ext2[0]; out[88 + b] = 0.f; }
    } else {
        int i = role - 2;
        inb[t] = pooled[((1 + i) * 8 + b) * 512 + t];
        inb[256 + t] = pooled[((1 + i) * 8 + b) * 512 + 256 + t];
        __syncthreads();
        float acc = b_org1[i * 256 + t];
        for (int j = 0; j < 512; ++j)
            acc += inb[j] * w_org1[((long long)i * 512 + j) * 256 + t];
        hid[t] = mishf(acc);
        __syncthreads();
        for (int c = 0; c < 3; ++c) {
            red[t] = hid[t] * w_org2[(i * 256 + t) * 3 + c];
            __syncthreads();
            for (int s = 128; s; s >>= 1) { if (t < s) red[t] += red[t + s]; __syncthreads(); }
            if (t == 0) out[b * 11 + 2 + i * 3 + c] = red[0] + b_org2[i * 3 + c];
            __syncthreads();
        }
    }
}

// ---------------------------------------------------------------------------
// Launch
// ---------------------------------------------------------------------------
extern "C" void kernel_launch(void* const* d_in, const int* in_sizes, int n_in,
                              void* d_out, int out_size, void* d_ws, size_t ws_size,
                              hipStream_t stream)
{
    const float* x      = (const float*)d_in[0];
    const float* w_mlp  = (const float*)d_in[1];
    const float* b_mlp  = (const float*)d_in[2];
    const float* w_cnn  = (const float*)d_in[3];
    const float* b_cnn  = (const float*)d_in[4];
    const float* rel_emb= (const float*)d_in[5];
    const float* rel_g  = (const float*)d_in[6];
    const float* rel_b  = (const float*)d_in[7];
    const float* wq     = (const float*)d_in[8];
    const float* wk     = (const float*)d_in[9];
    const float* wv     = (const float*)d_in[10];
    const float* wo     = (const float*)d_in[11];
    const float* wi     = (const float*)d_in[12];
    const float* bq     = (const float*)d_in[13];
    const float* bk     = (const float*)d_in[14];
    const float* bv     = (const float*)d_in[15];
    const float* bo     = (const float*)d_in[16];
    const float* bi     = (const float*)d_in[17];
    const float* wout   = (const float*)d_in[18];
    const float* bout   = (const float*)d_in[19];
    const float* ln1g   = (const float*)d_in[20];
    const float* ln1b   = (const float*)d_in[21];
    const float* ln2g   = (const float*)d_in[22];
    const float* ln2b   = (const float*)d_in[23];
    const float* w_bow1 = (const float*)d_in[24];
    const float* b_bow1 = (const float*)d_in[25];
    const float* w_bow2 = (const float*)d_in[26];
    const float* b_bow2 = (const float*)d_in[27];
    const float* w_ext1 = (const float*)d_in[28];
    const float* b_ext1 = (const float*)d_in[29];
    const float* w_ext2 = (const float*)d_in[30];
    const float* b_ext2 = (const float*)d_in[31];
    const float* w_org1 = (const float*)d_in[32];
    const float* b_org1 = (const float*)d_in[33];
    const float* w_org2 = (const float*)d_in[34];
    const float* b_org2 = (const float*)d_in[35];

    float* ws = (float*)d_ws;
    float* outf = (float*)d_out;
    const bool big = ws_size >= 143012736ull;   // big layout = 35,753,184 floats

    if (big) {
        // ---------------- organ-batched path ----------------
        float* featsb   = ws + 0;
        float* ctx_all  = ws + 1638400;      // 6,553,600 (f1pad aliases start)
        float* f1pad    = ctx_all;
        float* qkA_f    = ws + 8192000;      // 6,553,600: relln_all / qk_hi_all / tmp,tmp2,outln
        float* qkB_f    = ws + 14745600;     // 6,553,600: qk_lo_all
        unsigned short* qkA = (unsigned short*)qkA_f;
        unsigned short* qkB = (unsigned short*)qkB_f;
        float* relln_all = qkA_f;            // 2,457,600 (dead before QKV writes)
        unsigned short* vtA = (unsigned short*)(ws + 21299200);  // 4x4096x416
        unsigned short* vtB = (unsigned short*)(ws + 24707072);
        unsigned short* pkgA = (unsigned short*)(ws + 28114944); // 4x799x1024
        unsigned short* pkgB = (unsigned short*)(ws + 29751296);
        unsigned short* whiA = (unsigned short*)(ws + 31387648); // 4x786,432
        unsigned short* wloA = (unsigned short*)(ws + 32960512);
        unsigned short* whiB = (unsigned short*)(ws + 34533376); // 655,360
        unsigned short* wloB = (unsigned short*)(ws + 34861056);
        unsigned short* wcnn_hi = (unsigned short*)(ws + 35188736);
        unsigned short* wcnn_lo = (unsigned short*)(ws + 35287040);
        float* bqkvb   = ws + 35385344;
        float* masksb  = ws + 35391488;
        float* pooledb = ws + 35404288;
        float* mmb     = ws + 35420672;
        int*   relidx  = (int*)(ws + 35428864);
        int*   convidx = (int*)(ws + 35429664);
        float* poolpart= ws + 35432864;      // 13*32*514
        float* mmpart  = ws + 35646688;      // 13*8*1024
        float* tmp     = qkA_f;              // per-organ tail scratch
        float* tmp2    = qkA_f + 1638400;
        float* outln_all = qkA_f + 3276800;  // 4 x 819,200
        float* h1      = (float*)vtA;        // 1,638,400 of vt region
        float* outenc  = (float*)pkgA;       // 819,200 of pkg region

        gemm_bias<1, true><<<dim3(4, 50), 256, 0, stream>>>(
            x, w_mlp, b_mlp, featsb, f1pad, 3200, 256, 128, 512);
        setup_kernel<<<1080, 256, 0, stream>>>(x, bq, bk, bv, masksb, relidx, convidx,
                                               f1pad, bqkvb, vtA, vtB, 4);
        prep_wcnn<<<768, 256, 0, stream>>>(w_cnn, wcnn_hi, wcnn_lo);
        gemm_mfma<2, true, false, 32><<<dim3(2, 100), 256, 0, stream>>>(
            f1pad, wcnn_hi, wcnn_lo, b_cnn, featsb + 256, 3200, 768, 256, 512, convidx,
            nullptr, nullptr, 0, 0, nullptr, nullptr, 0, 0, 0, 0, 0);

        for (int o = 0; o < 4; ++o)
            ln2_kernel<false, 512><<<300, 256, 0, stream>>>(
                rel_emb + (long long)o * 614400, nullptr,
                rel_g + o * 512, rel_b + o * 512, relln_all + (long long)o * 614400, 1200);
        prep_wqkv<<<12288, 256, 0, stream>>>(wq, wk, wv, whiA, wloA, 0, 3145728);
        // PQK batched (z=organ)
        gemm_mfma<0, true, true, 64><<<dim3(8, 13, 4), 256, 0, stream>>>(
            relln_all, whiA, wloA, bqkvb, nullptr, 799, 512, 512, 0, relidx,
            pkgA, pkgB, 1024, 1024, nullptr, nullptr,
            614400, 786432, 1536, 818176, 0);
        // QKV batched (z=organ)
        gemm_mfma<0, false, true, 64><<<dim3(12, 50, 4), 256, 0, stream>>>(
            featsb, whiA, wloA, bqkvb, nullptr, 3200, 512, 512, 0, nullptr,
            qkA, qkB, 1024, 1024, vtA, vtB,
            0, 786432, 1536, 3276800, 1703936);
        // attention: all 4 organs in one launch
        attn_kernel<<<dim3(13, 8, 32), 128, 0, stream>>>(qkA, qkB, vtA, vtB,
            pkgA, pkgB, masksb, ctx_all);

        for (int o = 0; o < 4; ++o) {
            prep_woiw<<<2560, 256, 0, stream>>>(wo, wi, wout, whiB, wloB, o);
            gemm_mfma<0, false, false, 32><<<dim3(4, 100), 256, 0, stream>>>(
                ctx_all + (long long)o * 1638400, whiB, wloB, bo + o * 512, tmp,
                3200, 512, 512, 512, nullptr, nullptr, nullptr, 0, 0, nullptr, nullptr,
                0, 0, 0, 0, 0);
            ln2_kernel<true, 512><<<800, 256, 0, stream>>>(
                tmp, featsb, ln1g + o * 512, ln1b + o * 512, h1, 3200);
            gemm_mfma<1, false, false, 32><<<dim3(4, 100), 256, 0, stream>>>(
                h1, whiB + 262144, wloB + 262144, bi + o * 512, tmp2,
                3200, 512, 512, 512, nullptr, nullptr, nullptr, 0, 0, nullptr, nullptr,
                0, 0, 0, 0, 0);
            gemm_mfma<0, false, false, 32><<<dim3(2, 100), 256, 0, stream>>>(
                tmp2, whiB + 524288, wloB + 524288, bout + o * 256, outenc,
                3200, 512, 512, 256, nullptr, nullptr, nullptr, 0, 0, nullptr, nullptr,
                0, 0, 0, 0, 0);
            ln2_kernel<false, 256><<<800, 256, 0, stream>>>(
                outenc, nullptr, ln2g + o * 256, ln2b + o * 256,
                outln_all + (long long)o * 819200, 3200);
        }
        pool_part<<<dim3(32, 13), 256, 0, stream>>>(outln_all, 819200, masksb, poolpart);
        pool_merge<<<32, 256, 0, stream>>>(poolpart, pooledb, 32);
        mm_part<<<dim3(8, 13), 512, 0, stream>>>(featsb, mmpart);
        mm_merge<<<8, 512, 0, stream>>>(mmpart, mmb);
        heads_kernel<<<dim3(8, 5), 256, 0, stream>>>(pooledb, mmb,
            w_bow1, b_bow1, w_bow2, b_bow2, w_ext1, b_ext1, w_ext2, b_ext2,
            w_org1, b_org1, w_org2, b_org2, outf);
        return;
    }

    // ---------------- per-organ fallback path (proven-size layout) ----------------
    float* featsb  = ws + 0;
    float* ctxB    = ws + 1638400;
    float* qkvA_f  = ws + 3276800;
    float* qkvB_f  = ws + 4915200;
    unsigned short* qkv_hi = (unsigned short*)qkvA_f;
    unsigned short* qkv_lo = (unsigned short*)qkvB_f;
    float* rellnb  = qkvB_f;
    unsigned short* pkg_hi = (unsigned short*)(ws + 6553600);
    unsigned short* pkg_lo = (unsigned short*)(ws + 6963200);
    unsigned short* vt_hi  = (unsigned short*)(ws + 7372800);
    unsigned short* vt_lo  = (unsigned short*)(ws + 8224768);
    unsigned short* whi    = (unsigned short*)(ws + 9076736);
    unsigned short* wlo    = (unsigned short*)(ws + 9469952);
    float* bqkvb   = ws + 9863168;
    float* masksb  = ws + 9869312;
    float* pooledb = ws + 9882112;
    float* mmb     = ws + 9898496;
    int*   relidx  = (int*)(ws + 9906688);
    unsigned short* wcnn_hi = (unsigned short*)(ws + 9907488);
    unsigned short* wcnn_lo = (unsigned short*)(ws + 10005792);
    int*   convidx = (int*)(ws + 10104096);
    float* poolpart= ws + 10107296;
    float* mmpart  = ws + 10160752;
    float* f1pad   = ctxB;

    gemm_bias<1, true><<<dim3(4, 50), 256, 0, stream>>>(
        x, w_mlp, b_mlp, featsb, f1pad, 3200, 256, 128, 512);
    setup_kernel<<<312, 256, 0, stream>>>(x, bq, bk, bv, masksb, relidx, convidx,
                                          f1pad, bqkvb, vt_hi, vt_lo, 1);
    prep_wcnn<<<768, 256, 0, stream>>>(w_cnn, wcnn_hi, wcnn_lo);
    gemm_mfma<2, true, false, 32><<<dim3(2, 100), 256, 0, stream>>>(
        f1pad, wcnn_hi, wcnn_lo, b_cnn, featsb + 256, 3200, 768, 256, 512, convidx,
        nullptr, nullptr, 0, 0, nullptr, nullptr, 0, 0, 0, 0, 0);

    for (int o = 0; o < 4; ++o) {
        ln2_kernel<false, 512><<<300, 256, 0, stream>>>(
            rel_emb + (long long)o * 614400, nullptr,
            rel_g + o * 512, rel_b + o * 512, rellnb, 1200);
        prep_wqkv<<<3072, 256, 0, stream>>>(wq, wk, wv, whi, wlo, o, 786432);
        gemm_mfma<0, true, true, 64><<<dim3(8, 13), 256, 0, stream>>>(
            rellnb, whi, wlo, bqkvb + o * 1536, nullptr, 799, 512, 512, 0, relidx,
            pkg_hi, pkg_lo, 1024, 1024, nullptr, nullptr, 0, 0, 0, 0, 0);
        gemm_mfma<0, false, true, 64><<<dim3(12, 50), 256, 0, stream>>>(
            featsb, whi, wlo, bqkvb + o * 1536, nullptr, 3200, 512, 512, 0, nullptr,
            qkv_hi, qkv_lo, 1024, 1024, vt_hi, vt_lo, 0, 0, 0, 0, 0);
        prep_woiw<<<2560, 256, 0, stream>>>(wo, wi, wout, whi, wlo, o);
        attn_kernel<<<dim3(13, 8, 8), 128, 0, stream>>>(qkv_hi, qkv_lo, vt_hi, vt_lo,
            pkg_hi, pkg_lo, masksb + o * 3200, ctxB);
        gemm_mfma<0, false, false, 32><<<dim3(4, 100), 256, 0, stream>>>(
            ctxB, whi, wlo, bo + o * 512, qkvA_f, 3200, 512, 512, 512, nullptr,
            nullptr, nullptr, 0, 0, nullptr, nullptr, 0, 0, 0, 0, 0);
        ln2_kernel<true, 512><<<800, 256, 0, stream>>>(
            qkvA_f, featsb, ln1g + o * 512, ln1b + o * 512, ctxB, 3200);
        gemm_mfma<1, false, false, 32><<<dim3(4, 100), 256, 0, stream>>>(
            ctxB, whi + 262144, wlo + 262144, bi + o * 512, qkvA_f, 3200, 512, 512, 512,
            nullptr, nullptr, nullptr, 0, 0, nullptr, nullptr, 0, 0, 0, 0, 0);
        gemm_mfma<0, false, false, 32><<<dim3(2, 100), 256, 0, stream>>>(
            qkvA_f, whi + 524288, wlo + 524288, bout + o * 256, ctxB, 3200, 512, 512, 256,
            nullptr, nullptr, nullptr, 0, 0, nullptr, nullptr, 0, 0, 0, 0, 0);
        ln2_kernel<false, 256><<<800, 256, 0, stream>>>(
            ctxB, nullptr, ln2g + o * 256, ln2b + o * 256, ctxB + 819200, 3200);
        pool_part<<<dim3(8, 13), 256, 0, stream>>>(ctxB + 819200, 0,
                                                   masksb + o * 3200, poolpart);
        pool_merge<<<8, 256, 0, stream>>>(poolpart, pooledb + o * 4096, 8);
    }

    mm_part<<<dim3(8, 13), 512, 0, stream>>>(featsb, mmpart);
    mm_merge<<<8, 512, 0, stream>>>(mmpart, mmb);
    heads_kernel<<<dim3(8, 5), 256, 0, stream>>>(pooledb, mmb,
        w_bow1, b_bow1, w_bow2, b_bow2, w_ext1, b_ext1, w_ext2, b_ext2,
        w_org1, b_org1, w_org2, b_org2, outf);
}

// Round 8
// 824.923 us; speedup vs baseline: 3.2491x; 1.2168x over previous
//
#include <hip/hip_runtime.h>
#include <math.h>

// ---------------------------------------------------------------------------
// Model dims (fixed): B=8 L=400 F=128 D=256 T=256 H=512 NH=8 HD=64 P=1200
// ---------------------------------------------------------------------------

typedef __attribute__((ext_vector_type(8))) short bf16x8;
typedef __attribute__((ext_vector_type(4))) float f32x4;
typedef __attribute__((ext_vector_type(4))) unsigned int u32x4;

__device__ __forceinline__ float mishf(float x) {
    float sp = fmaxf(x, 0.f) + log1pf(expf(-fabsf(x)));   // stable softplus
    return x * tanhf(sp);
}

__device__ __forceinline__ unsigned short f2bf(float f) {
    unsigned int u = __float_as_uint(f);
    u = (u + 0x7fffu + ((u >> 16) & 1u)) >> 16;           // RNE
    return (unsigned short)u;
}
__device__ __forceinline__ float bf2f(unsigned short h) {
    return __uint_as_float(((unsigned int)h) << 16);
}

__device__ __forceinline__ bf16x8 load_bf8(const unsigned short* p, bool valid) {
    bf16x8 z = {0, 0, 0, 0, 0, 0, 0, 0};
    if (valid) z = *(const bf16x8*)p;
    return z;
}

// ---------------------------------------------------------------------------
// fp32 GEMM (front MLP, K=128). DUAL: also write to padded conv layout.
// ---------------------------------------------------------------------------
template<int EPI, bool DUAL>
__global__ __launch_bounds__(256) void gemm_bias(
    const float* __restrict__ A, const float* __restrict__ Bm,
    const float* __restrict__ bias, float* __restrict__ C,
    float* __restrict__ C2,
    int M, int N, int K, int ldc)
{
    __shared__ float As[16][68];
    __shared__ float Bs[16][68];
    int bm = blockIdx.y << 6, bn = blockIdx.x << 6;
    int tid = threadIdx.x;
    int tm = (tid >> 4) << 2, tn = (tid & 15) << 2;
    int ar = tid >> 2, ac4 = (tid & 3) << 2;
    int br = tid >> 4, bc4 = (tid & 15) << 2;
    float acc[4][4] = {};
    for (int k0 = 0; k0 < K; k0 += 16) {
        float4 av = make_float4(0.f, 0.f, 0.f, 0.f);
        if (bm + ar < M)
            av = *(const float4*)&A[(long long)(bm + ar) * K + k0 + ac4];
        As[ac4][ar] = av.x; As[ac4 + 1][ar] = av.y;
        As[ac4 + 2][ar] = av.z; As[ac4 + 3][ar] = av.w;
        *(float4*)&Bs[br][bc4] =
            *(const float4*)&Bm[(long long)(k0 + br) * N + bn + bc4];
        __syncthreads();
        #pragma unroll
        for (int kk = 0; kk < 16; ++kk) {
            float4 a4 = *(const float4*)&As[kk][tm];
            float4 b4 = *(const float4*)&Bs[kk][tn];
            acc[0][0] += a4.x * b4.x; acc[0][1] += a4.x * b4.y;
            acc[0][2] += a4.x * b4.z; acc[0][3] += a4.x * b4.w;
            acc[1][0] += a4.y * b4.x; acc[1][1] += a4.y * b4.y;
            acc[1][2] += a4.y * b4.z; acc[1][3] += a4.y * b4.w;
            acc[2][0] += a4.z * b4.x; acc[2][1] += a4.z * b4.y;
            acc[2][2] += a4.z * b4.z; acc[2][3] += a4.z * b4.w;
            acc[3][0] += a4.w * b4.x; acc[3][1] += a4.w * b4.y;
            acc[3][2] += a4.w * b4.z; acc[3][3] += a4.w * b4.w;
        }
        __syncthreads();
    }
    #pragma unroll
    for (int i = 0; i < 4; ++i) {
        int r = bm + tm + i;
        if (r < M) {
            float v0 = acc[i][0] + bias[bn + tn + 0];
            float v1 = acc[i][1] + bias[bn + tn + 1];
            float v2 = acc[i][2] + bias[bn + tn + 2];
            float v3 = acc[i][3] + bias[bn + tn + 3];
            if (EPI == 1) { v0 = mishf(v0); v1 = mishf(v1); v2 = mishf(v2); v3 = mishf(v3); }
            float4 o; o.x = v0; o.y = v1; o.z = v2; o.w = v3;
            *(float4*)&C[(long long)r * ldc + bn + tn] = o;
            if (DUAL) {
                int rr2 = (r / 400) * 402 + (r % 400) + 1;
                *(float4*)&C2[(long long)rr2 * 256 + bn + tn] = o;
            }
        }
    }
}

// ---------------------------------------------------------------------------
// MFMA bf16x3-split GEMM. B pre-transposed+split [N][K] bf16 hi/lo.
// MT = M-tile (64 or 32). z-strides enable organ batching via blockIdx.z.
// SPLIT: cols<nhl -> qk hi/lo; cols>=1024 -> V transposed split (ld 416).
// EPI: 0 none, 1 mish, 2 relu.
// ---------------------------------------------------------------------------
template<int EPI, bool GATHER, bool SPLIT, int MT>
__global__ __launch_bounds__(256) void gemm_mfma(
    const float* __restrict__ A,
    const unsigned short* __restrict__ Bth, const unsigned short* __restrict__ Btl,
    const float* __restrict__ bias, float* __restrict__ C,
    int M, int K, int lda, int ldc, const int* __restrict__ gidx,
    unsigned short* __restrict__ Chi, unsigned short* __restrict__ Clo,
    int ldhl, int nhl,
    unsigned short* __restrict__ vthi, unsigned short* __restrict__ vtlo,
    int zA, int zB, int zBias, int zC, int zChi, int zVt)
{
    constexpr int AI = MT / 32;
    __shared__ unsigned short Ah[MT * 40];
    __shared__ unsigned short Al[MT * 40];
    __shared__ unsigned short Bh[128 * 40];
    __shared__ unsigned short Bl[128 * 40];

    long long zz = blockIdx.z;
    A    += zz * zA;
    Bth  += zz * zB;  Btl += zz * zB;
    bias += zz * zBias;
    C    += zz * zC;
    if (SPLIT) {
        Chi += zz * zChi; Clo += zz * zChi;
        vthi += zz * zVt; vtlo += zz * zVt;
    }

    int bm = blockIdx.y * MT, bn = blockIdx.x << 7;
    int tid = threadIdx.x;
    int lane = tid & 63, wid = tid >> 6;
    int wm = wid >> 1, wn = wid & 1;
    int fr = lane & 15, kg = (lane >> 4) << 3;

    int ar = tid >> 2, akc = (tid & 3) << 3;
    int bnr = tid >> 1, bkc = (tid & 1) << 4;
    bool astage = ar < MT;

    long long arow = 0; bool avalid = false;
    if (astage) {
        int gr = bm + ar;
        avalid = gr < M;
        if (GATHER) arow = avalid ? (long long)gidx[gr] : 0;
        else        arow = avalid ? (long long)gr : 0;
    }

    f32x4 acc[AI][4] = {};

    for (int k0 = 0; k0 < K; k0 += 32) {
        if (astage) {
            float vv[8];
            if (avalid) {
                float4 v0 = *(const float4*)&A[arow * lda + k0 + akc];
                float4 v1 = *(const float4*)&A[arow * lda + k0 + akc + 4];
                vv[0] = v0.x; vv[1] = v0.y; vv[2] = v0.z; vv[3] = v0.w;
                vv[4] = v1.x; vv[5] = v1.y; vv[6] = v1.z; vv[7] = v1.w;
            } else {
                #pragma unroll
                for (int e = 0; e < 8; ++e) vv[e] = 0.f;
            }
            union { unsigned short u[8]; u32x4 v; } ph, pl;
            #pragma unroll
            for (int e = 0; e < 8; ++e) {
                unsigned short h = f2bf(vv[e]);
                ph.u[e] = h;
                pl.u[e] = f2bf(vv[e] - bf2f(h));
            }
            *(u32x4*)&Ah[ar * 40 + akc] = ph.v;
            *(u32x4*)&Al[ar * 40 + akc] = pl.v;
        }
        {
            long long boff = (long long)(bn + bnr) * K + k0 + bkc;
            *(u32x4*)&Bh[bnr * 40 + bkc]     = *(const u32x4*)&Bth[boff];
            *(u32x4*)&Bh[bnr * 40 + bkc + 8] = *(const u32x4*)&Bth[boff + 8];
            *(u32x4*)&Bl[bnr * 40 + bkc]     = *(const u32x4*)&Btl[boff];
            *(u32x4*)&Bl[bnr * 40 + bkc + 8] = *(const u32x4*)&Btl[boff + 8];
        }
        __syncthreads();

        bf16x8 af[AI], alf[AI], bfj[4], blf[4];
        #pragma unroll
        for (int i = 0; i < AI; ++i) {
            int row = (MT == 64 ? wm * 32 + i * 16 : wm * 16) + fr;
            af[i]  = *(const bf16x8*)&Ah[row * 40 + kg];
            alf[i] = *(const bf16x8*)&Al[row * 40 + kg];
        }
        #pragma unroll
        for (int j = 0; j < 4; ++j) {
            int row = wn * 64 + j * 16 + fr;
            bfj[j] = *(const bf16x8*)&Bh[row * 40 + kg];
            blf[j] = *(const bf16x8*)&Bl[row * 40 + kg];
        }
        #pragma unroll
        for (int i = 0; i < AI; ++i)
        #pragma unroll
        for (int j = 0; j < 4; ++j) {
            acc[i][j] = __builtin_amdgcn_mfma_f32_16x16x32_bf16(af[i],  bfj[j], acc[i][j], 0, 0, 0);
            acc[i][j] = __builtin_amdgcn_mfma_f32_16x16x32_bf16(af[i],  blf[j], acc[i][j], 0, 0, 0);
            acc[i][j] = __builtin_amdgcn_mfma_f32_16x16x32_bf16(alf[i], bfj[j], acc[i][j], 0, 0, 0);
        }
        __syncthreads();
    }

    #pragma unroll
    for (int i = 0; i < AI; ++i) {
        int rbase = bm + (MT == 64 ? wm * 32 + i * 16 : wm * 16) + ((lane >> 4) << 2);
        #pragma unroll
        for (int j = 0; j < 4; ++j) {
            int ccol = bn + wn * 64 + j * 16 + fr;
            float bv = bias[ccol];
            #pragma unroll
            for (int r = 0; r < 4; ++r) {
                int row = rbase + r;
                if (row < M) {
                    float val = acc[i][j][r] + bv;
                    if (SPLIT) {
                        unsigned short hh = f2bf(val);
                        unsigned short ll = f2bf(val - bf2f(hh));
                        if (ccol < nhl) {
                            Chi[(long long)row * ldhl + ccol] = hh;
                            Clo[(long long)row * ldhl + ccol] = ll;
                        } else {
                            int bb = row / 400, m = row - bb * 400;
                            long long vi = ((long long)(bb * 512 + (ccol - 1024))) * 416 + m;
                            vthi[vi] = hh;
                            vtlo[vi] = ll;
                        }
                    } else {
                        if (EPI == 1) val = mishf(val);
                        if (EPI == 2) val = fmaxf(val, 0.f);
                        C[(long long)row * ldc + ccol] = val;
                    }
                }
            }
        }
    }
}

// ---------------------------------------------------------------------------
// Weight prep kernels (write-coalesced)
// ---------------------------------------------------------------------------
__global__ __launch_bounds__(256) void prep_wqkv(
    const float* __restrict__ wq, const float* __restrict__ wk,
    const float* __restrict__ wv,
    unsigned short* __restrict__ whi, unsigned short* __restrict__ wlo,
    int obase, int total)
{
    int idx = blockIdx.x * 256 + threadIdx.x;
    if (idx >= total) return;
    int o = obase + idx / 786432;
    int rem = idx % 786432;
    int n = rem >> 9, k = rem & 511;
    int sel = n >> 9, col = n & 511;
    const float* W = sel == 0 ? wq : (sel == 1 ? wk : wv);
    float v = W[(long long)o * 262144 + k * 512 + col];
    unsigned short h = f2bf(v);
    whi[idx] = h;
    wlo[idx] = f2bf(v - bf2f(h));
}

__global__ __launch_bounds__(256) void prep_woiw(
    const float* __restrict__ wo, const float* __restrict__ wi,
    const float* __restrict__ wout,
    unsigned short* __restrict__ whi, unsigned short* __restrict__ wlo,
    int obase, int total)
{
    int idx = blockIdx.x * 256 + threadIdx.x;
    if (idx >= total) return;
    int o = obase + idx / 655360;
    int rem = idx % 655360;
    float v;
    if (rem < 262144) {
        int n = rem >> 9, k = rem & 511;
        v = wo[(long long)o * 262144 + k * 512 + n];
    } else if (rem < 524288) {
        int nk = rem - 262144;
        int n = nk >> 9, k = nk & 511;
        v = wi[(long long)o * 262144 + k * 512 + n];
    } else {
        int nk = rem - 524288;
        int n = nk >> 9, k = nk & 511;   // n < 256
        v = wout[(long long)o * 131072 + k * 256 + n];
    }
    unsigned short h = f2bf(v);
    whi[idx] = h;
    wlo[idx] = f2bf(v - bf2f(h));
}

// conv weights: [3][256][256] -> [256][768] hi/lo
__global__ __launch_bounds__(256) void prep_wcnn(
    const float* __restrict__ w,
    unsigned short* __restrict__ whi, unsigned short* __restrict__ wlo)
{
    int idx = blockIdx.x * 256 + threadIdx.x;
    if (idx >= 256 * 768) return;
    int n = idx / 768, k = idx % 768;
    float v = w[k * 256 + n];
    unsigned short h = f2bf(v);
    whi[idx] = h;
    wlo[idx] = f2bf(v - bf2f(h));
}

// ---------------------------------------------------------------------------
// Fused setup: masks, convidx, relidx, f1pad guards, bqkv pack, vt pad zero
// ---------------------------------------------------------------------------
__global__ __launch_bounds__(256) void setup_kernel(
    const float* __restrict__ x,
    const float* __restrict__ bq, const float* __restrict__ bk,
    const float* __restrict__ bv,
    float* __restrict__ mk, int* __restrict__ relT, int* __restrict__ convidx,
    float* __restrict__ f1pad, float* __restrict__ bqkv,
    unsigned short* __restrict__ vt_hi, unsigned short* __restrict__ vt_lo,
    int nOrg)
{
    int i = blockIdx.x * 256 + threadIdx.x;
    if (i < 3200) {
        const float* xr = x + (long long)i * 128;
        mk[i] = xr[4];
        mk[3200 + i] = fmaxf(xr[2], xr[3]);
        mk[6400 + i] = xr[0];
        mk[9600 + i] = xr[1];
        convidx[i] = (i / 400) * 402 + (i % 400);
    }
    int j = i - 3200;
    if (j >= 0 && j < 799) {
        int rel = j - 399;
        int sgn = (rel > 0) - (rel < 0);
        int ab = (rel < 300 && rel > -300) ? 299 : (rel < 0 ? -rel : rel);
        long long bpos;
        if (ab <= 300) bpos = rel;
        else {
            double lp = ceil(log((double)ab / 300.0) / log(599.0 / 300.0) * 299.0) + 300.0;
            bpos = (long long)lp * sgn;
        }
        long long c2p = bpos + 600;
        c2p = c2p < 0 ? 0 : (c2p > 1199 ? 1199 : c2p);
        relT[j] = (int)c2p;
    }
    int k = i - 4000;
    if (k >= 0 && k < 4096) {
        int b = k >> 9, rem = k & 511;
        int row = b * 402 + (rem < 256 ? 0 : 401);
        f1pad[(long long)row * 256 + (rem & 255)] = 0.f;
    }
    int m = i - 8100;
    if (m >= 0 && m < 6144) {
        int o = m / 1536, n = m % 1536;
        float v;
        if (n < 512) v = bq[o * 512 + n];
        else if (n < 1024) v = bk[o * 512 + n - 512];
        else v = bv[o * 512 + n - 1024];
        bqkv[m] = v;
    }
    int v = i - 14244;
    if (v >= 0 && v < nOrg * 65536) {   // vt pad cols [400..416) zero, as u32
        int og = v >> 16, rem = v & 65535;
        int vb = rem & 32767;
        int row = vb >> 3, c = vb & 7;
        unsigned int* p = (unsigned int*)((rem < 32768) ? vt_hi : vt_lo);
        p[(long long)og * 851968 + row * 208 + 200 + c] = 0u;
    }
}

// ---------------------------------------------------------------------------
// LayerNorm, wave-per-row (4 rows/block). eps 1e-7. Organ-batchable:
// per-row organ o = row / rpo selects g/be slice; residual R uses row % rpo.
// ---------------------------------------------------------------------------
template<bool RES, int HD>
__global__ __launch_bounds__(256) void ln2_kernel(
    const float* __restrict__ X, const float* __restrict__ R,
    const float* __restrict__ g, const float* __restrict__ be,
    float* __restrict__ Y, int rows, int rpo)
{
    constexpr int EPL = HD / 64;
    int wv = threadIdx.x >> 6, lane = threadIdx.x & 63;
    long long row = (long long)blockIdx.x * 4 + wv;
    if (row >= rows) return;
    int o = (int)(row / rpo);
    long long rrow = row % rpo;
    const float* x = X + row * HD;
    float v[EPL];
    #pragma unroll
    for (int q = 0; q < EPL / 4; ++q) {
        float4 a = *(const float4*)&x[lane * EPL + q * 4];
        v[q*4+0] = a.x; v[q*4+1] = a.y; v[q*4+2] = a.z; v[q*4+3] = a.w;
        if (RES) {
            float4 rr = *(const float4*)&R[rrow * HD + lane * EPL + q * 4];
            v[q*4+0] += rr.x; v[q*4+1] += rr.y; v[q*4+2] += rr.z; v[q*4+3] += rr.w;
        }
    }
    float s = 0.f;
    #pragma unroll
    for (int e = 0; e < EPL; ++e) s += v[e];
    #pragma unroll
    for (int d = 1; d < 64; d <<= 1) s += __shfl_xor(s, d, 64);
    float mean = s * (1.f / HD);
    float s2 = 0.f;
    #pragma unroll
    for (int e = 0; e < EPL; ++e) { float d0 = v[e] - mean; s2 += d0 * d0; }
    #pragma unroll
    for (int d = 1; d < 64; d <<= 1) s2 += __shfl_xor(s2, d, 64);
    float inv = 1.f / sqrtf(s2 * (1.f / HD) + 1e-7f);
    #pragma unroll
    for (int q = 0; q < EPL / 4; ++q) {
        int c = lane * EPL + q * 4;
        float4 gg = *(const float4*)&g[o * HD + c];
        float4 bb = *(const float4*)&be[o * HD + c];
        float4 ov;
        ov.x = (v[q*4+0] - mean) * inv * gg.x + bb.x;
        ov.y = (v[q*4+1] - mean) * inv * gg.y + bb.y;
        ov.z = (v[q*4+2] - mean) * inv * gg.z + bb.z;
        ov.w = (v[q*4+3] - mean) * inv * gg.w + bb.w;
        *(float4*)&Y[row * HD + c] = ov;
    }
}

// ---------------------------------------------------------------------------
// MFMA fused disentangled flash attention (round 8: XCD-swizzled).
// grid (13, 8, 8*nOrg). Bijective remap so all 13 lt-blocks of one (h,z)
// land consecutively on ONE XCD (round-robin heuristic xcd = lin % 8)
// -> that head's K/V/pkg working set (~1MB) stays L2-resident.
// ---------------------------------------------------------------------------
__global__ __launch_bounds__(128) void attn_kernel(
    const unsigned short* __restrict__ qk_hi, const unsigned short* __restrict__ qk_lo,
    const unsigned short* __restrict__ vt_hi, const unsigned short* __restrict__ vt_lo,
    const unsigned short* __restrict__ pkg_hi, const unsigned short* __restrict__ pkg_lo,
    const float* __restrict__ mask, float* __restrict__ ctx)
{
    const float scale = 0.07216878364870322f;       // 1/sqrt(64*3)
    const float NEGMIN = -3.402823466e38f;
    // --- XCD-aware swizzle (bijective; gridDim.y == 8) ---
    int lin = blockIdx.x + 13 * (blockIdx.y + 8 * blockIdx.z);
    int gz = gridDim.z;
    int xcd = lin & 7, within = lin >> 3;
    int g = within / 13, lt = within - g * 13;
    int combo = xcd * gz + g;          // in [0, 8*gz)
    int h = combo & 7, z = combo >> 3;
    int b = z & 7, o = z >> 3;
    qk_hi  += (long long)o * 3276800;
    qk_lo  += (long long)o * 3276800;
    vt_hi  += (long long)o * 1703936;
    vt_lo  += (long long)o * 1703936;
    pkg_hi += (long long)o * 818176;
    pkg_lo += (long long)o * 818176;
    mask   += o * 3200;
    ctx    += (long long)o * 1638400;

    int l0 = lt * 32;
    int tid = threadIdx.x;
    int lane = tid & 63, w = tid >> 6;
    int fr = lane & 15, kg8 = (lane >> 4) << 3, g4 = (lane >> 4) << 2;

    __shared__ float T2s[32 * 68];
    __shared__ float T3s[32 * 68];
    __shared__ unsigned short Sth[32 * 40], Stl[32 * 40];

    bf16x8 qfh[2], qfl[2];
    {
        int qi = l0 + w * 16 + fr;
        bool valid = qi < 400;
        long long base = ((long long)(b * 400 + (valid ? qi : 0))) * 1024 + h * 64 + kg8;
        #pragma unroll
        for (int kk = 0; kk < 2; ++kk) {
            qfh[kk] = load_bf8(qk_hi + base + kk * 32, valid);
            qfl[kk] = load_bf8(qk_lo + base + kk * 32, valid);
        }
    }
    float wlv_r[4], ms[4], ls[4];
    #pragma unroll
    for (int r = 0; r < 4; ++r) {
        int lg = l0 + w * 16 + g4 + r;
        wlv_r[r] = (lg < 400) ? mask[b * 400 + lg] : 0.f;
        ms[r] = -INFINITY;
        ls[r] = 0.f;
    }
    f32x4 O[4] = {};
    long long vtbase = ((long long)(b * 512 + h * 64)) * 416;

    for (int mt = 0; mt < 13; ++mt) {
        int m0 = mt * 32;
        int D0 = l0 - m0 + 368;
        bf16x8 kfh[2][2], kfl[2][2];
        #pragma unroll
        for (int jf = 0; jf < 2; ++jf) {
            int kr = m0 + jf * 16 + fr;
            bool valid = kr < 400;
            long long base = ((long long)(b * 400 + (valid ? kr : 0))) * 1024 + 512 + h * 64 + kg8;
            #pragma unroll
            for (int kk = 0; kk < 2; ++kk) {
                kfh[jf][kk] = load_bf8(qk_hi + base + kk * 32, valid);
                kfl[jf][kk] = load_bf8(qk_lo + base + kk * 32, valid);
            }
        }
        bf16x8 b2h[3][2], b2l[3][2];
        #pragma unroll
        for (int c = 0; c < 3; ++c) {
            int dd = D0 + w * 16 + c * 16 + fr;
            bool vv = (unsigned)dd < 799u;
            long long base = (long long)(vv ? dd : 0) * 1024 + 512 + h * 64 + kg8;
            #pragma unroll
            for (int kk = 0; kk < 2; ++kk) {
                b2h[c][kk] = load_bf8(pkg_hi + base + kk * 32, vv);
                b2l[c][kk] = load_bf8(pkg_lo + base + kk * 32, vv);
            }
        }
        __builtin_amdgcn_s_setprio(1);
        f32x4 aT1[2] = {};
        #pragma unroll
        for (int jf = 0; jf < 2; ++jf)
        #pragma unroll
        for (int kk = 0; kk < 2; ++kk) {
            aT1[jf] = __builtin_amdgcn_mfma_f32_16x16x32_bf16(qfh[kk], kfh[jf][kk], aT1[jf], 0, 0, 0);
            aT1[jf] = __builtin_amdgcn_mfma_f32_16x16x32_bf16(qfh[kk], kfl[jf][kk], aT1[jf], 0, 0, 0);
            aT1[jf] = __builtin_amdgcn_mfma_f32_16x16x32_bf16(qfl[kk], kfh[jf][kk], aT1[jf], 0, 0, 0);
        }
        f32x4 aT2[3] = {};
        #pragma unroll
        for (int c = 0; c < 3; ++c)
        #pragma unroll
        for (int kk = 0; kk < 2; ++kk) {
            aT2[c] = __builtin_amdgcn_mfma_f32_16x16x32_bf16(qfh[kk], b2h[c][kk], aT2[c], 0, 0, 0);
            aT2[c] = __builtin_amdgcn_mfma_f32_16x16x32_bf16(qfh[kk], b2l[c][kk], aT2[c], 0, 0, 0);
            aT2[c] = __builtin_amdgcn_mfma_f32_16x16x32_bf16(qfl[kk], b2h[c][kk], aT2[c], 0, 0, 0);
        }
        __builtin_amdgcn_s_setprio(0);
        bf16x8 b3h[2][2], b3l[2][2];
        #pragma unroll
        for (int c2 = 0; c2 < 2; ++c2) {
            int dd = D0 + w * 32 + c2 * 16 + fr;
            bool vv = (unsigned)dd < 799u;
            long long base = (long long)(vv ? dd : 0) * 1024 + h * 64 + kg8;
            #pragma unroll
            for (int kk = 0; kk < 2; ++kk) {
                b3h[c2][kk] = load_bf8(pkg_hi + base + kk * 32, vv);
                b3l[c2][kk] = load_bf8(pkg_lo + base + kk * 32, vv);
            }
        }
        __builtin_amdgcn_s_setprio(1);
        f32x4 aT3[2][2] = {};
        #pragma unroll
        for (int jf = 0; jf < 2; ++jf)
        #pragma unroll
        for (int c2 = 0; c2 < 2; ++c2)
        #pragma unroll
        for (int kk = 0; kk < 2; ++kk) {
            aT3[jf][c2] = __builtin_amdgcn_mfma_f32_16x16x32_bf16(kfh[jf][kk], b3h[c2][kk], aT3[jf][c2], 0, 0, 0);
            aT3[jf][c2] = __builtin_amdgcn_mfma_f32_16x16x32_bf16(kfh[jf][kk], b3l[c2][kk], aT3[jf][c2], 0, 0, 0);
            aT3[jf][c2] = __builtin_amdgcn_mfma_f32_16x16x32_bf16(kfl[jf][kk], b3h[c2][kk], aT3[jf][c2], 0, 0, 0);
        }
        __builtin_amdgcn_s_setprio(0);
        __syncthreads();   // prev tile's T2s/T3s reads complete
        #pragma unroll
        for (int c = 0; c < 3; ++c) {
            int cc = w * 16 + c * 16 + fr;
            #pragma unroll
            for (int r = 0; r < 4; ++r)
                T2s[(w * 16 + g4 + r) * 68 + cc] = aT2[c][r];
        }
        #pragma unroll
        for (int jf = 0; jf < 2; ++jf)
        #pragma unroll
        for (int c2 = 0; c2 < 2; ++c2) {
            int cc = w * 32 + c2 * 16 + fr;
            #pragma unroll
            for (int r = 0; r < 4; ++r)
                T3s[(jf * 16 + g4 + r) * 68 + cc] = aT3[jf][c2][r];
        }
        __syncthreads();   // writes visible
        bf16x8 vfh[4], vfl[4];
        #pragma unroll
        for (int f = 0; f < 4; ++f) {
            long long a = vtbase + (long long)(f * 16 + fr) * 416 + m0 + kg8;
            vfh[f] = *(const bf16x8*)&vt_hi[a];
            vfl[f] = *(const bf16x8*)&vt_lo[a];
        }
        float wm_c[2];
        #pragma unroll
        for (int cf = 0; cf < 2; ++cf) {
            int mg = m0 + cf * 16 + fr;
            wm_c[cf] = (mg < 400) ? mask[b * 400 + mg] : 0.f;
        }
        float sc0[4], sc1[4];
        #pragma unroll
        for (int r = 0; r < 4; ++r) {
            int i = w * 16 + g4 + r;
            {
                int j = fr, rr = i - j + 31;
                bool jv = (m0 + j) < 400;
                sc0[r] = !jv ? -INFINITY :
                    ((wlv_r[r] != 0.f && wm_c[0] != 0.f) ?
                     (aT1[0][r] + T2s[i * 68 + rr] + T3s[j * 68 + rr]) * scale : NEGMIN);
            }
            {
                int j = 16 + fr, rr = i - j + 31;
                bool jv = (m0 + j) < 400;
                sc1[r] = !jv ? -INFINITY :
                    ((wlv_r[r] != 0.f && wm_c[1] != 0.f) ?
                     (aT1[1][r] + T2s[i * 68 + rr] + T3s[j * 68 + rr]) * scale : NEGMIN);
            }
        }
        float corr[4];
        #pragma unroll
        for (int r = 0; r < 4; ++r) {
            float mx = fmaxf(sc0[r], sc1[r]);
            #pragma unroll
            for (int d = 1; d < 16; d <<= 1) mx = fmaxf(mx, __shfl_xor(mx, d, 64));
            float mn = fmaxf(ms[r], mx);
            corr[r] = expf(ms[r] - mn);
            ms[r] = mn;
            float p0 = expf(sc0[r] - mn), p1 = expf(sc1[r] - mn);
            float rs = p0 + p1;
            #pragma unroll
            for (int d = 1; d < 16; d <<= 1) rs += __shfl_xor(rs, d, 64);
            ls[r] = ls[r] * corr[r] + rs;
            int i = w * 16 + g4 + r;
            unsigned short h0 = f2bf(p0);
            Sth[i * 40 + fr] = h0;
            Stl[i * 40 + fr] = f2bf(p0 - bf2f(h0));
            unsigned short h1 = f2bf(p1);
            Sth[i * 40 + 16 + fr] = h1;
            Stl[i * 40 + 16 + fr] = f2bf(p1 - bf2f(h1));
        }
        #pragma unroll
        for (int f = 0; f < 4; ++f)
        #pragma unroll
        for (int r = 0; r < 4; ++r) O[f][r] *= corr[r];
        bf16x8 Pha = *(const bf16x8*)&Sth[(w * 16 + fr) * 40 + kg8];
        bf16x8 Pla = *(const bf16x8*)&Stl[(w * 16 + fr) * 40 + kg8];
        __builtin_amdgcn_s_setprio(1);
        #pragma unroll
        for (int f = 0; f < 4; ++f) {
            O[f] = __builtin_amdgcn_mfma_f32_16x16x32_bf16(Pha, vfh[f], O[f], 0, 0, 0);
            O[f] = __builtin_amdgcn_mfma_f32_16x16x32_bf16(Pha, vfl[f], O[f], 0, 0, 0);
            O[f] = __builtin_amdgcn_mfma_f32_16x16x32_bf16(Pla, vfh[f], O[f], 0, 0, 0);
        }
        __builtin_amdgcn_s_setprio(0);
    }
    #pragma unroll
    for (int f = 0; f < 4; ++f) {
        int colg = h * 64 + f * 16 + fr;
        #pragma unroll
        for (int r = 0; r < 4; ++r) {
            int lg = l0 + w * 16 + g4 + r;
            if (lg < 400)
                ctx[((long long)(b * 400 + lg)) * 512 + colg] = O[f][r] / ls[r];
        }
    }
}

// ---------------------------------------------------------------------------
// Chunked pool / meanmax (full-chip), heads
// ---------------------------------------------------------------------------
__global__ __launch_bounds__(256) void pool_part(
    const float* __restrict__ in, long long inOStride,
    const float* __restrict__ mk, float* __restrict__ pp)
{
    int bi = blockIdx.x, c = blockIdx.y, t = threadIdx.x;
    int o = bi >> 3, b = bi & 7;
    int l0 = c * 31, l1 = min(400, l0 + 31);
    const float* ib = in + (long long)o * inOStride + (long long)(b * 400) * 256;
    const float* mkb = mk + o * 3200 + b * 400;
    float s = 0.f, mx = -INFINITY, sw = 0.f;
    for (int l = l0; l < l1; ++l) {
        float wv = mkb[l];
        float v = ib[(long long)l * 256 + t] * wv;
        s += v; mx = fmaxf(mx, v); sw += wv;
    }
    long long base = (long long)(c * gridDim.x + bi) * 514;
    pp[base + t] = s;
    pp[base + 256 + t] = mx;
    if (t == 0) pp[base + 512] = sw;
}

__global__ __launch_bounds__(256) void pool_merge(
    const float* __restrict__ pp, float* __restrict__ pooled, int nBI)
{
    int bi = blockIdx.x, t = threadIdx.x;
    float s = 0.f, mx = -INFINITY, sw = 0.f;
    for (int c = 0; c < 13; ++c) {
        long long base = (long long)(c * nBI + bi) * 514;
        s += pp[base + t];
        mx = fmaxf(mx, pp[base + 256 + t]);
        sw += pp[base + 512];
    }
    int o = bi >> 3, b = bi & 7;
    pooled[o * 4096 + b * 512 + t] = s / (sw + 1e-6f);
    pooled[o * 4096 + b * 512 + 256 + t] = mx;
}

__global__ __launch_bounds__(512) void mm_part(
    const float* __restrict__ feats, float* __restrict__ mmp)
{
    int b = blockIdx.x, c = blockIdx.y, t = threadIdx.x;
    int l0 = c * 31, l1 = min(400, l0 + 31);
    float s = 0.f, mx = -INFINITY;
    for (int l = l0; l < l1; ++l) {
        float v = feats[((long long)(b * 400 + l)) * 512 + t];
        s += v; mx = fmaxf(mx, v);
    }
    long long base = (long long)(c * 8 + b) * 1024;
    mmp[base + t] = s;
    mmp[base + 512 + t] = mx;
}

__global__ __launch_bounds__(512) void mm_merge(
    const float* __restrict__ mmp, float* __restrict__ mm)
{
    int b = blockIdx.x, t = threadIdx.x;
    float s = 0.f, mx = -INFINITY;
    for (int c = 0; c < 13; ++c) {
        long long base = (long long)(c * 8 + b) * 1024;
        s += mmp[base + t];
        mx = fmaxf(mx, mmp[base + 512 + t]);
    }
    mm[b * 1024 + t] = s / 400.f;
    mm[b * 1024 + 512 + t] = mx;
}

__global__ __launch_bounds__(256) void heads_kernel(
    const float* __restrict__ pooled, const float* __restrict__ mm,
    const float* __restrict__ w_bow1, const float* __restrict__ b_bow1,
    const float* __restrict__ w_bow2, const float* __restrict__ b_bow2,
    const float* __restrict__ w_ext1, const float* __restrict__ b_ext1,
    const float* __restrict__ w_ext2, const float* __restrict__ b_ext2,
    const float* __restrict__ w_org1, const float* __restrict__ b_org1,
    const float* __restrict__ w_org2, const float* __restrict__ b_org2,
    float* __restrict__ out)
{
    int b = blockIdx.x, role = blockIdx.y;
    int t = threadIdx.x;
    __shared__ float inb[1024];
    __shared__ float red[256];
    __shared__ float hid[256];
    if (role == 0) {
        inb[t] = pooled[b * 512 + t];
        inb[256 + t] = pooled[b * 512 + 256 + t];
        __syncthreads();
        float acc = b_bow1[t];
        for (int j = 0; j < 512; ++j) acc += inb[j] * w_bow1[j * 256 + t];
        red[t] = mishf(acc) * w_bow2[t];
        __syncthreads();
        for (int s = 128; s; s >>= 1) { if (t < s) red[t] += red[t + s]; __syncthreads(); }
        if (t == 0) out[b * 11 + 0] = red[0] + b_bow2[0];
    } else if (role == 1) {
        inb[t] = mm[b * 1024 + t];
        inb[256 + t] = mm[b * 1024 + 256 + t];
        inb[512 + t] = mm[b * 1024 + 512 + t];
        inb[768 + t] = mm[b * 1024 + 768 + t];
        __syncthreads();
        float acc = b_ext1[t];
        for (int j = 0; j < 1024; ++j) acc += inb[j] * w_ext1[j * 256 + t];
        red[t] = mishf(acc) * w_ext2[t];
        __syncthreads();
        for (int s = 128; s; s >>= 1) { if (t < s) red[t] += red[t + s]; __syncthreads(); }
        if (t == 0) { out[b * 11 + 1] = red[0] + b_ext2[0]; out[88 + b] = 0.f; }
    } else {
        int i = role - 2;
        inb[t] = pooled[((1 + i) * 8 + b) * 512 + t];
        inb[256 + t] = pooled[((1 + i) * 8 + b) * 512 + 256 + t];
        __syncthreads();
        float acc = b_org1[i * 256 + t];
        for (int j = 0; j < 512; ++j)
            acc += inb[j] * w_org1[((long long)i * 512 + j) * 256 + t];
        hid[t] = mishf(acc);
        __syncthreads();
        for (int c = 0; c < 3; ++c) {
            red[t] = hid[t] * w_org2[(i * 256 + t) * 3 + c];
            __syncthreads();
            for (int s = 128; s; s >>= 1) { if (t < s) red[t] += red[t + s]; __syncthreads(); }
            if (t == 0) out[b * 11 + 2 + i * 3 + c] = red[0] + b_org2[i * 3 + c];
            __syncthreads();
        }
    }
}

// ---------------------------------------------------------------------------
// Launch
// ---------------------------------------------------------------------------
extern "C" void kernel_launch(void* const* d_in, const int* in_sizes, int n_in,
                              void* d_out, int out_size, void* d_ws, size_t ws_size,
                              hipStream_t stream)
{
    const float* x      = (const float*)d_in[0];
    const float* w_mlp  = (const float*)d_in[1];
    const float* b_mlp  = (const float*)d_in[2];
    const float* w_cnn  = (const float*)d_in[3];
    const float* b_cnn  = (const float*)d_in[4];
    const float* rel_emb= (const float*)d_in[5];
    const float* rel_g  = (const float*)d_in[6];
    const float* rel_b  = (const float*)d_in[7];
    const float* wq     = (const float*)d_in[8];
    const float* wk     = (const float*)d_in[9];
    const float* wv     = (const float*)d_in[10];
    const float* wo     = (const float*)d_in[11];
    const float* wi     = (const float*)d_in[12];
    const float* bq     = (const float*)d_in[13];
    const float* bk     = (const float*)d_in[14];
    const float* bv     = (const float*)d_in[15];
    const float* bo     = (const float*)d_in[16];
    const float* bi     = (const float*)d_in[17];
    const float* wout   = (const float*)d_in[18];
    const float* bout   = (const float*)d_in[19];
    const float* ln1g   = (const float*)d_in[20];
    const float* ln1b   = (const float*)d_in[21];
    const float* ln2g   = (const float*)d_in[22];
    const float* ln2b   = (const float*)d_in[23];
    const float* w_bow1 = (const float*)d_in[24];
    const float* b_bow1 = (const float*)d_in[25];
    const float* w_bow2 = (const float*)d_in[26];
    const float* b_bow2 = (const float*)d_in[27];
    const float* w_ext1 = (const float*)d_in[28];
    const float* b_ext1 = (const float*)d_in[29];
    const float* w_ext2 = (const float*)d_in[30];
    const float* b_ext2 = (const float*)d_in[31];
    const float* w_org1 = (const float*)d_in[32];
    const float* b_org1 = (const float*)d_in[33];
    const float* w_org2 = (const float*)d_in[34];
    const float* b_org2 = (const float*)d_in[35];

    float* ws = (float*)d_ws;
    float* outf = (float*)d_out;
    const bool big = ws_size >= 143012736ull;   // big layout = 35,753,184 floats

    if (big) {
        // ---------------- organ-batched path ----------------
        float* featsb   = ws + 0;
        float* ctx_all  = ws + 1638400;      // 6,553,600 (f1pad first; outln_all after WO)
        float* f1pad    = ctx_all;
        float* qkA_f    = ws + 8192000;      // 6,553,600: relln_all / qk_hi_all / tmp_all,inter_all
        float* qkB_f    = ws + 14745600;     // 6,553,600: qk_lo_all / h1_all
        unsigned short* qkA = (unsigned short*)qkA_f;
        unsigned short* qkB = (unsigned short*)qkB_f;
        float* relln_all = qkA_f;            // 2,457,600 (dead before QKV writes)
        unsigned short* vtA = (unsigned short*)(ws + 21299200);  // 4x4096x416
        unsigned short* vtB = (unsigned short*)(ws + 24707072);
        unsigned short* pkgA = (unsigned short*)(ws + 28114944); // 4x799x1024
        unsigned short* pkgB = (unsigned short*)(ws + 29751296);
        unsigned short* whiA = (unsigned short*)(ws + 31387648); // 4x786,432 (later whiB_all)
        unsigned short* wloA = (unsigned short*)(ws + 32960512);
        unsigned short* wcnn_hi = (unsigned short*)(ws + 35188736);
        unsigned short* wcnn_lo = (unsigned short*)(ws + 35287040);
        float* bqkvb   = ws + 35385344;
        float* masksb  = ws + 35391488;
        float* pooledb = ws + 35404288;
        float* mmb     = ws + 35420672;
        int*   relidx  = (int*)(ws + 35428864);
        int*   convidx = (int*)(ws + 35429664);
        float* poolpart= ws + 35432864;      // 13*32*514
        float* mmpart  = ws + 35646688;      // 13*8*1024
        float* tmp_all   = qkA_f;            // 4x1,638,400 (WO out; dead qk_hi)
        float* h1_all    = qkB_f;            // 4x1,638,400 (LN1 out; dead qk_lo)
        float* inter_all = qkA_f;            // WI out overwrites tmp_all
        float* outenc_all= (float*)vtA;      // 4x819,200 (dead vt region)
        float* outln_all = ctx_all;          // 4x819,200 (ctx dead after WO)
        unsigned short* whiB_all = whiA;     // 4x655,360 (whiA dead after QKV)
        unsigned short* wloB_all = wloA;

        gemm_bias<1, true><<<dim3(4, 50), 256, 0, stream>>>(
            x, w_mlp, b_mlp, featsb, f1pad, 3200, 256, 128, 512);
        setup_kernel<<<1080, 256, 0, stream>>>(x, bq, bk, bv, masksb, relidx, convidx,
                                               f1pad, bqkvb, vtA, vtB, 4);
        prep_wcnn<<<768, 256, 0, stream>>>(w_cnn, wcnn_hi, wcnn_lo);
        gemm_mfma<2, true, false, 32><<<dim3(2, 100), 256, 0, stream>>>(
            f1pad, wcnn_hi, wcnn_lo, b_cnn, featsb + 256, 3200, 768, 256, 512, convidx,
            nullptr, nullptr, 0, 0, nullptr, nullptr, 0, 0, 0, 0, 0, 0);

        // batched rel LN (4 organs, 4800 rows)
        ln2_kernel<false, 512><<<1200, 256, 0, stream>>>(
            rel_emb, nullptr, rel_g, rel_b, relln_all, 4800, 1200);
        prep_wqkv<<<12288, 256, 0, stream>>>(wq, wk, wv, whiA, wloA, 0, 3145728);
        // PQK batched (z=organ)
        gemm_mfma<0, true, true, 64><<<dim3(8, 13, 4), 256, 0, stream>>>(
            relln_all, whiA, wloA, bqkvb, nullptr, 799, 512, 512, 0, relidx,
            pkgA, pkgB, 1024, 1024, nullptr, nullptr,
            614400, 786432, 1536, 0, 818176, 0);
        // QKV batched (z=organ)
        gemm_mfma<0, false, true, 64><<<dim3(12, 50, 4), 256, 0, stream>>>(
            featsb, whiA, wloA, bqkvb, nullptr, 3200, 512, 512, 0, nullptr,
            qkA, qkB, 1024, 1024, vtA, vtB,
            0, 786432, 1536, 0, 3276800, 1703936);
        // tail weights for all organs (whiA dead after QKV)
        prep_woiw<<<10240, 256, 0, stream>>>(wo, wi, wout, whiB_all, wloB_all,
                                             0, 2621440);
        // attention: all 4 organs, XCD-swizzled
        attn_kernel<<<dim3(13, 8, 32), 128, 0, stream>>>(qkA, qkB, vtA, vtB,
            pkgA, pkgB, masksb, ctx_all);
        // batched tail: WO -> LN1 -> WI -> WOUT -> LN2
        gemm_mfma<0, false, false, 32><<<dim3(4, 100, 4), 256, 0, stream>>>(
            ctx_all, whiB_all, wloB_all, bo, tmp_all,
            3200, 512, 512, 512, nullptr, nullptr, nullptr, 0, 0, nullptr, nullptr,
            1638400, 655360, 512, 1638400, 0, 0);
        ln2_kernel<true, 512><<<3200, 256, 0, stream>>>(
            tmp_all, featsb, ln1g, ln1b, h1_all, 12800, 3200);
        gemm_mfma<1, false, false, 32><<<dim3(4, 100, 4), 256, 0, stream>>>(
            h1_all, whiB_all + 262144, wloB_all + 262144, bi, inter_all,
            3200, 512, 512, 512, nullptr, nullptr, nullptr, 0, 0, nullptr, nullptr,
            1638400, 655360, 512, 1638400, 0, 0);
        gemm_mfma<0, false, false, 32><<<dim3(2, 100, 4), 256, 0, stream>>>(
            inter_all, whiB_all + 524288, wloB_all + 524288, bout, outenc_all,
            3200, 512, 512, 256, nullptr, nullptr, nullptr, 0, 0, nullptr, nullptr,
            1638400, 655360, 256, 819200, 0, 0);
        ln2_kernel<false, 256><<<3200, 256, 0, stream>>>(
            outenc_all, nullptr, ln2g, ln2b, outln_all, 12800, 3200);

        pool_part<<<dim3(32, 13), 256, 0, stream>>>(outln_all, 819200, masksb, poolpart);
        pool_merge<<<32, 256, 0, stream>>>(poolpart, pooledb, 32);
        mm_part<<<dim3(8, 13), 512, 0, stream>>>(featsb, mmpart);
        mm_merge<<<8, 512, 0, stream>>>(mmpart, mmb);
        heads_kernel<<<dim3(8, 5), 256, 0, stream>>>(pooledb, mmb,
            w_bow1, b_bow1, w_bow2, b_bow2, w_ext1, b_ext1, w_ext2, b_ext2,
            w_org1, b_org1, w_org2, b_org2, outf);
        return;
    }

    // ---------------- per-organ fallback path (proven-size layout) ----------------
    float* featsb  = ws + 0;
    float* ctxB    = ws + 1638400;
    float* qkvA_f  = ws + 3276800;
    float* qkvB_f  = ws + 4915200;
    unsigned short* qkv_hi = (unsigned short*)qkvA_f;
    unsigned short* qkv_lo = (unsigned short*)qkvB_f;
    float* rellnb  = qkvB_f;
    unsigned short* pkg_hi = (unsigned short*)(ws + 6553600);
    unsigned short* pkg_lo = (unsigned short*)(ws + 6963200);
    unsigned short* vt_hi  = (unsigned short*)(ws + 7372800);
    unsigned short* vt_lo  = (unsigned short*)(ws + 8224768);
    unsigned short* whi    = (unsigned short*)(ws + 9076736);
    unsigned short* wlo    = (unsigned short*)(ws + 9469952);
    float* bqkvb   = ws + 9863168;
    float* masksb  = ws + 9869312;
    float* pooledb = ws + 9882112;
    float* mmb     = ws + 9898496;
    int*   relidx  = (int*)(ws + 9906688);
    unsigned short* wcnn_hi = (unsigned short*)(ws + 9907488);
    unsigned short* wcnn_lo = (unsigned short*)(ws + 10005792);
    int*   convidx = (int*)(ws + 10104096);
    float* poolpart= ws + 10107296;
    float* mmpart  = ws + 10160752;
    float* f1pad   = ctxB;

    gemm_bias<1, true><<<dim3(4, 50), 256, 0, stream>>>(
        x, w_mlp, b_mlp, featsb, f1pad, 3200, 256, 128, 512);
    setup_kernel<<<312, 256, 0, stream>>>(x, bq, bk, bv, masksb, relidx, convidx,
                                          f1pad, bqkvb, vt_hi, vt_lo, 1);
    prep_wcnn<<<768, 256, 0, stream>>>(w_cnn, wcnn_hi, wcnn_lo);
    gemm_mfma<2, true, false, 32><<<dim3(2, 100), 256, 0, stream>>>(
        f1pad, wcnn_hi, wcnn_lo, b_cnn, featsb + 256, 3200, 768, 256, 512, convidx,
        nullptr, nullptr, 0, 0, nullptr, nullptr, 0, 0, 0, 0, 0, 0);

    for (int o = 0; o < 4; ++o) {
        ln2_kernel<false, 512><<<300, 256, 0, stream>>>(
            rel_emb + (long long)o * 614400, nullptr,
            rel_g + o * 512, rel_b + o * 512, rellnb, 1200, 1200);
        prep_wqkv<<<3072, 256, 0, stream>>>(wq, wk, wv, whi, wlo, o, 786432);
        gemm_mfma<0, true, true, 64><<<dim3(8, 13), 256, 0, stream>>>(
            rellnb, whi, wlo, bqkvb + o * 1536, nullptr, 799, 512, 512, 0, relidx,
            pkg_hi, pkg_lo, 1024, 1024, nullptr, nullptr, 0, 0, 0, 0, 0, 0);
        gemm_mfma<0, false, true, 64><<<dim3(12, 50), 256, 0, stream>>>(
            featsb, whi, wlo, bqkvb + o * 1536, nullptr, 3200, 512, 512, 0, nullptr,
            qkv_hi, qkv_lo, 1024, 1024, vt_hi, vt_lo, 0, 0, 0, 0, 0, 0);
        prep_woiw<<<2560, 256, 0, stream>>>(wo, wi, wout, whi, wlo, o, 655360);
        attn_kernel<<<dim3(13, 8, 8), 128, 0, stream>>>(qkv_hi, qkv_lo, vt_hi, vt_lo,
            pkg_hi, pkg_lo, masksb + o * 3200, ctxB);
        gemm_mfma<0, false, false, 32><<<dim3(4, 100), 256, 0, stream>>>(
            ctxB, whi, wlo, bo + o * 512, qkvA_f, 3200, 512, 512, 512, nullptr,
            nullptr, nullptr, 0, 0, nullptr, nullptr, 0, 0, 0, 0, 0, 0);
        ln2_kernel<true, 512><<<800, 256, 0, stream>>>(
            qkvA_f, featsb, ln1g + o * 512, ln1b + o * 512, ctxB, 3200, 3200);
        gemm_mfma<1, false, false, 32><<<dim3(4, 100), 256, 0, stream>>>(
            ctxB, whi + 262144, wlo + 262144, bi + o * 512, qkvA_f, 3200, 512, 512, 512,
            nullptr, nullptr, nullptr, 0, 0, nullptr, nullptr, 0, 0, 0, 0, 0, 0);
        gemm_mfma<0, false, false, 32><<<dim3(2, 100), 256, 0, stream>>>(
            qkvA_f, whi + 524288, wlo + 524288, bout + o * 256, ctxB, 3200, 512, 512, 256,
            nullptr, nullptr, nullptr, 0, 0, nullptr, nullptr, 0, 0, 0, 0, 0, 0);
        ln2_kernel<false, 256><<<800, 256, 0, stream>>>(
            ctxB, nullptr, ln2g + o * 256, ln2b + o * 256, ctxB + 819200, 3200, 3200);
        pool_part<<<dim3(8, 13), 256, 0, stream>>>(ctxB + 819200, 0,
                                                   masksb + o * 3200, poolpart);
        pool_merge<<<8, 256, 0, stream>>>(poolpart, pooledb + o * 4096, 8);
    }

    mm_part<<<dim3(8, 13), 512, 0, stream>>>(featsb, mmpart);
    mm_merge<<<8, 512, 0, stream>>>(mmpart, mmb);
    heads_kernel<<<dim3(8, 5), 256, 0, stream>>>(pooledb, mmb,
        w_bow1, b_bow1, w_bow2, b_bow2, w_ext1, b_ext1, w_ext2, b_ext2,
        w_org1, b_org1, w_org2, b_org2, outf);
}